// Round 5
// baseline (735.966 us; speedup 1.0000x reference)
//
#include <hip/hip_runtime.h>
#include <math.h>

#define NN 100000
#define NE 1600000
#define NG 1024
#define FF 128
#define BSH 9
#define NBK ((NN + 511) >> BSH)   // 196 buckets of 512 nodes
#define RB 256                    // radix blocks
#define BCAP 16384                // fixed bucket capacity (mean 8192, sigma~90)

typedef __attribute__((ext_vector_type(8))) short short8;
typedef __attribute__((ext_vector_type(4))) float f32x4;
typedef __attribute__((ext_vector_type(2))) float f32x2;

__device__ __forceinline__ unsigned short f2b(float f) {
    union { float f; unsigned u; } v; v.f = f;
    unsigned r = (v.u + 0x7FFF + ((v.u >> 16) & 1)) >> 16;
    return (unsigned short)r;
}
__device__ __forceinline__ float us2f(unsigned short u) {
    union { unsigned u; float f; } v; v.u = ((unsigned)u) << 16; return v.f;
}
// hardware ELU: v_exp_f32 is 2^x; elu(v)=v>0?v:2^(v*log2e)-1.
__device__ __forceinline__ float fast_elu(float v) {
    float e = __builtin_amdgcn_exp2f(v * 1.44269504088896340736f) - 1.0f;
    return v > 0.f ? v : e;
}
// pack 8 floats -> 8 fp8 (uint2), byte i = v[i]
__device__ __forceinline__ uint2 pk8(const float* v) {
    unsigned lo = 0, hi = 0;
    lo = (unsigned)__builtin_amdgcn_cvt_pk_fp8_f32(v[0], v[1], (int)lo, false);
    lo = (unsigned)__builtin_amdgcn_cvt_pk_fp8_f32(v[2], v[3], (int)lo, true);
    hi = (unsigned)__builtin_amdgcn_cvt_pk_fp8_f32(v[4], v[5], (int)hi, false);
    hi = (unsigned)__builtin_amdgcn_cvt_pk_fp8_f32(v[6], v[7], (int)hi, true);
    uint2 r; r.x = lo; r.y = hi; return r;
}

// ---------------- init bucket cursors to region bases -----------------------
__global__ void init_bcur(int* __restrict__ bcur) {
    int b = blockIdx.x * blockDim.x + threadIdx.x;
    if (b < NBK) bcur[b] = b * BCAP;
}

// ---------------- pass 1: scatter packed (src<<9|local) into padded buckets -
__global__ __launch_bounds__(256)
void radix_scatter(const int* __restrict__ src, const int* __restrict__ dst,
                   int* __restrict__ bcur, unsigned* __restrict__ pairs, int n) {
    __shared__ int base[NBK];
    __shared__ int cnt[NBK];
    for (int i = threadIdx.x; i < NBK; i += 256) cnt[i] = 0;
    __syncthreads();
    const int per = (n + RB - 1) / RB;
    const int beg = blockIdx.x * per;
    const int end = min(n, beg + per);
    for (int i = beg + threadIdx.x; i < end; i += 256)
        atomicAdd(&cnt[dst[i] >> BSH], 1);
    __syncthreads();
    for (int i = threadIdx.x; i < NBK; i += 256)
        base[i] = cnt[i] ? atomicAdd(&bcur[i], cnt[i]) : 0;
    __syncthreads();
    for (int i = beg + threadIdx.x; i < end; i += 256) {
        int d = dst[i];
        int p = atomicAdd(&base[d >> BSH], 1);
        pairs[p] = ((unsigned)src[i] << BSH) | (unsigned)(d & 511);
    }
}

// ---------------- pass 2: per-bucket hist+scan+scatter -> padded CSR --------
// ssrc stores PRE-SCALED byte offsets (src*128) for the fused gathers.
__global__ __launch_bounds__(256)
void bucket_build(const unsigned* __restrict__ pairs, const int* __restrict__ bcur,
                  int* __restrict__ row_beg, int* __restrict__ row_end,
                  float* __restrict__ inv_deg, int* __restrict__ ssrc) {
    __shared__ int cnt[512];
    __shared__ int curs[512];
    __shared__ int wsum[4];
    const int b = blockIdx.x;
    const int n0 = b << BSH;
    const int t = threadIdx.x;
    const int lane = t & 63, wid = t >> 6;

    for (int i = t; i < 512; i += 256) cnt[i] = 0;
    __syncthreads();
    const int beg = b * BCAP, end = bcur[b];
    for (int i = beg + t; i < end; i += 256)
        atomicAdd(&cnt[pairs[i] & 511], 1);
    __syncthreads();

    int c0 = cnt[2 * t], c1 = cnt[2 * t + 1];
    int v = c0 + c1;
    int x = v;
    #pragma unroll
    for (int o = 1; o < 64; o <<= 1) {
        int y = __shfl_up(x, o);
        if (lane >= o) x += y;
    }
    if (lane == 63) wsum[wid] = x;
    __syncthreads();
    if (t == 0) {
        int s = 0;
        #pragma unroll
        for (int w2 = 0; w2 < 4; ++w2) { int tv = wsum[w2]; wsum[w2] = s; s += tv; }
    }
    __syncthreads();
    int g0 = beg + wsum[wid] + x - v;
    int g1 = g0 + c0;
    curs[2 * t] = g0;
    curs[2 * t + 1] = g1;
    {
        int node = n0 + 2 * t;
        if (node < NN) {
            row_beg[node] = g0; row_end[node] = g1;
            inv_deg[node] = 1.0f / (float)(c0 > 1 ? c0 : 1);
        }
        node = n0 + 2 * t + 1;
        if (node < NN) {
            row_beg[node] = g1; row_end[node] = g1 + c1;
            inv_deg[node] = 1.0f / (float)(c1 > 1 ? c1 : 1);
        }
    }
    __syncthreads();
    for (int i = beg + t; i < end; i += 256) {
        unsigned pr = pairs[i];
        int p = atomicAdd(&curs[pr & 511], 1);
        ssrc[p] = (int)(pr >> BSH) << 7;   // pre-scaled byte offset (row*128)
    }
}

// ---------------- graph offsets via binary search on sorted batch -----------
__global__ __launch_bounds__(256)
void graph_offsets(const int* __restrict__ batch, int* __restrict__ g_off,
                   float* __restrict__ inv_cnt) {
    int g = blockIdx.x * blockDim.x + threadIdx.x;
    if (g > NG) return;
    if (g == NG) { g_off[NG] = NN; return; }
    int lo = 0, hi = NN;
    while (lo < hi) { int mid = (lo + hi) >> 1; if (batch[mid] < g) lo = mid + 1; else hi = mid; }
    int lo2 = lo, hi2 = NN;
    while (lo2 < hi2) { int mid = (lo2 + hi2) >> 1; if (batch[mid] < g + 1) lo2 = mid + 1; else hi2 = mid; }
    g_off[g] = lo;
    int c = lo2 - lo;
    inv_cnt[g] = 1.0f / (float)(c > 1 ? c : 1);
}

// ---------------- weight prep: fp32 [k][n] -> bf16 MFMA-FRAGMENT order ------
struct WTab { const float* a[16]; };
__global__ __launch_bounds__(256)
void prep_weights(WTab tab, unsigned short* __restrict__ dst) {
    int w = blockIdx.x >> 6;
    int idx = ((blockIdx.x & 63) << 8) + threadIdx.x;
    int j = idx & 7, lane = (idx >> 3) & 63, nt = (idx >> 9) & 7, kc = idx >> 12;
    int cb = lane & 15, rq = lane >> 4;
    int k = kc * 32 + rq * 8 + j;
    int n = nt * 16 + cb;
    dst[(size_t)w * 16384 + idx] = f2b(tab.a[w][k * 128 + n]);
}

// ---------------- mean pool per graph from bf16 ----------------
__global__ __launch_bounds__(128)
void pool_mean_b(const unsigned short* __restrict__ src, const int* __restrict__ g_off,
                 const float* __restrict__ inv_cnt, float* __restrict__ out) {
    const int g = blockIdx.x;
    const int j = threadIdx.x;
    const int beg = g_off[g], end = g_off[g + 1];
    float s = 0.f;
    for (int n = beg; n < end; ++n) s += us2f(src[(size_t)n * FF + j]);
    out[(size_t)g * FF + j] = s * inv_cnt[g];
}

// ---------------- MFMA bf16 GEMM, frag-ordered W from global (L2) ----------
template<bool AB16, bool R1, int RESM, int ACT, bool LN, bool OF32, bool OB16, bool OB8>
__global__ __launch_bounds__(256)
void gemm_mfma(const void* __restrict__ A_,
               const unsigned short* __restrict__ Wf,
               const float* __restrict__ bias,
               const float* __restrict__ rvec, const float* __restrict__ rrow,
               const float* __restrict__ res,
               const float* __restrict__ lng, const float* __restrict__ lnb,
               float* __restrict__ outf, unsigned short* __restrict__ outb,
               unsigned char* __restrict__ outb8, int M) {
    __shared__ short Al[64 * 136];

    const int t = threadIdx.x;
    const int lane = t & 63, wid = t >> 6;
    const int m0 = blockIdx.x * 64;
    const int cb = lane & 15, rq = lane >> 4;

    if (AB16) {
        const unsigned short* Ab = (const unsigned short*)A_;
        for (int i = t; i < 1024; i += 256) {
            int row = i >> 4, seg = i & 15;
            int gr = m0 + row; if (gr >= M) gr = M - 1;
            *(uint4*)&Al[row * 136 + seg * 8] = *(const uint4*)&Ab[(size_t)gr * 128 + seg * 8];
        }
    } else {
        const float* Af = (const float*)A_;
        for (int i = t; i < 2048; i += 256) {
            int row = i >> 5, seg = i & 31;
            int gr = m0 + row; if (gr >= M) gr = M - 1;
            float4 v = *(const float4*)&Af[(size_t)gr * 128 + seg * 4];
            ushort4 o = {f2b(v.x), f2b(v.y), f2b(v.z), f2b(v.w)};
            *(ushort4*)&Al[row * 136 + seg * 4] = o;
        }
    }
    __syncthreads();

    f32x4 acc[8];
    #pragma unroll
    for (int nt = 0; nt < 8; ++nt) acc[nt] = (f32x4){0.f, 0.f, 0.f, 0.f};

    const int aoff_base = (wid * 16 + cb) * 136 + rq * 8;
    for (int kc = 0; kc < 4; ++kc) {
        short8 a0 = *(const short8*)&Al[aoff_base + kc * 32];
        #pragma unroll
        for (int nt = 0; nt < 8; ++nt) {
            short8 b0 = *(const short8*)&Wf[(size_t)(kc * 8 + nt) * 512 + lane * 8];
            acc[nt] = __builtin_amdgcn_mfma_f32_16x16x32_bf16(a0, b0, acc[nt], 0, 0, 0);
        }
    }

    float bs[8], rr[8], lg[8], lb[8];
    #pragma unroll
    for (int nt = 0; nt < 8; ++nt) {
        int col = nt * 16 + cb;
        bs[nt] = bias[col];
        if (R1) rr[nt] = rrow[col];
        if (LN) { lg[nt] = lng[col]; lb[nt] = lnb[col]; }
    }
    #pragma unroll
    for (int reg = 0; reg < 4; ++reg) {
        int m = m0 + wid * 16 + rq * 4 + reg;
        int mc = m < M ? m : M - 1;
        float v[8];
        #pragma unroll
        for (int nt = 0; nt < 8; ++nt) v[nt] = acc[nt][reg] + bs[nt];
        if (R1) {
            float rv = rvec[mc];
            #pragma unroll
            for (int nt = 0; nt < 8; ++nt) v[nt] += rv * rr[nt];
        }
        if (RESM == 1) {
            #pragma unroll
            for (int nt = 0; nt < 8; ++nt) v[nt] += res[(size_t)mc * 128 + nt * 16 + cb];
        }
        if (ACT == 1) {
            #pragma unroll
            for (int nt = 0; nt < 8; ++nt) v[nt] = fast_elu(v[nt]);
        }
        if (LN) {
            float s1 = 0.f, s2 = 0.f;
            #pragma unroll
            for (int nt = 0; nt < 8; ++nt) { s1 += v[nt]; s2 += v[nt] * v[nt]; }
            #pragma unroll
            for (int o = 8; o >= 1; o >>= 1) { s1 += __shfl_xor(s1, o); s2 += __shfl_xor(s2, o); }
            float mu = s1 * (1.f / 128.f);
            float rs = rsqrtf(s2 * (1.f / 128.f) - mu * mu + 1e-5f);
            #pragma unroll
            for (int nt = 0; nt < 8; ++nt) v[nt] = (v[nt] - mu) * rs * lg[nt] + lb[nt];
        }
        if (m < M) {
            #pragma unroll
            for (int nt = 0; nt < 8; ++nt) {
                size_t o = (size_t)m * 128 + nt * 16 + cb;
                if (OF32) outf[o] = v[nt];
                if (OB16) outb[o] = f2b(v[nt]);
            }
            if (OB8) *(uint2*)&outb8[(size_t)m * 128 + cb * 8] = pk8(v);
        }
    }
}

// ---------------- FUSED layer: SAGE-agg prologue + GEMM chain --------------
// Each block aggregates its own 64 rows (gathering neighbor fp8 rows from
// h8in) directly into the Gl LDS tile, then runs the dual-GEMM + FF chain.
// Co-resident blocks sit in different phases (gather / MFMA / epilogue),
// filling each other's stalls; aggb never round-trips HBM; 1 launch/layer.
// h8in/h8out are DISTINCT buffers (ping-pong) — blocks gather from h8in
// while writing h8out, so no cross-block race.
__global__ __launch_bounds__(256)
void gc_chain(const unsigned short* __restrict__ hin,
              const unsigned char* __restrict__ h8in,
              const int* __restrict__ row_beg, const int* __restrict__ row_end,
              const float* __restrict__ inv_deg, const int* __restrict__ ssrc,
              unsigned short* __restrict__ hout, unsigned char* __restrict__ h8out,
              const unsigned short* __restrict__ Wl_f, const unsigned short* __restrict__ Wr_f,
              const unsigned short* __restrict__ W1_f, const unsigned short* __restrict__ W2_f,
              const float* __restrict__ bl,
              const float* __restrict__ g1, const float* __restrict__ b1,
              const float* __restrict__ bb1, const float* __restrict__ bb2,
              const float* __restrict__ g2, const float* __restrict__ b2, int M) {
    __shared__ short Hl[64 * 136];     // h tile -> y1 tile
    __shared__ short Gl[64 * 136];     // agg tile -> elu(t) tile

    const int t = threadIdx.x;
    const int lane = t & 63, wid = t >> 6;
    const int m0 = blockIdx.x * 64;
    const int cb = lane & 15, rq = lane >> 4;
    const int aoff_base = (wid * 16 + cb) * 136 + rq * 8;
    const int boff = lane * 8;

    // ---- stage Hl (loads issue first, overlap with the gather chains) ----
    for (int i = t; i < 1024; i += 256) {
        int row = i >> 4, seg = i & 15;
        int gr = m0 + row; if (gr >= M) gr = M - 1;
        *(uint4*)&Hl[row * 136 + seg * 8] = *(const uint4*)&hin[(size_t)gr * 128 + seg * 8];
    }

    // ---- fused SAGE aggregation: wave wid aggregates rows wid*16..+15 ----
    {
        const int eg = lane >> 4, j = lane & 15, jo = j * 8;
        for (int nl = 0; nl < 16; ++nl) {
            int row = wid * 16 + nl;
            int node = m0 + row; if (node >= NN) node = NN - 1;
            const int beg = row_beg[node], end = row_end[node];
            f32x2 a0 = {0.f, 0.f}, a1 = {0.f, 0.f}, a2 = {0.f, 0.f}, a3 = {0.f, 0.f};
            for (int e = beg + eg; e < end; e += 32) {
                uint2 u[8];
                #pragma unroll
                for (int k = 0; k < 8; ++k) {
                    int ek = e + 4 * k;
                    bool ok = ek < end;
                    int idx = ssrc[ok ? ek : e];               // e always < end
                    uint2 uu = *(const uint2*)(h8in + (unsigned)(idx + jo));
                    uu.x = ok ? uu.x : 0u;
                    uu.y = ok ? uu.y : 0u;                     // fp8 0x00 -> 0.0f
                    u[k] = uu;
                }
                #pragma unroll
                for (int k = 0; k < 8; ++k) {
                    a0 += __builtin_amdgcn_cvt_pk_f32_fp8(u[k].x, false);
                    a1 += __builtin_amdgcn_cvt_pk_f32_fp8(u[k].x, true);
                    a2 += __builtin_amdgcn_cvt_pk_f32_fp8(u[k].y, false);
                    a3 += __builtin_amdgcn_cvt_pk_f32_fp8(u[k].y, true);
                }
            }
            float af[8] = {a0.x, a0.y, a1.x, a1.y, a2.x, a2.y, a3.x, a3.y};
            #pragma unroll
            for (int k = 0; k < 8; ++k) {
                af[k] += __shfl_xor(af[k], 16);
                af[k] += __shfl_xor(af[k], 32);
            }
            if (eg == 0) {
                float id = inv_deg[node];
                #pragma unroll
                for (int nt = 0; nt < 8; ++nt)
                    Gl[row * 136 + nt * 16 + j] = (short)f2b(af[nt] * id);
            }
        }
    }
    __syncthreads();   // the only barrier

    f32x4 acc[8];
    #pragma unroll
    for (int nt = 0; nt < 8; ++nt) acc[nt] = (f32x4){0.f, 0.f, 0.f, 0.f};

    // ---- dual GEMM: acc = agg@Wl + h@Wr ----
    for (int kc = 0; kc < 4; ++kc) {
        short8 a0 = *(const short8*)&Gl[aoff_base + kc * 32];
        short8 a1 = *(const short8*)&Hl[aoff_base + kc * 32];
        #pragma unroll
        for (int nt = 0; nt < 8; ++nt) {
            const size_t wo = (size_t)(kc * 8 + nt) * 512 + boff;
            acc[nt] = __builtin_amdgcn_mfma_f32_16x16x32_bf16(a0, *(const short8*)&Wl_f[wo], acc[nt], 0, 0, 0);
            acc[nt] = __builtin_amdgcn_mfma_f32_16x16x32_bf16(a1, *(const short8*)&Wr_f[wo], acc[nt], 0, 0, 0);
        }
    }

    // ---- epilogue 1 (band-local): y1 = LN1(acc + bl + h) -> Hl + regs ----
    float y1r[4][8];
    {
        float bs[8], lg[8], lb[8];
        #pragma unroll
        for (int nt = 0; nt < 8; ++nt) {
            int col = nt * 16 + cb;
            bs[nt] = bl[col]; lg[nt] = g1[col]; lb[nt] = b1[col];
        }
        #pragma unroll
        for (int reg = 0; reg < 4; ++reg) {
            int r = wid * 16 + rq * 4 + reg;
            float v[8];
            float s1 = 0.f, s2 = 0.f;
            #pragma unroll
            for (int nt = 0; nt < 8; ++nt) {
                v[nt] = acc[nt][reg] + bs[nt] + us2f((unsigned short)Hl[r * 136 + nt * 16 + cb]);
                s1 += v[nt]; s2 += v[nt] * v[nt];
            }
            #pragma unroll
            for (int o = 8; o >= 1; o >>= 1) { s1 += __shfl_xor(s1, o); s2 += __shfl_xor(s2, o); }
            float mu = s1 * (1.f / 128.f);
            float rs = rsqrtf(s2 * (1.f / 128.f) - mu * mu + 1e-5f);
            #pragma unroll
            for (int nt = 0; nt < 8; ++nt) {
                float y = (v[nt] - mu) * rs * lg[nt] + lb[nt];
                y1r[reg][nt] = y;
                Hl[r * 136 + nt * 16 + cb] = (short)f2b(y);
            }
        }
    }

    // ---- FF1 (band-local): t = elu(y1@W1 + bb1) -> Gl ----
    #pragma unroll
    for (int nt = 0; nt < 8; ++nt) acc[nt] = (f32x4){0.f, 0.f, 0.f, 0.f};
    for (int kc = 0; kc < 4; ++kc) {
        short8 a0 = *(const short8*)&Hl[aoff_base + kc * 32];
        #pragma unroll
        for (int nt = 0; nt < 8; ++nt)
            acc[nt] = __builtin_amdgcn_mfma_f32_16x16x32_bf16(
                a0, *(const short8*)&W1_f[(size_t)(kc * 8 + nt) * 512 + boff], acc[nt], 0, 0, 0);
    }
    {
        float bs[8];
        #pragma unroll
        for (int nt = 0; nt < 8; ++nt) bs[nt] = bb1[nt * 16 + cb];
        #pragma unroll
        for (int reg = 0; reg < 4; ++reg) {
            int r = wid * 16 + rq * 4 + reg;
            #pragma unroll
            for (int nt = 0; nt < 8; ++nt) {
                float v = fast_elu(acc[nt][reg] + bs[nt]);
                Gl[r * 136 + nt * 16 + cb] = (short)f2b(v);
            }
        }
    }

    // ---- FF2 (band-local): h' = LN2(t@W2 + bb2 + y1) -> global bf16 + fp8 --
    #pragma unroll
    for (int nt = 0; nt < 8; ++nt) acc[nt] = (f32x4){0.f, 0.f, 0.f, 0.f};
    for (int kc = 0; kc < 4; ++kc) {
        short8 a0 = *(const short8*)&Gl[aoff_base + kc * 32];
        #pragma unroll
        for (int nt = 0; nt < 8; ++nt)
            acc[nt] = __builtin_amdgcn_mfma_f32_16x16x32_bf16(
                a0, *(const short8*)&W2_f[(size_t)(kc * 8 + nt) * 512 + boff], acc[nt], 0, 0, 0);
    }
    {
        float bs[8], lg[8], lb[8];
        #pragma unroll
        for (int nt = 0; nt < 8; ++nt) {
            int col = nt * 16 + cb;
            bs[nt] = bb2[col]; lg[nt] = g2[col]; lb[nt] = b2[col];
        }
        #pragma unroll
        for (int reg = 0; reg < 4; ++reg) {
            int r = wid * 16 + rq * 4 + reg;
            int m = m0 + r;
            float v[8];
            float s1 = 0.f, s2 = 0.f;
            #pragma unroll
            for (int nt = 0; nt < 8; ++nt) {
                v[nt] = acc[nt][reg] + bs[nt] + y1r[reg][nt];
                s1 += v[nt]; s2 += v[nt] * v[nt];
            }
            #pragma unroll
            for (int o = 8; o >= 1; o >>= 1) { s1 += __shfl_xor(s1, o); s2 += __shfl_xor(s2, o); }
            float mu = s1 * (1.f / 128.f);
            float rs = rsqrtf(s2 * (1.f / 128.f) - mu * mu + 1e-5f);
            if (m < M) {
                float fv[8];
                #pragma unroll
                for (int nt = 0; nt < 8; ++nt) {
                    fv[nt] = (v[nt] - mu) * rs * lg[nt] + lb[nt];
                    hout[(size_t)m * 128 + nt * 16 + cb] = f2b(fv[nt]);
                }
                *(uint2*)&h8out[(size_t)m * 128 + cb * 8] = pk8(fv);
            }
        }
    }
}

extern "C" void kernel_launch(void* const* d_in, const int* in_sizes, int n_in,
                              void* d_out, int out_size, void* d_ws, size_t ws_size,
                              hipStream_t stream) {
    const float* x      = (const float*)d_in[0];
    const float* w      = (const float*)d_in[1];
    const int*   ei     = (const int*)d_in[2];
    const int*   batch  = (const int*)d_in[3];
    const float* W_in   = (const float*)d_in[4];
    const float* b_in   = (const float*)d_in[5];
    const float* sage_Wl = (const float*)d_in[6];
    const float* sage_bl = (const float*)d_in[7];
    const float* sage_Wr = (const float*)d_in[8];
    const float* ln1_g  = (const float*)d_in[9];
    const float* ln1_b  = (const float*)d_in[10];
    const float* lin1_W = (const float*)d_in[11];
    const float* lin1_b = (const float*)d_in[12];
    const float* lin2_W = (const float*)d_in[13];
    const float* lin2_b = (const float*)d_in[14];
    const float* ln2_g  = (const float*)d_in[15];
    const float* ln2_b  = (const float*)d_in[16];
    const float* mdf_W  = (const float*)d_in[17];
    const float* mdf_b  = (const float*)d_in[18];
    const float* pln1_g = (const float*)d_in[19];
    const float* pln1_b = (const float*)d_in[20];
    const float* plin1_W = (const float*)d_in[21];
    const float* plin1_b = (const float*)d_in[22];
    const float* plin2_W = (const float*)d_in[23];
    const float* plin2_b = (const float*)d_in[24];
    const float* pln2_g = (const float*)d_in[25];
    const float* pln2_b = (const float*)d_in[26];
    float* out = (float*)d_out;

    const int* e_src = ei;
    const int* e_dst = ei + NE;

    // ---- workspace layout ----
    float* ws = (float*)d_ws;
    size_t off = 0;
    float* gm    = ws + off; off += (size_t)NG * FF;
    float* hh    = ws + off; off += (size_t)NG * FF;
    float* tt    = ws + off; off += (size_t)NG * FF;
    float* inv_deg = ws + off; off += NN;
    float* inv_cnt = ws + off; off += NG;
    unsigned short* us = (unsigned short*)(ws + off);
    size_t uoff = 0;
    unsigned short* hb0  = us + uoff; uoff += (size_t)NN * FF;
    unsigned short* hb1  = us + uoff; uoff += (size_t)NN * FF;
    unsigned short* aggb = us + uoff; uoff += (size_t)NN * FF;   // reused: h8_b
    unsigned short* wt   = us + uoff; uoff += (size_t)16 * 16384;
    int* iw = (int*)(us + uoff);
    size_t ioff = 0;
    unsigned* pairs = (unsigned*)iw; ioff += (size_t)NBK * BCAP;
    int* ssrc    = iw + ioff; ioff += (size_t)NBK * BCAP;
    int* row_beg = iw + ioff; ioff += NN;
    int* row_end = iw + ioff; ioff += NN;
    int* g_off   = iw + ioff; ioff += NG + 1;
    int* bcur    = iw + ioff; ioff += NBK;
    // h8_a (12.8 MB) aliases pairs (12.85 MB): pairs is dead after
    // bucket_build, h8_a is first written by the input GEMM (runs after).
    // h8_b reuses the dead aggb region (25.6 MB). Fused gc_chain gathers
    // from one and writes the other (ping-pong) to avoid the overwrite race.
    unsigned char* h8a = (unsigned char*)pairs;
    unsigned char* h8b = (unsigned char*)aggb;

    // ---- weight prep (16 matrices -> frag-ordered bf16) ----
    WTab tab;
    tab.a[0] = W_in;
    for (int l = 0; l < 3; ++l) {
        tab.a[1 + l]  = sage_Wl + (size_t)l * 16384;
        tab.a[4 + l]  = sage_Wr + (size_t)l * 16384;
        tab.a[7 + l]  = lin1_W + (size_t)l * 16384;
        tab.a[10 + l] = lin2_W + (size_t)l * 16384;
    }
    tab.a[13] = mdf_W;      // first 128 rows only (Wa)
    tab.a[14] = plin1_W;
    tab.a[15] = plin2_W;
    prep_weights<<<16 * 64, 256, 0, stream>>>(tab, wt);
    const unsigned short* win_t = wt + 0 * 16384;
    const unsigned short* wa_t  = wt + 13 * 16384;
    const unsigned short* p1_t  = wt + 14 * 16384;
    const unsigned short* p2_t  = wt + 15 * 16384;

    // ---- build padded CSR (no histogram pass, no scan) ----
    init_bcur<<<1, 256, 0, stream>>>(bcur);
    graph_offsets<<<(NG + 256) / 256, 256, 0, stream>>>(batch, g_off, inv_cnt);
    radix_scatter<<<RB, 256, 0, stream>>>(e_src, e_dst, bcur, pairs, NE);
    bucket_build<<<NBK, 256, 0, stream>>>(pairs, bcur, row_beg, row_end, inv_deg, ssrc);

    const int GN = (NN + 63) / 64;     // 1563
    const int GB = NG / 64;            // 16

    // ---- input linear: hb0 (bf16) + h8a (fp8, permuted) ----
    gemm_mfma<false, true, 0, 0, false, false, true, true><<<GN, 256, 0, stream>>>(
        x, win_t, b_in, w, W_in + 128 * 128,
        nullptr, nullptr, nullptr, nullptr, hb0, h8a, NN);

    // ---- 3 fused GC layers: agg prologue + GEMM chain, h8 ping-pong ----
    unsigned short* hcur = hb0;
    unsigned short* hnxt = hb1;
    unsigned char* h8cur = h8a;
    unsigned char* h8nxt = h8b;
    for (int l = 0; l < 3; ++l) {
        gc_chain<<<GN, 256, 0, stream>>>(
            hcur, h8cur, row_beg, row_end, inv_deg, ssrc,
            hnxt, h8nxt,
            wt + (size_t)(1 + l) * 16384, wt + (size_t)(4 + l) * 16384,
            wt + (size_t)(7 + l) * 16384, wt + (size_t)(10 + l) * 16384,
            sage_bl + (size_t)l * FF,
            ln1_g + (size_t)l * FF, ln1_b + (size_t)l * FF,
            lin1_b + (size_t)l * FF, lin2_b + (size_t)l * FF,
            ln2_g + (size_t)l * FF, ln2_b + (size_t)l * FF, NN);
        unsigned short* tmp = hcur; hcur = hnxt; hnxt = tmp;
        unsigned char* t8 = h8cur; h8cur = h8nxt; h8nxt = t8;
    }

    // ---- head: pool(h2) == gm @ mdf_W[0:128] + mdf_b  (exact algebra) ----
    pool_mean_b<<<NG, 128, 0, stream>>>(hcur, g_off, inv_cnt, gm);
    gemm_mfma<false, false, 0, 0, true, true, false, false><<<GB, 256, 0, stream>>>(
        gm, wa_t, mdf_b, nullptr, nullptr,
        nullptr, pln1_g, pln1_b, hh, nullptr, nullptr, NG);
    gemm_mfma<false, false, 0, 1, false, true, false, false><<<GB, 256, 0, stream>>>(
        hh, p1_t, plin1_b, nullptr, nullptr,
        nullptr, nullptr, nullptr, tt, nullptr, nullptr, NG);
    gemm_mfma<false, false, 1, 0, true, true, false, false><<<GB, 256, 0, stream>>>(
        tt, p2_t, plin2_b, nullptr, nullptr,
        hh, pln2_g, pln2_b, out, nullptr, nullptr, NG);
}

// Round 6
// 623.900 us; speedup vs baseline: 1.1796x; 1.1796x over previous
//
#include <hip/hip_runtime.h>
#include <math.h>

#define NN 100000
#define NE 1600000
#define NG 1024
#define FF 128
#define BSH 9
#define NBK ((NN + 511) >> BSH)   // 196 buckets of 512 nodes
#define RB 256                    // radix blocks
#define BCAP 16384                // fixed bucket capacity (mean 8192, sigma~90)

typedef __attribute__((ext_vector_type(8))) short short8;
typedef __attribute__((ext_vector_type(4))) float f32x4;
typedef __attribute__((ext_vector_type(2))) float f32x2;

__device__ __forceinline__ unsigned short f2b(float f) {
    union { float f; unsigned u; } v; v.f = f;
    unsigned r = (v.u + 0x7FFF + ((v.u >> 16) & 1)) >> 16;
    return (unsigned short)r;
}
__device__ __forceinline__ float us2f(unsigned short u) {
    union { unsigned u; float f; } v; v.u = ((unsigned)u) << 16; return v.f;
}
// hardware ELU: v_exp_f32 is 2^x; elu(v)=v>0?v:2^(v*log2e)-1.
__device__ __forceinline__ float fast_elu(float v) {
    float e = __builtin_amdgcn_exp2f(v * 1.44269504088896340736f) - 1.0f;
    return v > 0.f ? v : e;
}
// pack 8 floats -> 8 fp8 (uint2), byte i = v[i]
__device__ __forceinline__ uint2 pk8(const float* v) {
    unsigned lo = 0, hi = 0;
    lo = (unsigned)__builtin_amdgcn_cvt_pk_fp8_f32(v[0], v[1], (int)lo, false);
    lo = (unsigned)__builtin_amdgcn_cvt_pk_fp8_f32(v[2], v[3], (int)lo, true);
    hi = (unsigned)__builtin_amdgcn_cvt_pk_fp8_f32(v[4], v[5], (int)hi, false);
    hi = (unsigned)__builtin_amdgcn_cvt_pk_fp8_f32(v[6], v[7], (int)hi, true);
    uint2 r; r.x = lo; r.y = hi; return r;
}

// ---------------- init bucket cursors to region bases -----------------------
__global__ void init_bcur(int* __restrict__ bcur) {
    int b = blockIdx.x * blockDim.x + threadIdx.x;
    if (b < NBK) bcur[b] = b * BCAP;
}

// ---------------- pass 1: scatter packed (src<<9|local) into padded buckets -
__global__ __launch_bounds__(256)
void radix_scatter(const int* __restrict__ src, const int* __restrict__ dst,
                   int* __restrict__ bcur, unsigned* __restrict__ pairs, int n) {
    __shared__ int base[NBK];
    __shared__ int cnt[NBK];
    for (int i = threadIdx.x; i < NBK; i += 256) cnt[i] = 0;
    __syncthreads();
    const int per = (n + RB - 1) / RB;
    const int beg = blockIdx.x * per;
    const int end = min(n, beg + per);
    for (int i = beg + threadIdx.x; i < end; i += 256)
        atomicAdd(&cnt[dst[i] >> BSH], 1);
    __syncthreads();
    for (int i = threadIdx.x; i < NBK; i += 256)
        base[i] = cnt[i] ? atomicAdd(&bcur[i], cnt[i]) : 0;
    __syncthreads();
    for (int i = beg + threadIdx.x; i < end; i += 256) {
        int d = dst[i];
        int p = atomicAdd(&base[d >> BSH], 1);
        pairs[p] = ((unsigned)src[i] << BSH) | (unsigned)(d & 511);
    }
}

// ---------------- pass 2: per-bucket hist+scan+scatter -> padded CSR --------
// ssrc stores PRE-SCALED byte offsets (src*128) for sage_agg's gathers.
__global__ __launch_bounds__(256)
void bucket_build(const unsigned* __restrict__ pairs, const int* __restrict__ bcur,
                  int* __restrict__ row_beg, int* __restrict__ row_end,
                  float* __restrict__ inv_deg, int* __restrict__ ssrc) {
    __shared__ int cnt[512];
    __shared__ int curs[512];
    __shared__ int wsum[4];
    const int b = blockIdx.x;
    const int n0 = b << BSH;
    const int t = threadIdx.x;
    const int lane = t & 63, wid = t >> 6;

    for (int i = t; i < 512; i += 256) cnt[i] = 0;
    __syncthreads();
    const int beg = b * BCAP, end = bcur[b];
    for (int i = beg + t; i < end; i += 256)
        atomicAdd(&cnt[pairs[i] & 511], 1);
    __syncthreads();

    int c0 = cnt[2 * t], c1 = cnt[2 * t + 1];
    int v = c0 + c1;
    int x = v;
    #pragma unroll
    for (int o = 1; o < 64; o <<= 1) {
        int y = __shfl_up(x, o);
        if (lane >= o) x += y;
    }
    if (lane == 63) wsum[wid] = x;
    __syncthreads();
    if (t == 0) {
        int s = 0;
        #pragma unroll
        for (int w2 = 0; w2 < 4; ++w2) { int tv = wsum[w2]; wsum[w2] = s; s += tv; }
    }
    __syncthreads();
    int g0 = beg + wsum[wid] + x - v;
    int g1 = g0 + c0;
    curs[2 * t] = g0;
    curs[2 * t + 1] = g1;
    {
        int node = n0 + 2 * t;
        if (node < NN) {
            row_beg[node] = g0; row_end[node] = g1;
            inv_deg[node] = 1.0f / (float)(c0 > 1 ? c0 : 1);
        }
        node = n0 + 2 * t + 1;
        if (node < NN) {
            row_beg[node] = g1; row_end[node] = g1 + c1;
            inv_deg[node] = 1.0f / (float)(c1 > 1 ? c1 : 1);
        }
    }
    __syncthreads();
    for (int i = beg + t; i < end; i += 256) {
        unsigned pr = pairs[i];
        int p = atomicAdd(&curs[pr & 511], 1);
        ssrc[p] = (int)(pr >> BSH) << 7;   // pre-scaled byte offset (row*128)
    }
}

// ---------------- graph offsets via binary search on sorted batch -----------
__global__ __launch_bounds__(256)
void graph_offsets(const int* __restrict__ batch, int* __restrict__ g_off,
                   float* __restrict__ inv_cnt) {
    int g = blockIdx.x * blockDim.x + threadIdx.x;
    if (g > NG) return;
    if (g == NG) { g_off[NG] = NN; return; }
    int lo = 0, hi = NN;
    while (lo < hi) { int mid = (lo + hi) >> 1; if (batch[mid] < g) lo = mid + 1; else hi = mid; }
    int lo2 = lo, hi2 = NN;
    while (lo2 < hi2) { int mid = (lo2 + hi2) >> 1; if (batch[mid] < g + 1) lo2 = mid + 1; else hi2 = mid; }
    g_off[g] = lo;
    int c = lo2 - lo;
    inv_cnt[g] = 1.0f / (float)(c > 1 ? c : 1);
}

// ---------------- weight prep: fp32 [k][n] -> bf16 MFMA-FRAGMENT order ------
struct WTab { const float* a[16]; };
__global__ __launch_bounds__(256)
void prep_weights(WTab tab, unsigned short* __restrict__ dst) {
    int w = blockIdx.x >> 6;
    int idx = ((blockIdx.x & 63) << 8) + threadIdx.x;
    int j = idx & 7, lane = (idx >> 3) & 63, nt = (idx >> 9) & 7, kc = idx >> 12;
    int cb = lane & 15, rq = lane >> 4;
    int k = kc * 32 + rq * 8 + j;
    int n = nt * 16 + cb;
    dst[(size_t)w * 16384 + idx] = f2b(tab.a[w][k * 128 + n]);
}

// ---------------- SAGE mean aggregation from fp8 shadow (permuted rows) -----
// Predicated batch-of-6: covers 24 edges/iter (P(deg>24 | Poisson 16) ~2%),
// cutting predicated-off gather waste 25% vs batch-of-8 at mean deg 16.
__global__ __launch_bounds__(256)
void sage_agg(const unsigned char* __restrict__ h8, const int* __restrict__ row_beg,
              const int* __restrict__ row_end, const float* __restrict__ inv_deg,
              const int* __restrict__ ssrc, unsigned short* __restrict__ aggb) {
    const int wid = threadIdx.x >> 6;
    const int lane = threadIdx.x & 63;
    const int node = blockIdx.x * 4 + wid;
    const int eg = lane >> 4, j = lane & 15;
    const int jo = j * 8;
    const int beg = row_beg[node], end = row_end[node];
    f32x2 a0 = {0.f, 0.f}, a1 = {0.f, 0.f}, a2 = {0.f, 0.f}, a3 = {0.f, 0.f};
    for (int e = beg + eg; e < end; e += 24) {
        uint2 u[6];
        #pragma unroll
        for (int k = 0; k < 6; ++k) {
            int ek = e + 4 * k;
            bool ok = ek < end;
            int idx = ssrc[ok ? ek : e];                       // e always < end
            uint2 uu = *(const uint2*)(h8 + (unsigned)(idx + jo));
            uu.x = ok ? uu.x : 0u;
            uu.y = ok ? uu.y : 0u;                             // fp8 0x00 -> 0.0f
            u[k] = uu;
        }
        #pragma unroll
        for (int k = 0; k < 6; ++k) {
            a0 += __builtin_amdgcn_cvt_pk_f32_fp8(u[k].x, false);
            a1 += __builtin_amdgcn_cvt_pk_f32_fp8(u[k].x, true);
            a2 += __builtin_amdgcn_cvt_pk_f32_fp8(u[k].y, false);
            a3 += __builtin_amdgcn_cvt_pk_f32_fp8(u[k].y, true);
        }
    }
    float af[8] = {a0.x, a0.y, a1.x, a1.y, a2.x, a2.y, a3.x, a3.y};
    #pragma unroll
    for (int k = 0; k < 8; ++k) {
        af[k] += __shfl_xor(af[k], 16);
        af[k] += __shfl_xor(af[k], 32);
    }
    if (eg == 0) {
        float id = inv_deg[node];
        #pragma unroll
        for (int nt = 0; nt < 8; ++nt)
            aggb[(size_t)node * 128 + nt * 16 + j] = f2b(af[nt] * id);
    }
}

// ---------------- mean pool per graph from bf16 ----------------
__global__ __launch_bounds__(128)
void pool_mean_b(const unsigned short* __restrict__ src, const int* __restrict__ g_off,
                 const float* __restrict__ inv_cnt, float* __restrict__ out) {
    const int g = blockIdx.x;
    const int j = threadIdx.x;
    const int beg = g_off[g], end = g_off[g + 1];
    float s = 0.f;
    for (int n = beg; n < end; ++n) s += us2f(src[(size_t)n * FF + j]);
    out[(size_t)g * FF + j] = s * inv_cnt[g];
}

// ---------------- MFMA bf16 GEMM, frag-ordered W from global (L2) ----------
template<bool AB16, bool R1, int RESM, int ACT, bool LN, bool OF32, bool OB16, bool OB8>
__global__ __launch_bounds__(256)
void gemm_mfma(const void* __restrict__ A_,
               const unsigned short* __restrict__ Wf,
               const float* __restrict__ bias,
               const float* __restrict__ rvec, const float* __restrict__ rrow,
               const float* __restrict__ res,
               const float* __restrict__ lng, const float* __restrict__ lnb,
               float* __restrict__ outf, unsigned short* __restrict__ outb,
               unsigned char* __restrict__ outb8, int M) {
    __shared__ short Al[64 * 136];

    const int t = threadIdx.x;
    const int lane = t & 63, wid = t >> 6;
    const int m0 = blockIdx.x * 64;
    const int cb = lane & 15, rq = lane >> 4;

    if (AB16) {
        const unsigned short* Ab = (const unsigned short*)A_;
        for (int i = t; i < 1024; i += 256) {
            int row = i >> 4, seg = i & 15;
            int gr = m0 + row; if (gr >= M) gr = M - 1;
            *(uint4*)&Al[row * 136 + seg * 8] = *(const uint4*)&Ab[(size_t)gr * 128 + seg * 8];
        }
    } else {
        const float* Af = (const float*)A_;
        for (int i = t; i < 2048; i += 256) {
            int row = i >> 5, seg = i & 31;
            int gr = m0 + row; if (gr >= M) gr = M - 1;
            float4 v = *(const float4*)&Af[(size_t)gr * 128 + seg * 4];
            ushort4 o = {f2b(v.x), f2b(v.y), f2b(v.z), f2b(v.w)};
            *(ushort4*)&Al[row * 136 + seg * 4] = o;
        }
    }
    __syncthreads();

    f32x4 acc[8];
    #pragma unroll
    for (int nt = 0; nt < 8; ++nt) acc[nt] = (f32x4){0.f, 0.f, 0.f, 0.f};

    const int aoff_base = (wid * 16 + cb) * 136 + rq * 8;
    for (int kc = 0; kc < 4; ++kc) {
        short8 a0 = *(const short8*)&Al[aoff_base + kc * 32];
        #pragma unroll
        for (int nt = 0; nt < 8; ++nt) {
            short8 b0 = *(const short8*)&Wf[(size_t)(kc * 8 + nt) * 512 + lane * 8];
            acc[nt] = __builtin_amdgcn_mfma_f32_16x16x32_bf16(a0, b0, acc[nt], 0, 0, 0);
        }
    }

    float bs[8], rr[8], lg[8], lb[8];
    #pragma unroll
    for (int nt = 0; nt < 8; ++nt) {
        int col = nt * 16 + cb;
        bs[nt] = bias[col];
        if (R1) rr[nt] = rrow[col];
        if (LN) { lg[nt] = lng[col]; lb[nt] = lnb[col]; }
    }
    #pragma unroll
    for (int reg = 0; reg < 4; ++reg) {
        int m = m0 + wid * 16 + rq * 4 + reg;
        int mc = m < M ? m : M - 1;
        float v[8];
        #pragma unroll
        for (int nt = 0; nt < 8; ++nt) v[nt] = acc[nt][reg] + bs[nt];
        if (R1) {
            float rv = rvec[mc];
            #pragma unroll
            for (int nt = 0; nt < 8; ++nt) v[nt] += rv * rr[nt];
        }
        if (RESM == 1) {
            #pragma unroll
            for (int nt = 0; nt < 8; ++nt) v[nt] += res[(size_t)mc * 128 + nt * 16 + cb];
        }
        if (ACT == 1) {
            #pragma unroll
            for (int nt = 0; nt < 8; ++nt) v[nt] = fast_elu(v[nt]);
        }
        if (LN) {
            float s1 = 0.f, s2 = 0.f;
            #pragma unroll
            for (int nt = 0; nt < 8; ++nt) { s1 += v[nt]; s2 += v[nt] * v[nt]; }
            #pragma unroll
            for (int o = 8; o >= 1; o >>= 1) { s1 += __shfl_xor(s1, o); s2 += __shfl_xor(s2, o); }
            float mu = s1 * (1.f / 128.f);
            float rs = rsqrtf(s2 * (1.f / 128.f) - mu * mu + 1e-5f);
            #pragma unroll
            for (int nt = 0; nt < 8; ++nt) v[nt] = (v[nt] - mu) * rs * lg[nt] + lb[nt];
        }
        if (m < M) {
            #pragma unroll
            for (int nt = 0; nt < 8; ++nt) {
                size_t o = (size_t)m * 128 + nt * 16 + cb;
                if (OF32) outf[o] = v[nt];
                if (OB16) outb[o] = f2b(v[nt]);
            }
            if (OB8) *(uint2*)&outb8[(size_t)m * 128 + cb * 8] = pk8(v);
        }
    }
}

// ---------------- fused GEMM chain: W from L2 (frag order), ONE barrier -----
// __launch_bounds__(256,4): force total regs (VGPR+AGPR unified) <= 128 so
// 4 waves/SIMD fit (was 2 at 100 VGPR + 32 AGPR). y1 is NOT kept in regs:
// epilogue-1 stores it to Hl (bf16) and FF2 re-reads it from there (Hl is
// never overwritten after epilogue-1), saving the 32-VGPR y1r array.
__global__ __launch_bounds__(256, 4)
void gc_chain(const unsigned short* __restrict__ hin, const unsigned short* __restrict__ aggb,
              unsigned short* __restrict__ hout, unsigned char* __restrict__ h8out,
              const unsigned short* __restrict__ Wl_f, const unsigned short* __restrict__ Wr_f,
              const unsigned short* __restrict__ W1_f, const unsigned short* __restrict__ W2_f,
              const float* __restrict__ bl,
              const float* __restrict__ g1, const float* __restrict__ b1,
              const float* __restrict__ bb1, const float* __restrict__ bb2,
              const float* __restrict__ g2, const float* __restrict__ b2, int M) {
    __shared__ short Hl[64 * 136];     // h tile -> y1 tile (live through FF2)
    __shared__ short Gl[64 * 136];     // agg tile -> elu(t) tile

    const int t = threadIdx.x;
    const int lane = t & 63, wid = t >> 6;
    const int m0 = blockIdx.x * 64;
    const int cb = lane & 15, rq = lane >> 4;
    const int aoff_base = (wid * 16 + cb) * 136 + rq * 8;
    const int boff = lane * 8;

    for (int i = t; i < 1024; i += 256) {
        int row = i >> 4, seg = i & 15;
        int gr = m0 + row; if (gr >= M) gr = M - 1;
        *(uint4*)&Hl[row * 136 + seg * 8] = *(const uint4*)&hin[(size_t)gr * 128 + seg * 8];
        *(uint4*)&Gl[row * 136 + seg * 8] = *(const uint4*)&aggb[(size_t)gr * 128 + seg * 8];
    }
    __syncthreads();   // the only barrier

    f32x4 acc[8];
    #pragma unroll
    for (int nt = 0; nt < 8; ++nt) acc[nt] = (f32x4){0.f, 0.f, 0.f, 0.f};

    // ---- dual GEMM: acc = agg@Wl + h@Wr ----
    for (int kc = 0; kc < 4; ++kc) {
        short8 a0 = *(const short8*)&Gl[aoff_base + kc * 32];
        short8 a1 = *(const short8*)&Hl[aoff_base + kc * 32];
        #pragma unroll
        for (int nt = 0; nt < 8; ++nt) {
            const size_t wo = (size_t)(kc * 8 + nt) * 512 + boff;
            acc[nt] = __builtin_amdgcn_mfma_f32_16x16x32_bf16(a0, *(const short8*)&Wl_f[wo], acc[nt], 0, 0, 0);
            acc[nt] = __builtin_amdgcn_mfma_f32_16x16x32_bf16(a1, *(const short8*)&Wr_f[wo], acc[nt], 0, 0, 0);
        }
    }

    // ---- epilogue 1 (band-local): y1 = LN1(acc + bl + h) -> Hl ----
    {
        float bs[8], lg[8], lb[8];
        #pragma unroll
        for (int nt = 0; nt < 8; ++nt) {
            int col = nt * 16 + cb;
            bs[nt] = bl[col]; lg[nt] = g1[col]; lb[nt] = b1[col];
        }
        #pragma unroll
        for (int reg = 0; reg < 4; ++reg) {
            int r = wid * 16 + rq * 4 + reg;
            float v[8];
            float s1 = 0.f, s2 = 0.f;
            #pragma unroll
            for (int nt = 0; nt < 8; ++nt) {
                v[nt] = acc[nt][reg] + bs[nt] + us2f((unsigned short)Hl[r * 136 + nt * 16 + cb]);
                s1 += v[nt]; s2 += v[nt] * v[nt];
            }
            #pragma unroll
            for (int o = 8; o >= 1; o >>= 1) { s1 += __shfl_xor(s1, o); s2 += __shfl_xor(s2, o); }
            float mu = s1 * (1.f / 128.f);
            float rs = rsqrtf(s2 * (1.f / 128.f) - mu * mu + 1e-5f);
            #pragma unroll
            for (int nt = 0; nt < 8; ++nt) {
                float y = (v[nt] - mu) * rs * lg[nt] + lb[nt];
                Hl[r * 136 + nt * 16 + cb] = (short)f2b(y);
            }
        }
    }

    // ---- FF1 (band-local): t = elu(y1@W1 + bb1) -> Gl ----
    #pragma unroll
    for (int nt = 0; nt < 8; ++nt) acc[nt] = (f32x4){0.f, 0.f, 0.f, 0.f};
    for (int kc = 0; kc < 4; ++kc) {
        short8 a0 = *(const short8*)&Hl[aoff_base + kc * 32];
        #pragma unroll
        for (int nt = 0; nt < 8; ++nt)
            acc[nt] = __builtin_amdgcn_mfma_f32_16x16x32_bf16(
                a0, *(const short8*)&W1_f[(size_t)(kc * 8 + nt) * 512 + boff], acc[nt], 0, 0, 0);
    }
    {
        float bs[8];
        #pragma unroll
        for (int nt = 0; nt < 8; ++nt) bs[nt] = bb1[nt * 16 + cb];
        #pragma unroll
        for (int reg = 0; reg < 4; ++reg) {
            int r = wid * 16 + rq * 4 + reg;
            #pragma unroll
            for (int nt = 0; nt < 8; ++nt) {
                float v = fast_elu(acc[nt][reg] + bs[nt]);
                Gl[r * 136 + nt * 16 + cb] = (short)f2b(v);
            }
        }
    }

    // ---- FF2 (band-local): h' = LN2(t@W2 + bb2 + y1[from Hl]) -> global ----
    #pragma unroll
    for (int nt = 0; nt < 8; ++nt) acc[nt] = (f32x4){0.f, 0.f, 0.f, 0.f};
    for (int kc = 0; kc < 4; ++kc) {
        short8 a0 = *(const short8*)&Gl[aoff_base + kc * 32];
        #pragma unroll
        for (int nt = 0; nt < 8; ++nt)
            acc[nt] = __builtin_amdgcn_mfma_f32_16x16x32_bf16(
                a0, *(const short8*)&W2_f[(size_t)(kc * 8 + nt) * 512 + boff], acc[nt], 0, 0, 0);
    }
    {
        float bs[8], lg[8], lb[8];
        #pragma unroll
        for (int nt = 0; nt < 8; ++nt) {
            int col = nt * 16 + cb;
            bs[nt] = bb2[col]; lg[nt] = g2[col]; lb[nt] = b2[col];
        }
        #pragma unroll
        for (int reg = 0; reg < 4; ++reg) {
            int r = wid * 16 + rq * 4 + reg;
            int m = m0 + r;
            float v[8];
            float s1 = 0.f, s2 = 0.f;
            #pragma unroll
            for (int nt = 0; nt < 8; ++nt) {
                v[nt] = acc[nt][reg] + bs[nt] + us2f((unsigned short)Hl[r * 136 + nt * 16 + cb]);
                s1 += v[nt]; s2 += v[nt] * v[nt];
            }
            #pragma unroll
            for (int o = 8; o >= 1; o >>= 1) { s1 += __shfl_xor(s1, o); s2 += __shfl_xor(s2, o); }
            float mu = s1 * (1.f / 128.f);
            float rs = rsqrtf(s2 * (1.f / 128.f) - mu * mu + 1e-5f);
            if (m < M) {
                float fv[8];
                #pragma unroll
                for (int nt = 0; nt < 8; ++nt) {
                    fv[nt] = (v[nt] - mu) * rs * lg[nt] + lb[nt];
                    hout[(size_t)m * 128 + nt * 16 + cb] = f2b(fv[nt]);
                }
                *(uint2*)&h8out[(size_t)m * 128 + cb * 8] = pk8(fv);
            }
        }
    }
}

extern "C" void kernel_launch(void* const* d_in, const int* in_sizes, int n_in,
                              void* d_out, int out_size, void* d_ws, size_t ws_size,
                              hipStream_t stream) {
    const float* x      = (const float*)d_in[0];
    const float* w      = (const float*)d_in[1];
    const int*   ei     = (const int*)d_in[2];
    const int*   batch  = (const int*)d_in[3];
    const float* W_in   = (const float*)d_in[4];
    const float* b_in   = (const float*)d_in[5];
    const float* sage_Wl = (const float*)d_in[6];
    const float* sage_bl = (const float*)d_in[7];
    const float* sage_Wr = (const float*)d_in[8];
    const float* ln1_g  = (const float*)d_in[9];
    const float* ln1_b  = (const float*)d_in[10];
    const float* lin1_W = (const float*)d_in[11];
    const float* lin1_b = (const float*)d_in[12];
    const float* lin2_W = (const float*)d_in[13];
    const float* lin2_b = (const float*)d_in[14];
    const float* ln2_g  = (const float*)d_in[15];
    const float* ln2_b  = (const float*)d_in[16];
    const float* mdf_W  = (const float*)d_in[17];
    const float* mdf_b  = (const float*)d_in[18];
    const float* pln1_g = (const float*)d_in[19];
    const float* pln1_b = (const float*)d_in[20];
    const float* plin1_W = (const float*)d_in[21];
    const float* plin1_b = (const float*)d_in[22];
    const float* plin2_W = (const float*)d_in[23];
    const float* plin2_b = (const float*)d_in[24];
    const float* pln2_g = (const float*)d_in[25];
    const float* pln2_b = (const float*)d_in[26];
    float* out = (float*)d_out;

    const int* e_src = ei;
    const int* e_dst = ei + NE;

    // ---- workspace layout ----
    float* ws = (float*)d_ws;
    size_t off = 0;
    float* gm    = ws + off; off += (size_t)NG * FF;
    float* hh    = ws + off; off += (size_t)NG * FF;
    float* tt    = ws + off; off += (size_t)NG * FF;
    float* inv_deg = ws + off; off += NN;
    float* inv_cnt = ws + off; off += NG;
    unsigned short* us = (unsigned short*)(ws + off);
    size_t uoff = 0;
    unsigned short* hb0  = us + uoff; uoff += (size_t)NN * FF;
    unsigned short* hb1  = us + uoff; uoff += (size_t)NN * FF;
    unsigned short* aggb = us + uoff; uoff += (size_t)NN * FF;
    unsigned short* wt   = us + uoff; uoff += (size_t)16 * 16384;
    int* iw = (int*)(us + uoff);
    size_t ioff = 0;
    unsigned* pairs = (unsigned*)iw; ioff += (size_t)NBK * BCAP;
    int* ssrc    = iw + ioff; ioff += (size_t)NBK * BCAP;
    int* row_beg = iw + ioff; ioff += NN;
    int* row_end = iw + ioff; ioff += NN;
    int* g_off   = iw + ioff; ioff += NG + 1;
    int* bcur    = iw + ioff; ioff += NBK;
    // h8 (12.8 MB) aliases pairs (12.85 MB): pairs is dead after bucket_build,
    // h8 is first written by the input GEMM which runs after.
    unsigned char* h8 = (unsigned char*)pairs;

    // ---- weight prep (16 matrices -> frag-ordered bf16) ----
    WTab tab;
    tab.a[0] = W_in;
    for (int l = 0; l < 3; ++l) {
        tab.a[1 + l]  = sage_Wl + (size_t)l * 16384;
        tab.a[4 + l]  = sage_Wr + (size_t)l * 16384;
        tab.a[7 + l]  = lin1_W + (size_t)l * 16384;
        tab.a[10 + l] = lin2_W + (size_t)l * 16384;
    }
    tab.a[13] = mdf_W;      // first 128 rows only (Wa)
    tab.a[14] = plin1_W;
    tab.a[15] = plin2_W;
    prep_weights<<<16 * 64, 256, 0, stream>>>(tab, wt);
    const unsigned short* win_t = wt + 0 * 16384;
    const unsigned short* wa_t  = wt + 13 * 16384;
    const unsigned short* p1_t  = wt + 14 * 16384;
    const unsigned short* p2_t  = wt + 15 * 16384;

    // ---- build padded CSR (no histogram pass, no scan) ----
    init_bcur<<<1, 256, 0, stream>>>(bcur);
    graph_offsets<<<(NG + 256) / 256, 256, 0, stream>>>(batch, g_off, inv_cnt);
    radix_scatter<<<RB, 256, 0, stream>>>(e_src, e_dst, bcur, pairs, NE);
    bucket_build<<<NBK, 256, 0, stream>>>(pairs, bcur, row_beg, row_end, inv_deg, ssrc);

    const int GN = (NN + 63) / 64;     // 1563
    const int GB = NG / 64;            // 16

    // ---- input linear: hb0 (bf16) + h8 (fp8, permuted) ----
    gemm_mfma<false, true, 0, 0, false, false, true, true><<<GN, 256, 0, stream>>>(
        x, win_t, b_in, w, W_in + 128 * 128,
        nullptr, nullptr, nullptr, nullptr, hb0, h8, NN);

    // ---- 3 GC blocks: fp8 gather + fused GEMM chain ----
    unsigned short* hcur = hb0;
    unsigned short* hnxt = hb1;
    for (int l = 0; l < 3; ++l) {
        sage_agg<<<NN / 4, 256, 0, stream>>>(h8, row_beg, row_end, inv_deg, ssrc, aggb);
        gc_chain<<<GN, 256, 0, stream>>>(
            hcur, aggb, hnxt, h8,
            wt + (size_t)(1 + l) * 16384, wt + (size_t)(4 + l) * 16384,
            wt + (size_t)(7 + l) * 16384, wt + (size_t)(10 + l) * 16384,
            sage_bl + (size_t)l * FF,
            ln1_g + (size_t)l * FF, ln1_b + (size_t)l * FF,
            lin1_b + (size_t)l * FF, lin2_b + (size_t)l * FF,
            ln2_g + (size_t)l * FF, ln2_b + (size_t)l * FF, NN);
        unsigned short* tmp = hcur; hcur = hnxt; hnxt = tmp;
    }

    // ---- head: pool(h2) == gm @ mdf_W[0:128] + mdf_b  (exact algebra) ----
    pool_mean_b<<<NG, 128, 0, stream>>>(hcur, g_off, inv_cnt, gm);
    gemm_mfma<false, false, 0, 0, true, true, false, false><<<GB, 256, 0, stream>>>(
        gm, wa_t, mdf_b, nullptr, nullptr,
        nullptr, pln1_g, pln1_b, hh, nullptr, nullptr, NG);
    gemm_mfma<false, false, 0, 1, false, true, false, false><<<GB, 256, 0, stream>>>(
        hh, p1_t, plin1_b, nullptr, nullptr,
        nullptr, nullptr, nullptr, tt, nullptr, nullptr, NG);
    gemm_mfma<false, false, 1, 0, true, true, false, false><<<GB, 256, 0, stream>>>(
        tt, p2_t, plin2_b, nullptr, nullptr,
        hh, pln2_g, pln2_b, out, nullptr, nullptr, NG);
}

// Round 7
// 568.245 us; speedup vs baseline: 1.2952x; 1.0979x over previous
//
#include <hip/hip_runtime.h>
#include <math.h>

#define NN 100000
#define NE 1600000
#define NG 1024
#define FF 128
#define BSH 9
#define NBK ((NN + 511) >> BSH)   // 196 buckets of 512 nodes
#define RB 256                    // radix blocks
#define BCAP 16384                // fixed bucket capacity (mean 8192, sigma~90)
#define NPB 256                   // persistent blocks for gc_chain (1/CU)
#define GC_LDS ((4 * 16384 + 64 * 136) * 2)   // 148480 B: W[4] + tile

typedef __attribute__((ext_vector_type(8))) short short8;
typedef __attribute__((ext_vector_type(4))) float f32x4;
typedef __attribute__((ext_vector_type(2))) float f32x2;

__device__ __forceinline__ unsigned short f2b(float f) {
    union { float f; unsigned u; } v; v.f = f;
    unsigned r = (v.u + 0x7FFF + ((v.u >> 16) & 1)) >> 16;
    return (unsigned short)r;
}
__device__ __forceinline__ float us2f(unsigned short u) {
    union { unsigned u; float f; } v; v.u = ((unsigned)u) << 16; return v.f;
}
// hardware ELU: v_exp_f32 is 2^x; elu(v)=v>0?v:2^(v*log2e)-1.
__device__ __forceinline__ float fast_elu(float v) {
    float e = __builtin_amdgcn_exp2f(v * 1.44269504088896340736f) - 1.0f;
    return v > 0.f ? v : e;
}
// pack 8 floats -> 8 fp8 (uint2), byte i = v[i]
__device__ __forceinline__ uint2 pk8(const float* v) {
    unsigned lo = 0, hi = 0;
    lo = (unsigned)__builtin_amdgcn_cvt_pk_fp8_f32(v[0], v[1], (int)lo, false);
    lo = (unsigned)__builtin_amdgcn_cvt_pk_fp8_f32(v[2], v[3], (int)lo, true);
    hi = (unsigned)__builtin_amdgcn_cvt_pk_fp8_f32(v[4], v[5], (int)hi, false);
    hi = (unsigned)__builtin_amdgcn_cvt_pk_fp8_f32(v[6], v[7], (int)hi, true);
    uint2 r; r.x = lo; r.y = hi; return r;
}
#define MFMA(a, b, c) __builtin_amdgcn_mfma_f32_16x16x32_bf16((a), (b), (c), 0, 0, 0)

// ---------------- init bucket cursors to region bases -----------------------
__global__ void init_bcur(int* __restrict__ bcur) {
    int b = blockIdx.x * blockDim.x + threadIdx.x;
    if (b < NBK) bcur[b] = b * BCAP;
}

// ---------------- pass 1: scatter packed (src<<9|local) into padded buckets -
__global__ __launch_bounds__(256)
void radix_scatter(const int* __restrict__ src, const int* __restrict__ dst,
                   int* __restrict__ bcur, unsigned* __restrict__ pairs, int n) {
    __shared__ int base[NBK];
    __shared__ int cnt[NBK];
    for (int i = threadIdx.x; i < NBK; i += 256) cnt[i] = 0;
    __syncthreads();
    const int per = (n + RB - 1) / RB;
    const int beg = blockIdx.x * per;
    const int end = min(n, beg + per);
    for (int i = beg + threadIdx.x; i < end; i += 256)
        atomicAdd(&cnt[dst[i] >> BSH], 1);
    __syncthreads();
    for (int i = threadIdx.x; i < NBK; i += 256)
        base[i] = cnt[i] ? atomicAdd(&bcur[i], cnt[i]) : 0;
    __syncthreads();
    for (int i = beg + threadIdx.x; i < end; i += 256) {
        int d = dst[i];
        int p = atomicAdd(&base[d >> BSH], 1);
        pairs[p] = ((unsigned)src[i] << BSH) | (unsigned)(d & 511);
    }
}

// ---------------- pass 2: per-bucket hist+scan+scatter -> padded CSR --------
// ssrc stores PRE-SCALED byte offsets (src*128) for sage_agg's gathers.
__global__ __launch_bounds__(256)
void bucket_build(const unsigned* __restrict__ pairs, const int* __restrict__ bcur,
                  int* __restrict__ row_beg, int* __restrict__ row_end,
                  float* __restrict__ inv_deg, int* __restrict__ ssrc) {
    __shared__ int cnt[512];
    __shared__ int curs[512];
    __shared__ int wsum[4];
    const int b = blockIdx.x;
    const int n0 = b << BSH;
    const int t = threadIdx.x;
    const int lane = t & 63, wid = t >> 6;

    for (int i = t; i < 512; i += 256) cnt[i] = 0;
    __syncthreads();
    const int beg = b * BCAP, end = bcur[b];
    for (int i = beg + t; i < end; i += 256)
        atomicAdd(&cnt[pairs[i] & 511], 1);
    __syncthreads();

    int c0 = cnt[2 * t], c1 = cnt[2 * t + 1];
    int v = c0 + c1;
    int x = v;
    #pragma unroll
    for (int o = 1; o < 64; o <<= 1) {
        int y = __shfl_up(x, o);
        if (lane >= o) x += y;
    }
    if (lane == 63) wsum[wid] = x;
    __syncthreads();
    if (t == 0) {
        int s = 0;
        #pragma unroll
        for (int w2 = 0; w2 < 4; ++w2) { int tv = wsum[w2]; wsum[w2] = s; s += tv; }
    }
    __syncthreads();
    int g0 = beg + wsum[wid] + x - v;
    int g1 = g0 + c0;
    curs[2 * t] = g0;
    curs[2 * t + 1] = g1;
    {
        int node = n0 + 2 * t;
        if (node < NN) {
            row_beg[node] = g0; row_end[node] = g1;
            inv_deg[node] = 1.0f / (float)(c0 > 1 ? c0 : 1);
        }
        node = n0 + 2 * t + 1;
        if (node < NN) {
            row_beg[node] = g1; row_end[node] = g1 + c1;
            inv_deg[node] = 1.0f / (float)(c1 > 1 ? c1 : 1);
        }
    }
    __syncthreads();
    for (int i = beg + t; i < end; i += 256) {
        unsigned pr = pairs[i];
        int p = atomicAdd(&curs[pr & 511], 1);
        ssrc[p] = (int)(pr >> BSH) << 7;   // pre-scaled byte offset (row*128)
    }
}

// ---------------- graph offsets via binary search on sorted batch -----------
__global__ __launch_bounds__(256)
void graph_offsets(const int* __restrict__ batch, int* __restrict__ g_off,
                   float* __restrict__ inv_cnt) {
    int g = blockIdx.x * blockDim.x + threadIdx.x;
    if (g > NG) return;
    if (g == NG) { g_off[NG] = NN; return; }
    int lo = 0, hi = NN;
    while (lo < hi) { int mid = (lo + hi) >> 1; if (batch[mid] < g) lo = mid + 1; else hi = mid; }
    int lo2 = lo, hi2 = NN;
    while (lo2 < hi2) { int mid = (lo2 + hi2) >> 1; if (batch[mid] < g + 1) lo2 = mid + 1; else hi2 = mid; }
    g_off[g] = lo;
    int c = lo2 - lo;
    inv_cnt[g] = 1.0f / (float)(c > 1 ? c : 1);
}

// ---------------- weight prep: fp32 [k][n] -> bf16 MFMA-FRAGMENT order ------
struct WTab { const float* a[16]; };
__global__ __launch_bounds__(256)
void prep_weights(WTab tab, unsigned short* __restrict__ dst) {
    int w = blockIdx.x >> 6;
    int idx = ((blockIdx.x & 63) << 8) + threadIdx.x;
    int j = idx & 7, lane = (idx >> 3) & 63, nt = (idx >> 9) & 7, kc = idx >> 12;
    int cb = lane & 15, rq = lane >> 4;
    int k = kc * 32 + rq * 8 + j;
    int n = nt * 16 + cb;
    dst[(size_t)w * 16384 + idx] = f2b(tab.a[w][k * 128 + n]);
}

// ---------------- SAGE mean aggregation from fp8 shadow (permuted rows) -----
// Predicated batch-of-8 (R3-measured config).
__global__ __launch_bounds__(256)
void sage_agg(const unsigned char* __restrict__ h8, const int* __restrict__ row_beg,
              const int* __restrict__ row_end, const float* __restrict__ inv_deg,
              const int* __restrict__ ssrc, unsigned short* __restrict__ aggb) {
    const int wid = threadIdx.x >> 6;
    const int lane = threadIdx.x & 63;
    const int node = blockIdx.x * 4 + wid;
    const int eg = lane >> 4, j = lane & 15;
    const int jo = j * 8;
    const int beg = row_beg[node], end = row_end[node];
    f32x2 a0 = {0.f, 0.f}, a1 = {0.f, 0.f}, a2 = {0.f, 0.f}, a3 = {0.f, 0.f};
    for (int e = beg + eg; e < end; e += 32) {
        uint2 u[8];
        #pragma unroll
        for (int k = 0; k < 8; ++k) {
            int ek = e + 4 * k;
            bool ok = ek < end;
            int idx = ssrc[ok ? ek : e];                       // e always < end
            uint2 uu = *(const uint2*)(h8 + (unsigned)(idx + jo));
            uu.x = ok ? uu.x : 0u;
            uu.y = ok ? uu.y : 0u;                             // fp8 0x00 -> 0.0f
            u[k] = uu;
        }
        #pragma unroll
        for (int k = 0; k < 8; ++k) {
            a0 += __builtin_amdgcn_cvt_pk_f32_fp8(u[k].x, false);
            a1 += __builtin_amdgcn_cvt_pk_f32_fp8(u[k].x, true);
            a2 += __builtin_amdgcn_cvt_pk_f32_fp8(u[k].y, false);
            a3 += __builtin_amdgcn_cvt_pk_f32_fp8(u[k].y, true);
        }
    }
    float af[8] = {a0.x, a0.y, a1.x, a1.y, a2.x, a2.y, a3.x, a3.y};
    #pragma unroll
    for (int k = 0; k < 8; ++k) {
        af[k] += __shfl_xor(af[k], 16);
        af[k] += __shfl_xor(af[k], 32);
    }
    if (eg == 0) {
        float id = inv_deg[node];
        #pragma unroll
        for (int nt = 0; nt < 8; ++nt)
            aggb[(size_t)node * 128 + nt * 16 + j] = f2b(af[nt] * id);
    }
}

// ---------------- mean pool per graph from bf16 ----------------
__global__ __launch_bounds__(128)
void pool_mean_b(const unsigned short* __restrict__ src, const int* __restrict__ g_off,
                 const float* __restrict__ inv_cnt, float* __restrict__ out) {
    const int g = blockIdx.x;
    const int j = threadIdx.x;
    const int beg = g_off[g], end = g_off[g + 1];
    float s = 0.f;
    for (int n = beg; n < end; ++n) s += us2f(src[(size_t)n * FF + j]);
    out[(size_t)g * FF + j] = s * inv_cnt[g];
}

// ---------------- MFMA bf16 GEMM, frag-ordered W from global (L2) ----------
template<bool AB16, bool R1, int RESM, int ACT, bool LN, bool OF32, bool OB16, bool OB8>
__global__ __launch_bounds__(256)
void gemm_mfma(const void* __restrict__ A_,
               const unsigned short* __restrict__ Wf,
               const float* __restrict__ bias,
               const float* __restrict__ rvec, const float* __restrict__ rrow,
               const float* __restrict__ res,
               const float* __restrict__ lng, const float* __restrict__ lnb,
               float* __restrict__ outf, unsigned short* __restrict__ outb,
               unsigned char* __restrict__ outb8, int M) {
    __shared__ short Al[64 * 136];

    const int t = threadIdx.x;
    const int lane = t & 63, wid = t >> 6;
    const int m0 = blockIdx.x * 64;
    const int cb = lane & 15, rq = lane >> 4;

    if (AB16) {
        const unsigned short* Ab = (const unsigned short*)A_;
        for (int i = t; i < 1024; i += 256) {
            int row = i >> 4, seg = i & 15;
            int gr = m0 + row; if (gr >= M) gr = M - 1;
            *(uint4*)&Al[row * 136 + seg * 8] = *(const uint4*)&Ab[(size_t)gr * 128 + seg * 8];
        }
    } else {
        const float* Af = (const float*)A_;
        for (int i = t; i < 2048; i += 256) {
            int row = i >> 5, seg = i & 31;
            int gr = m0 + row; if (gr >= M) gr = M - 1;
            float4 v = *(const float4*)&Af[(size_t)gr * 128 + seg * 4];
            ushort4 o = {f2b(v.x), f2b(v.y), f2b(v.z), f2b(v.w)};
            *(ushort4*)&Al[row * 136 + seg * 4] = o;
        }
    }
    __syncthreads();

    f32x4 acc[8];
    #pragma unroll
    for (int nt = 0; nt < 8; ++nt) acc[nt] = (f32x4){0.f, 0.f, 0.f, 0.f};

    const int aoff_base = (wid * 16 + cb) * 136 + rq * 8;
    for (int kc = 0; kc < 4; ++kc) {
        short8 a0 = *(const short8*)&Al[aoff_base + kc * 32];
        #pragma unroll
        for (int nt = 0; nt < 8; ++nt) {
            short8 b0 = *(const short8*)&Wf[(size_t)(kc * 8 + nt) * 512 + lane * 8];
            acc[nt] = MFMA(a0, b0, acc[nt]);
        }
    }

    float bs[8], rr[8], lg[8], lb[8];
    #pragma unroll
    for (int nt = 0; nt < 8; ++nt) {
        int col = nt * 16 + cb;
        bs[nt] = bias[col];
        if (R1) rr[nt] = rrow[col];
        if (LN) { lg[nt] = lng[col]; lb[nt] = lnb[col]; }
    }
    #pragma unroll
    for (int reg = 0; reg < 4; ++reg) {
        int m = m0 + wid * 16 + rq * 4 + reg;
        int mc = m < M ? m : M - 1;
        float v[8];
        #pragma unroll
        for (int nt = 0; nt < 8; ++nt) v[nt] = acc[nt][reg] + bs[nt];
        if (R1) {
            float rv = rvec[mc];
            #pragma unroll
            for (int nt = 0; nt < 8; ++nt) v[nt] += rv * rr[nt];
        }
        if (RESM == 1) {
            #pragma unroll
            for (int nt = 0; nt < 8; ++nt) v[nt] += res[(size_t)mc * 128 + nt * 16 + cb];
        }
        if (ACT == 1) {
            #pragma unroll
            for (int nt = 0; nt < 8; ++nt) v[nt] = fast_elu(v[nt]);
        }
        if (LN) {
            float s1 = 0.f, s2 = 0.f;
            #pragma unroll
            for (int nt = 0; nt < 8; ++nt) { s1 += v[nt]; s2 += v[nt] * v[nt]; }
            #pragma unroll
            for (int o = 8; o >= 1; o >>= 1) { s1 += __shfl_xor(s1, o); s2 += __shfl_xor(s2, o); }
            float mu = s1 * (1.f / 128.f);
            float rs = rsqrtf(s2 * (1.f / 128.f) - mu * mu + 1e-5f);
            #pragma unroll
            for (int nt = 0; nt < 8; ++nt) v[nt] = (v[nt] - mu) * rs * lg[nt] + lb[nt];
        }
        if (m < M) {
            #pragma unroll
            for (int nt = 0; nt < 8; ++nt) {
                size_t o = (size_t)m * 128 + nt * 16 + cb;
                if (OF32) outf[o] = v[nt];
                if (OB16) outb[o] = f2b(v[nt]);
            }
            if (OB8) *(uint2*)&outb8[(size_t)m * 128 + cb * 8] = pk8(v);
        }
    }
}

// ---------------- PERSISTENT fused GEMM chain: W resident in LDS ------------
// 256 blocks (1/CU, 145 KB LDS). Each block stages all 4 W matrices into LDS
// ONCE, then grid-strides over 64-row tiles. All tile-loop LDS traffic is
// band-local per wave (each wave owns its 16 rows end-to-end), so the loop
// has ZERO barriers — the only __syncthreads covers the W staging. h/agg
// A-fragments load straight from global into registers; the 17 KB tile
// buffer Tl serves only the residual read and the y1/t layout transposes.
// Next tile's fragments prefetch right after the dual GEMM consumes them.
__global__ __launch_bounds__(256, 1)
void gc_chain(const unsigned short* __restrict__ hin, const unsigned short* __restrict__ aggb,
              unsigned short* __restrict__ hout, unsigned char* __restrict__ h8out,
              const unsigned short* __restrict__ Wl_f, const unsigned short* __restrict__ Wr_f,
              const unsigned short* __restrict__ W1_f, const unsigned short* __restrict__ W2_f,
              const float* __restrict__ bl,
              const float* __restrict__ g1, const float* __restrict__ b1,
              const float* __restrict__ bb1, const float* __restrict__ bb2,
              const float* __restrict__ g2, const float* __restrict__ b2,
              int M, int ntiles) {
    extern __shared__ short smem[];
    short* Wlds = smem;               // 4 * 16384 shorts = 128 KB
    short* Tl   = smem + 65536;       // 64 * 136 shorts  = 17 KB

    const int t = threadIdx.x;
    const int lane = t & 63, wid = t >> 6;
    const int cb = lane & 15, rq = lane >> 4;
    const int band = wid * 16;
    const int aoff_base = (band + cb) * 136 + rq * 8;
    const int boff = lane * 8;
    const int fcol = rq * 8;          // fragment column base within a kc chunk

    // ---- stage all 4 W matrices into LDS (once per block) ----
    {
        uint4* dst = (uint4*)Wlds;
        const uint4* s0 = (const uint4*)Wl_f;
        const uint4* s1 = (const uint4*)Wr_f;
        const uint4* s2 = (const uint4*)W1_f;
        const uint4* s3 = (const uint4*)W2_f;
        for (int i = t; i < 2048; i += 256) {
            dst[i]        = s0[i];
            dst[2048 + i] = s1[i];
            dst[4096 + i] = s2[i];
            dst[6144 + i] = s3[i];
        }
    }
    __syncthreads();   // the ONLY barrier

    const short* WL  = Wlds;
    const short* WR  = Wlds + 16384;
    const short* W1m = Wlds + 32768;
    const short* W2m = Wlds + 49152;

    int tile = blockIdx.x;
    short8 hp[4], gp[4];
    {   // prefetch tile 0 fragments
        int gr = tile * 64 + band + cb; if (gr >= M) gr = M - 1;
        const unsigned short* hrow = hin  + (size_t)gr * 128 + fcol;
        const unsigned short* grow = aggb + (size_t)gr * 128 + fcol;
        #pragma unroll
        for (int kc = 0; kc < 4; ++kc) {
            hp[kc] = *(const short8*)(hrow + kc * 32);
            gp[kc] = *(const short8*)(grow + kc * 32);
        }
    }

    for (; tile < ntiles; tile += NPB) {
        const int m0 = tile * 64;

        // own-band h copy into Tl (residual source for epi1)
        #pragma unroll
        for (int kc = 0; kc < 4; ++kc)
            *(short8*)&Tl[aoff_base + kc * 32] = hp[kc];

        // ---- dual GEMM: acc = agg@Wl + h@Wr (W from LDS) ----
        f32x4 acc[8];
        #pragma unroll
        for (int nt = 0; nt < 8; ++nt) acc[nt] = (f32x4){0.f, 0.f, 0.f, 0.f};
        #pragma unroll
        for (int kc = 0; kc < 4; ++kc) {
            #pragma unroll
            for (int nt = 0; nt < 8; ++nt) {
                const int wo = (kc * 8 + nt) * 512 + boff;
                acc[nt] = MFMA(gp[kc], *(const short8*)&WL[wo], acc[nt]);
                acc[nt] = MFMA(hp[kc], *(const short8*)&WR[wo], acc[nt]);
            }
        }

        // ---- prefetch next tile's fragments (hp/gp dead after dual GEMM) --
        {
            int tn = tile + NPB;
            if (tn < ntiles) {
                int gr = tn * 64 + band + cb; if (gr >= M) gr = M - 1;
                const unsigned short* hrow = hin  + (size_t)gr * 128 + fcol;
                const unsigned short* grow = aggb + (size_t)gr * 128 + fcol;
                #pragma unroll
                for (int kc = 0; kc < 4; ++kc) {
                    hp[kc] = *(const short8*)(hrow + kc * 32);
                    gp[kc] = *(const short8*)(grow + kc * 32);
                }
            }
        }

        // ---- epi1 (band-local): y1 = LN1(acc + bl + h[Tl]) -> y1r + Tl ----
        float y1r[4][8];
        {
            float bs[8], lg[8], lb[8];
            #pragma unroll
            for (int nt = 0; nt < 8; ++nt) {
                int col = nt * 16 + cb;
                bs[nt] = bl[col]; lg[nt] = g1[col]; lb[nt] = b1[col];
            }
            #pragma unroll
            for (int reg = 0; reg < 4; ++reg) {
                int r = band + rq * 4 + reg;
                float v[8];
                float s1 = 0.f, s2 = 0.f;
                #pragma unroll
                for (int nt = 0; nt < 8; ++nt) {
                    v[nt] = acc[nt][reg] + bs[nt] + us2f((unsigned short)Tl[r * 136 + nt * 16 + cb]);
                    s1 += v[nt]; s2 += v[nt] * v[nt];
                }
                #pragma unroll
                for (int o = 8; o >= 1; o >>= 1) { s1 += __shfl_xor(s1, o); s2 += __shfl_xor(s2, o); }
                float mu = s1 * (1.f / 128.f);
                float rs = rsqrtf(s2 * (1.f / 128.f) - mu * mu + 1e-5f);
                #pragma unroll
                for (int nt = 0; nt < 8; ++nt) {
                    float y = (v[nt] - mu) * rs * lg[nt] + lb[nt];
                    y1r[reg][nt] = y;
                    Tl[r * 136 + nt * 16 + cb] = (short)f2b(y);
                }
            }
        }

        // ---- FF1 (band-local): t = elu(y1@W1 + bb1) -> Tl ----
        #pragma unroll
        for (int nt = 0; nt < 8; ++nt) acc[nt] = (f32x4){0.f, 0.f, 0.f, 0.f};
        #pragma unroll
        for (int kc = 0; kc < 4; ++kc) {
            short8 a0 = *(const short8*)&Tl[aoff_base + kc * 32];
            #pragma unroll
            for (int nt = 0; nt < 8; ++nt)
                acc[nt] = MFMA(a0, *(const short8*)&W1m[(kc * 8 + nt) * 512 + boff], acc[nt]);
        }
        {
            float bs[8];
            #pragma unroll
            for (int nt = 0; nt < 8; ++nt) bs[nt] = bb1[nt * 16 + cb];
            #pragma unroll
            for (int reg = 0; reg < 4; ++reg) {
                int r = band + rq * 4 + reg;
                #pragma unroll
                for (int nt = 0; nt < 8; ++nt) {
                    float v = fast_elu(acc[nt][reg] + bs[nt]);
                    Tl[r * 136 + nt * 16 + cb] = (short)f2b(v);
                }
            }
        }

        // ---- FF2 (band-local): h' = LN2(t@W2 + bb2 + y1r) -> global ----
        #pragma unroll
        for (int nt = 0; nt < 8; ++nt) acc[nt] = (f32x4){0.f, 0.f, 0.f, 0.f};
        #pragma unroll
        for (int kc = 0; kc < 4; ++kc) {
            short8 a0 = *(const short8*)&Tl[aoff_base + kc * 32];
            #pragma unroll
            for (int nt = 0; nt < 8; ++nt)
                acc[nt] = MFMA(a0, *(const short8*)&W2m[(kc * 8 + nt) * 512 + boff], acc[nt]);
        }
        {
            float bs[8], lg[8], lb[8];
            #pragma unroll
            for (int nt = 0; nt < 8; ++nt) {
                int col = nt * 16 + cb;
                bs[nt] = bb2[col]; lg[nt] = g2[col]; lb[nt] = b2[col];
            }
            #pragma unroll
            for (int reg = 0; reg < 4; ++reg) {
                int r = band + rq * 4 + reg;
                int m = m0 + r;
                float v[8];
                float s1 = 0.f, s2 = 0.f;
                #pragma unroll
                for (int nt = 0; nt < 8; ++nt) {
                    v[nt] = acc[nt][reg] + bs[nt] + y1r[reg][nt];
                    s1 += v[nt]; s2 += v[nt] * v[nt];
                }
                #pragma unroll
                for (int o = 8; o >= 1; o >>= 1) { s1 += __shfl_xor(s1, o); s2 += __shfl_xor(s2, o); }
                float mu = s1 * (1.f / 128.f);
                float rs = rsqrtf(s2 * (1.f / 128.f) - mu * mu + 1e-5f);
                if (m < M) {
                    float fv[8];
                    #pragma unroll
                    for (int nt = 0; nt < 8; ++nt) {
                        fv[nt] = (v[nt] - mu) * rs * lg[nt] + lb[nt];
                        hout[(size_t)m * 128 + nt * 16 + cb] = f2b(fv[nt]);
                    }
                    *(uint2*)&h8out[(size_t)m * 128 + cb * 8] = pk8(fv);
                }
            }
        }
    }
}

extern "C" void kernel_launch(void* const* d_in, const int* in_sizes, int n_in,
                              void* d_out, int out_size, void* d_ws, size_t ws_size,
                              hipStream_t stream) {
    const float* x      = (const float*)d_in[0];
    const float* w      = (const float*)d_in[1];
    const int*   ei     = (const int*)d_in[2];
    const int*   batch  = (const int*)d_in[3];
    const float* W_in   = (const float*)d_in[4];
    const float* b_in   = (const float*)d_in[5];
    const float* sage_Wl = (const float*)d_in[6];
    const float* sage_bl = (const float*)d_in[7];
    const float* sage_Wr = (const float*)d_in[8];
    const float* ln1_g  = (const float*)d_in[9];
    const float* ln1_b  = (const float*)d_in[10];
    const float* lin1_W = (const float*)d_in[11];
    const float* lin1_b = (const float*)d_in[12];
    const float* lin2_W = (const float*)d_in[13];
    const float* lin2_b = (const float*)d_in[14];
    const float* ln2_g  = (const float*)d_in[15];
    const float* ln2_b  = (const float*)d_in[16];
    const float* mdf_W  = (const float*)d_in[17];
    const float* mdf_b  = (const float*)d_in[18];
    const float* pln1_g = (const float*)d_in[19];
    const float* pln1_b = (const float*)d_in[20];
    const float* plin1_W = (const float*)d_in[21];
    const float* plin1_b = (const float*)d_in[22];
    const float* plin2_W = (const float*)d_in[23];
    const float* plin2_b = (const float*)d_in[24];
    const float* pln2_g = (const float*)d_in[25];
    const float* pln2_b = (const float*)d_in[26];
    float* out = (float*)d_out;

    const int* e_src = ei;
    const int* e_dst = ei + NE;

    // allow >64KB dynamic LDS for gc_chain (metadata-only host call)
    static bool attr_set = false;
    if (!attr_set) {
        (void)hipFuncSetAttribute(reinterpret_cast<const void*>(gc_chain),
                                  hipFuncAttributeMaxDynamicSharedMemorySize, GC_LDS);
        attr_set = true;
    }

    // ---- workspace layout ----
    float* ws = (float*)d_ws;
    size_t off = 0;
    float* gm    = ws + off; off += (size_t)NG * FF;
    float* hh    = ws + off; off += (size_t)NG * FF;
    float* tt    = ws + off; off += (size_t)NG * FF;
    float* inv_deg = ws + off; off += NN;
    float* inv_cnt = ws + off; off += NG;
    unsigned short* us = (unsigned short*)(ws + off);
    size_t uoff = 0;
    unsigned short* hb0  = us + uoff; uoff += (size_t)NN * FF;
    unsigned short* hb1  = us + uoff; uoff += (size_t)NN * FF;
    unsigned short* aggb = us + uoff; uoff += (size_t)NN * FF;
    unsigned short* wt   = us + uoff; uoff += (size_t)16 * 16384;
    int* iw = (int*)(us + uoff);
    size_t ioff = 0;
    unsigned* pairs = (unsigned*)iw; ioff += (size_t)NBK * BCAP;
    int* ssrc    = iw + ioff; ioff += (size_t)NBK * BCAP;
    int* row_beg = iw + ioff; ioff += NN;
    int* row_end = iw + ioff; ioff += NN;
    int* g_off   = iw + ioff; ioff += NG + 1;
    int* bcur    = iw + ioff; ioff += NBK;
    // h8 (12.8 MB) aliases pairs (12.85 MB): pairs is dead after bucket_build,
    // h8 is first written by the input GEMM which runs after.
    unsigned char* h8 = (unsigned char*)pairs;

    // ---- weight prep (16 matrices -> frag-ordered bf16) ----
    WTab tab;
    tab.a[0] = W_in;
    for (int l = 0; l < 3; ++l) {
        tab.a[1 + l]  = sage_Wl + (size_t)l * 16384;
        tab.a[4 + l]  = sage_Wr + (size_t)l * 16384;
        tab.a[7 + l]  = lin1_W + (size_t)l * 16384;
        tab.a[10 + l] = lin2_W + (size_t)l * 16384;
    }
    tab.a[13] = mdf_W;      // first 128 rows only (Wa)
    tab.a[14] = plin1_W;
    tab.a[15] = plin2_W;
    prep_weights<<<16 * 64, 256, 0, stream>>>(tab, wt);
    const unsigned short* win_t = wt + 0 * 16384;
    const unsigned short* wa_t  = wt + 13 * 16384;
    const unsigned short* p1_t  = wt + 14 * 16384;
    const unsigned short* p2_t  = wt + 15 * 16384;

    // ---- build padded CSR (no histogram pass, no scan) ----
    init_bcur<<<1, 256, 0, stream>>>(bcur);
    graph_offsets<<<(NG + 256) / 256, 256, 0, stream>>>(batch, g_off, inv_cnt);
    radix_scatter<<<RB, 256, 0, stream>>>(e_src, e_dst, bcur, pairs, NE);
    bucket_build<<<NBK, 256, 0, stream>>>(pairs, bcur, row_beg, row_end, inv_deg, ssrc);

    const int GN = (NN + 63) / 64;     // 1563
    const int GB = NG / 64;            // 16

    // ---- input linear: hb0 (bf16) + h8 (fp8, permuted) ----
    gemm_mfma<false, true, 0, 0, false, false, true, true><<<GN, 256, 0, stream>>>(
        x, win_t, b_in, w, W_in + 128 * 128,
        nullptr, nullptr, nullptr, nullptr, hb0, h8, NN);

    // ---- 3 GC blocks: fp8 gather + persistent fused GEMM chain ----
    unsigned short* hcur = hb0;
    unsigned short* hnxt = hb1;
    for (int l = 0; l < 3; ++l) {
        sage_agg<<<NN / 4, 256, 0, stream>>>(h8, row_beg, row_end, inv_deg, ssrc, aggb);
        gc_chain<<<NPB, 256, GC_LDS, stream>>>(
            hcur, aggb, hnxt, h8,
            wt + (size_t)(1 + l) * 16384, wt + (size_t)(4 + l) * 16384,
            wt + (size_t)(7 + l) * 16384, wt + (size_t)(10 + l) * 16384,
            sage_bl + (size_t)l * FF,
            ln1_g + (size_t)l * FF, ln1_b + (size_t)l * FF,
            lin1_b + (size_t)l * FF, lin2_b + (size_t)l * FF,
            ln2_g + (size_t)l * FF, ln2_b + (size_t)l * FF, NN, GN);
        unsigned short* tmp = hcur; hcur = hnxt; hnxt = tmp;
    }

    // ---- head: pool(h2) == gm @ mdf_W[0:128] + mdf_b  (exact algebra) ----
    pool_mean_b<<<NG, 128, 0, stream>>>(hcur, g_off, inv_cnt, gm);
    gemm_mfma<false, false, 0, 0, true, true, false, false><<<GB, 256, 0, stream>>>(
        gm, wa_t, mdf_b, nullptr, nullptr,
        nullptr, pln1_g, pln1_b, hh, nullptr, nullptr, NG);
    gemm_mfma<false, false, 0, 1, false, true, false, false><<<GB, 256, 0, stream>>>(
        hh, p1_t, plin1_b, nullptr, nullptr,
        nullptr, nullptr, nullptr, tt, nullptr, nullptr, NG);
    gemm_mfma<false, false, 1, 0, true, true, false, false><<<GB, 256, 0, stream>>>(
        tt, p2_t, plin2_b, nullptr, nullptr,
        hh, pln2_g, pln2_b, out, nullptr, nullptr, NG);
}

// Round 8
// 541.334 us; speedup vs baseline: 1.3595x; 1.0497x over previous
//
#include <hip/hip_runtime.h>
#include <math.h>

#define NN 100000
#define NE 1600000
#define NG 1024
#define FF 128
#define BSH 9
#define NBK ((NN + 511) >> BSH)   // 196 buckets of 512 nodes
#define RB 256                    // radix blocks
#define BCAP 16384                // fixed bucket capacity (mean 8192, sigma~90)

typedef __attribute__((ext_vector_type(8))) short short8;
typedef __attribute__((ext_vector_type(4))) float f32x4;
typedef __attribute__((ext_vector_type(2))) float f32x2;

__device__ __forceinline__ unsigned short f2b(float f) {
    union { float f; unsigned u; } v; v.f = f;
    unsigned r = (v.u + 0x7FFF + ((v.u >> 16) & 1)) >> 16;
    return (unsigned short)r;
}
__device__ __forceinline__ float us2f(unsigned short u) {
    union { unsigned u; float f; } v; v.u = ((unsigned)u) << 16; return v.f;
}
// hardware ELU: v_exp_f32 is 2^x; elu(v)=v>0?v:2^(v*log2e)-1.
__device__ __forceinline__ float fast_elu(float v) {
    float e = __builtin_amdgcn_exp2f(v * 1.44269504088896340736f) - 1.0f;
    return v > 0.f ? v : e;
}
// pack 8 floats -> 8 fp8 (uint2), byte i = v[i]
__device__ __forceinline__ uint2 pk8(const float* v) {
    unsigned lo = 0, hi = 0;
    lo = (unsigned)__builtin_amdgcn_cvt_pk_fp8_f32(v[0], v[1], (int)lo, false);
    lo = (unsigned)__builtin_amdgcn_cvt_pk_fp8_f32(v[2], v[3], (int)lo, true);
    hi = (unsigned)__builtin_amdgcn_cvt_pk_fp8_f32(v[4], v[5], (int)hi, false);
    hi = (unsigned)__builtin_amdgcn_cvt_pk_fp8_f32(v[6], v[7], (int)hi, true);
    uint2 r; r.x = lo; r.y = hi; return r;
}
#define MFMA(a, b, c) __builtin_amdgcn_mfma_f32_16x16x32_bf16((a), (b), (c), 0, 0, 0)

// ---------------- init bucket cursors to region bases -----------------------
__global__ void init_bcur(int* __restrict__ bcur) {
    int b = blockIdx.x * blockDim.x + threadIdx.x;
    if (b < NBK) bcur[b] = b * BCAP;
}

// ---------------- pass 1: scatter packed (src<<9|local) into padded buckets -
__global__ __launch_bounds__(256)
void radix_scatter(const int* __restrict__ src, const int* __restrict__ dst,
                   int* __restrict__ bcur, unsigned* __restrict__ pairs, int n) {
    __shared__ int base[NBK];
    __shared__ int cnt[NBK];
    for (int i = threadIdx.x; i < NBK; i += 256) cnt[i] = 0;
    __syncthreads();
    const int per = (n + RB - 1) / RB;
    const int beg = blockIdx.x * per;
    const int end = min(n, beg + per);
    for (int i = beg + threadIdx.x; i < end; i += 256)
        atomicAdd(&cnt[dst[i] >> BSH], 1);
    __syncthreads();
    for (int i = threadIdx.x; i < NBK; i += 256)
        base[i] = cnt[i] ? atomicAdd(&bcur[i], cnt[i]) : 0;
    __syncthreads();
    for (int i = beg + threadIdx.x; i < end; i += 256) {
        int d = dst[i];
        int p = atomicAdd(&base[d >> BSH], 1);
        pairs[p] = ((unsigned)src[i] << BSH) | (unsigned)(d & 511);
    }
}

// ---------------- pass 2: per-bucket hist+scan+scatter -> padded CSR --------
// ssrc stores PRE-SCALED byte offsets (src*128) for sage_agg's gathers.
__global__ __launch_bounds__(256)
void bucket_build(const unsigned* __restrict__ pairs, const int* __restrict__ bcur,
                  int* __restrict__ row_beg, int* __restrict__ row_end,
                  float* __restrict__ inv_deg, int* __restrict__ ssrc) {
    __shared__ int cnt[512];
    __shared__ int curs[512];
    __shared__ int wsum[4];
    const int b = blockIdx.x;
    const int n0 = b << BSH;
    const int t = threadIdx.x;
    const int lane = t & 63, wid = t >> 6;

    for (int i = t; i < 512; i += 256) cnt[i] = 0;
    __syncthreads();
    const int beg = b * BCAP, end = bcur[b];
    for (int i = beg + t; i < end; i += 256)
        atomicAdd(&cnt[pairs[i] & 511], 1);
    __syncthreads();

    int c0 = cnt[2 * t], c1 = cnt[2 * t + 1];
    int v = c0 + c1;
    int x = v;
    #pragma unroll
    for (int o = 1; o < 64; o <<= 1) {
        int y = __shfl_up(x, o);
        if (lane >= o) x += y;
    }
    if (lane == 63) wsum[wid] = x;
    __syncthreads();
    if (t == 0) {
        int s = 0;
        #pragma unroll
        for (int w2 = 0; w2 < 4; ++w2) { int tv = wsum[w2]; wsum[w2] = s; s += tv; }
    }
    __syncthreads();
    int g0 = beg + wsum[wid] + x - v;
    int g1 = g0 + c0;
    curs[2 * t] = g0;
    curs[2 * t + 1] = g1;
    {
        int node = n0 + 2 * t;
        if (node < NN) {
            row_beg[node] = g0; row_end[node] = g1;
            inv_deg[node] = 1.0f / (float)(c0 > 1 ? c0 : 1);
        }
        node = n0 + 2 * t + 1;
        if (node < NN) {
            row_beg[node] = g1; row_end[node] = g1 + c1;
            inv_deg[node] = 1.0f / (float)(c1 > 1 ? c1 : 1);
        }
    }
    __syncthreads();
    for (int i = beg + t; i < end; i += 256) {
        unsigned pr = pairs[i];
        int p = atomicAdd(&curs[pr & 511], 1);
        ssrc[p] = (int)(pr >> BSH) << 7;   // pre-scaled byte offset (row*128)
    }
}

// ---------------- graph offsets via binary search on sorted batch -----------
__global__ __launch_bounds__(256)
void graph_offsets(const int* __restrict__ batch, int* __restrict__ g_off,
                   float* __restrict__ inv_cnt) {
    int g = blockIdx.x * blockDim.x + threadIdx.x;
    if (g > NG) return;
    if (g == NG) { g_off[NG] = NN; return; }
    int lo = 0, hi = NN;
    while (lo < hi) { int mid = (lo + hi) >> 1; if (batch[mid] < g) lo = mid + 1; else hi = mid; }
    int lo2 = lo, hi2 = NN;
    while (lo2 < hi2) { int mid = (lo2 + hi2) >> 1; if (batch[mid] < g + 1) lo2 = mid + 1; else hi2 = mid; }
    g_off[g] = lo;
    int c = lo2 - lo;
    inv_cnt[g] = 1.0f / (float)(c > 1 ? c : 1);
}

// ---------------- weight prep: fp32 [k][n] -> bf16 MFMA-FRAGMENT order ------
struct WTab { const float* a[16]; };
__global__ __launch_bounds__(256)
void prep_weights(WTab tab, unsigned short* __restrict__ dst) {
    int w = blockIdx.x >> 6;
    int idx = ((blockIdx.x & 63) << 8) + threadIdx.x;
    int j = idx & 7, lane = (idx >> 3) & 63, nt = (idx >> 9) & 7, kc = idx >> 12;
    int cb = lane & 15, rq = lane >> 4;
    int k = kc * 32 + rq * 8 + j;
    int n = nt * 16 + cb;
    dst[(size_t)w * 16384 + idx] = f2b(tab.a[w][k * 128 + n]);
}

// ---------------- SAGE mean aggregation from fp8 shadow (permuted rows) -----
// 16B gathers: 8 edge-groups x 8 col-lanes; uint4 per gather halves VMEM
// instruction count vs the 8B version (same cache-line traffic). Byte k of
// the 16B at offset j8*16 holds col ((j8*16+k)&7)*16 + ((j8*16+k)>>3).
__global__ __launch_bounds__(256)
void sage_agg(const unsigned char* __restrict__ h8, const int* __restrict__ row_beg,
              const int* __restrict__ row_end, const float* __restrict__ inv_deg,
              const int* __restrict__ ssrc, unsigned short* __restrict__ aggb) {
    const int wid = threadIdx.x >> 6;
    const int lane = threadIdx.x & 63;
    const int node = blockIdx.x * 4 + wid;
    const int eg = lane >> 3, j8 = lane & 7;
    const int jo = j8 * 16;
    const int beg = row_beg[node], end = row_end[node];
    f32x2 a[8];
    #pragma unroll
    for (int k = 0; k < 8; ++k) a[k] = (f32x2){0.f, 0.f};
    for (int e = beg + eg; e < end; e += 32) {
        uint4 u[4];
        #pragma unroll
        for (int k = 0; k < 4; ++k) {
            int ek = e + 8 * k;
            bool ok = ek < end;
            int idx = ssrc[ok ? ek : e];                       // e always < end
            uint4 uu = *(const uint4*)(h8 + (unsigned)(idx + jo));
            uu.x = ok ? uu.x : 0u; uu.y = ok ? uu.y : 0u;
            uu.z = ok ? uu.z : 0u; uu.w = ok ? uu.w : 0u;      // fp8 0 -> 0.0f
            u[k] = uu;
        }
        #pragma unroll
        for (int k = 0; k < 4; ++k) {
            a[0] += __builtin_amdgcn_cvt_pk_f32_fp8(u[k].x, false);
            a[1] += __builtin_amdgcn_cvt_pk_f32_fp8(u[k].x, true);
            a[2] += __builtin_amdgcn_cvt_pk_f32_fp8(u[k].y, false);
            a[3] += __builtin_amdgcn_cvt_pk_f32_fp8(u[k].y, true);
            a[4] += __builtin_amdgcn_cvt_pk_f32_fp8(u[k].z, false);
            a[5] += __builtin_amdgcn_cvt_pk_f32_fp8(u[k].z, true);
            a[6] += __builtin_amdgcn_cvt_pk_f32_fp8(u[k].w, false);
            a[7] += __builtin_amdgcn_cvt_pk_f32_fp8(u[k].w, true);
        }
    }
    float af[16];
    #pragma unroll
    for (int i = 0; i < 8; ++i) { af[2 * i] = a[i].x; af[2 * i + 1] = a[i].y; }
    #pragma unroll
    for (int k = 0; k < 16; ++k) {
        af[k] += __shfl_xor(af[k], 8);
        af[k] += __shfl_xor(af[k], 16);
        af[k] += __shfl_xor(af[k], 32);
    }
    if (eg == 0) {
        float id = inv_deg[node];
        #pragma unroll
        for (int k = 0; k < 16; ++k) {
            int p = jo + k;
            int col = (p & 7) * 16 + (p >> 3);
            aggb[(size_t)node * 128 + col] = f2b(af[k] * id);
        }
    }
}

// ---------------- mean pool per graph from bf16 (vectorized, 1 wave) --------
__global__ __launch_bounds__(64)
void pool_mean_b(const unsigned short* __restrict__ src, const int* __restrict__ g_off,
                 const float* __restrict__ inv_cnt, float* __restrict__ out) {
    const int g = blockIdx.x;
    const int lane = threadIdx.x & 63;
    const int j = lane & 15, rs = lane >> 4;
    const int beg = g_off[g], end = g_off[g + 1];
    float s[8] = {0.f, 0.f, 0.f, 0.f, 0.f, 0.f, 0.f, 0.f};
    for (int n = beg + rs; n < end; n += 4) {
        short8 v = *(const short8*)&src[(size_t)n * FF + j * 8];
        #pragma unroll
        for (int i = 0; i < 8; ++i) s[i] += us2f((unsigned short)v[i]);
    }
    #pragma unroll
    for (int i = 0; i < 8; ++i) {
        s[i] += __shfl_xor(s[i], 16);
        s[i] += __shfl_xor(s[i], 32);
    }
    if (rs == 0) {
        float ic = inv_cnt[g];
        #pragma unroll
        for (int i = 0; i < 8; ++i) out[(size_t)g * FF + j * 8 + i] = s[i] * ic;
    }
}

// ---------------- MFMA bf16 GEMM, frag-ordered W from global (L2) ----------
template<bool AB16, bool R1, int RESM, int ACT, bool LN, bool OF32, bool OB16, bool OB8>
__global__ __launch_bounds__(256)
void gemm_mfma(const void* __restrict__ A_,
               const unsigned short* __restrict__ Wf,
               const float* __restrict__ bias,
               const float* __restrict__ rvec, const float* __restrict__ rrow,
               const float* __restrict__ res,
               const float* __restrict__ lng, const float* __restrict__ lnb,
               float* __restrict__ outf, unsigned short* __restrict__ outb,
               unsigned char* __restrict__ outb8, int M) {
    __shared__ short Al[64 * 136];

    const int t = threadIdx.x;
    const int lane = t & 63, wid = t >> 6;
    const int m0 = blockIdx.x * 64;
    const int cb = lane & 15, rq = lane >> 4;

    if (AB16) {
        const unsigned short* Ab = (const unsigned short*)A_;
        for (int i = t; i < 1024; i += 256) {
            int row = i >> 4, seg = i & 15;
            int gr = m0 + row; if (gr >= M) gr = M - 1;
            *(uint4*)&Al[row * 136 + seg * 8] = *(const uint4*)&Ab[(size_t)gr * 128 + seg * 8];
        }
    } else {
        const float* Af = (const float*)A_;
        for (int i = t; i < 2048; i += 256) {
            int row = i >> 5, seg = i & 31;
            int gr = m0 + row; if (gr >= M) gr = M - 1;
            float4 v = *(const float4*)&Af[(size_t)gr * 128 + seg * 4];
            ushort4 o = {f2b(v.x), f2b(v.y), f2b(v.z), f2b(v.w)};
            *(ushort4*)&Al[row * 136 + seg * 4] = o;
        }
    }
    __syncthreads();

    f32x4 acc[8];
    #pragma unroll
    for (int nt = 0; nt < 8; ++nt) acc[nt] = (f32x4){0.f, 0.f, 0.f, 0.f};

    const int aoff_base = (wid * 16 + cb) * 136 + rq * 8;
    for (int kc = 0; kc < 4; ++kc) {
        short8 a0 = *(const short8*)&Al[aoff_base + kc * 32];
        #pragma unroll
        for (int nt = 0; nt < 8; ++nt) {
            short8 b0 = *(const short8*)&Wf[(size_t)(kc * 8 + nt) * 512 + lane * 8];
            acc[nt] = MFMA(a0, b0, acc[nt]);
        }
    }

    float bs[8], rr[8], lg[8], lb[8];
    #pragma unroll
    for (int nt = 0; nt < 8; ++nt) {
        int col = nt * 16 + cb;
        bs[nt] = bias[col];
        if (R1) rr[nt] = rrow[col];
        if (LN) { lg[nt] = lng[col]; lb[nt] = lnb[col]; }
    }
    #pragma unroll
    for (int reg = 0; reg < 4; ++reg) {
        int m = m0 + wid * 16 + rq * 4 + reg;
        int mc = m < M ? m : M - 1;
        float v[8];
        #pragma unroll
        for (int nt = 0; nt < 8; ++nt) v[nt] = acc[nt][reg] + bs[nt];
        if (R1) {
            float rv = rvec[mc];
            #pragma unroll
            for (int nt = 0; nt < 8; ++nt) v[nt] += rv * rr[nt];
        }
        if (RESM == 1) {
            #pragma unroll
            for (int nt = 0; nt < 8; ++nt) v[nt] += res[(size_t)mc * 128 + nt * 16 + cb];
        }
        if (ACT == 1) {
            #pragma unroll
            for (int nt = 0; nt < 8; ++nt) v[nt] = fast_elu(v[nt]);
        }
        if (LN) {
            float s1 = 0.f, s2 = 0.f;
            #pragma unroll
            for (int nt = 0; nt < 8; ++nt) { s1 += v[nt]; s2 += v[nt] * v[nt]; }
            #pragma unroll
            for (int o = 8; o >= 1; o >>= 1) { s1 += __shfl_xor(s1, o); s2 += __shfl_xor(s2, o); }
            float mu = s1 * (1.f / 128.f);
            float rs = rsqrtf(s2 * (1.f / 128.f) - mu * mu + 1e-5f);
            #pragma unroll
            for (int nt = 0; nt < 8; ++nt) v[nt] = (v[nt] - mu) * rs * lg[nt] + lb[nt];
        }
        if (m < M) {
            #pragma unroll
            for (int nt = 0; nt < 8; ++nt) {
                size_t o = (size_t)m * 128 + nt * 16 + cb;
                if (OF32) outf[o] = v[nt];
                if (OB16) outb[o] = f2b(v[nt]);
            }
            if (OB8) *(uint2*)&outb8[(size_t)m * 128 + cb * 8] = pk8(v);
        }
    }
}

// ---------------- fused GEMM chain: W from L2 (frag order), ONE barrier -----
// (R3-measured form: 4 waves/block, y1 residual in regs, no launch bound cap)
__global__ __launch_bounds__(256)
void gc_chain(const unsigned short* __restrict__ hin, const unsigned short* __restrict__ aggb,
              unsigned short* __restrict__ hout, unsigned char* __restrict__ h8out,
              const unsigned short* __restrict__ Wl_f, const unsigned short* __restrict__ Wr_f,
              const unsigned short* __restrict__ W1_f, const unsigned short* __restrict__ W2_f,
              const float* __restrict__ bl,
              const float* __restrict__ g1, const float* __restrict__ b1,
              const float* __restrict__ bb1, const float* __restrict__ bb2,
              const float* __restrict__ g2, const float* __restrict__ b2, int M) {
    __shared__ short Hl[64 * 136];     // h tile -> y1 tile
    __shared__ short Gl[64 * 136];     // agg tile -> elu(t) tile

    const int t = threadIdx.x;
    const int lane = t & 63, wid = t >> 6;
    const int m0 = blockIdx.x * 64;
    const int cb = lane & 15, rq = lane >> 4;
    const int aoff_base = (wid * 16 + cb) * 136 + rq * 8;
    const int boff = lane * 8;

    for (int i = t; i < 1024; i += 256) {
        int row = i >> 4, seg = i & 15;
        int gr = m0 + row; if (gr >= M) gr = M - 1;
        *(uint4*)&Hl[row * 136 + seg * 8] = *(const uint4*)&hin[(size_t)gr * 128 + seg * 8];
        *(uint4*)&Gl[row * 136 + seg * 8] = *(const uint4*)&aggb[(size_t)gr * 128 + seg * 8];
    }
    __syncthreads();   // the only barrier

    f32x4 acc[8];
    #pragma unroll
    for (int nt = 0; nt < 8; ++nt) acc[nt] = (f32x4){0.f, 0.f, 0.f, 0.f};

    // ---- dual GEMM: acc = agg@Wl + h@Wr ----
    for (int kc = 0; kc < 4; ++kc) {
        short8 a0 = *(const short8*)&Gl[aoff_base + kc * 32];
        short8 a1 = *(const short8*)&Hl[aoff_base + kc * 32];
        #pragma unroll
        for (int nt = 0; nt < 8; ++nt) {
            const size_t wo = (size_t)(kc * 8 + nt) * 512 + boff;
            acc[nt] = MFMA(a0, *(const short8*)&Wl_f[wo], acc[nt]);
            acc[nt] = MFMA(a1, *(const short8*)&Wr_f[wo], acc[nt]);
        }
    }

    // ---- epilogue 1 (band-local): y1 = LN1(acc + bl + h) -> Hl + regs ----
    float y1r[4][8];
    {
        float bs[8], lg[8], lb[8];
        #pragma unroll
        for (int nt = 0; nt < 8; ++nt) {
            int col = nt * 16 + cb;
            bs[nt] = bl[col]; lg[nt] = g1[col]; lb[nt] = b1[col];
        }
        #pragma unroll
        for (int reg = 0; reg < 4; ++reg) {
            int r = wid * 16 + rq * 4 + reg;
            float v[8];
            float s1 = 0.f, s2 = 0.f;
            #pragma unroll
            for (int nt = 0; nt < 8; ++nt) {
                v[nt] = acc[nt][reg] + bs[nt] + us2f((unsigned short)Hl[r * 136 + nt * 16 + cb]);
                s1 += v[nt]; s2 += v[nt] * v[nt];
            }
            #pragma unroll
            for (int o = 8; o >= 1; o >>= 1) { s1 += __shfl_xor(s1, o); s2 += __shfl_xor(s2, o); }
            float mu = s1 * (1.f / 128.f);
            float rs = rsqrtf(s2 * (1.f / 128.f) - mu * mu + 1e-5f);
            #pragma unroll
            for (int nt = 0; nt < 8; ++nt) {
                float y = (v[nt] - mu) * rs * lg[nt] + lb[nt];
                y1r[reg][nt] = y;
                Hl[r * 136 + nt * 16 + cb] = (short)f2b(y);
            }
        }
    }

    // ---- FF1 (band-local): t = elu(y1@W1 + bb1) -> Gl ----
    #pragma unroll
    for (int nt = 0; nt < 8; ++nt) acc[nt] = (f32x4){0.f, 0.f, 0.f, 0.f};
    for (int kc = 0; kc < 4; ++kc) {
        short8 a0 = *(const short8*)&Hl[aoff_base + kc * 32];
        #pragma unroll
        for (int nt = 0; nt < 8; ++nt)
            acc[nt] = MFMA(a0, *(const short8*)&W1_f[(size_t)(kc * 8 + nt) * 512 + boff], acc[nt]);
    }
    {
        float bs[8];
        #pragma unroll
        for (int nt = 0; nt < 8; ++nt) bs[nt] = bb1[nt * 16 + cb];
        #pragma unroll
        for (int reg = 0; reg < 4; ++reg) {
            int r = wid * 16 + rq * 4 + reg;
            #pragma unroll
            for (int nt = 0; nt < 8; ++nt) {
                float v = fast_elu(acc[nt][reg] + bs[nt]);
                Gl[r * 136 + nt * 16 + cb] = (short)f2b(v);
            }
        }
    }

    // ---- FF2 (band-local): h' = LN2(t@W2 + bb2 + y1) -> global bf16 + fp8 --
    #pragma unroll
    for (int nt = 0; nt < 8; ++nt) acc[nt] = (f32x4){0.f, 0.f, 0.f, 0.f};
    for (int kc = 0; kc < 4; ++kc) {
        short8 a0 = *(const short8*)&Gl[aoff_base + kc * 32];
        #pragma unroll
        for (int nt = 0; nt < 8; ++nt)
            acc[nt] = MFMA(a0, *(const short8*)&W2_f[(size_t)(kc * 8 + nt) * 512 + boff], acc[nt]);
    }
    {
        float bs[8], lg[8], lb[8];
        #pragma unroll
        for (int nt = 0; nt < 8; ++nt) {
            int col = nt * 16 + cb;
            bs[nt] = bb2[col]; lg[nt] = g2[col]; lb[nt] = b2[col];
        }
        #pragma unroll
        for (int reg = 0; reg < 4; ++reg) {
            int r = wid * 16 + rq * 4 + reg;
            int m = m0 + r;
            float v[8];
            float s1 = 0.f, s2 = 0.f;
            #pragma unroll
            for (int nt = 0; nt < 8; ++nt) {
                v[nt] = acc[nt][reg] + bs[nt] + y1r[reg][nt];
                s1 += v[nt]; s2 += v[nt] * v[nt];
            }
            #pragma unroll
            for (int o = 8; o >= 1; o >>= 1) { s1 += __shfl_xor(s1, o); s2 += __shfl_xor(s2, o); }
            float mu = s1 * (1.f / 128.f);
            float rs = rsqrtf(s2 * (1.f / 128.f) - mu * mu + 1e-5f);
            if (m < M) {
                float fv[8];
                #pragma unroll
                for (int nt = 0; nt < 8; ++nt) {
                    fv[nt] = (v[nt] - mu) * rs * lg[nt] + lb[nt];
                    hout[(size_t)m * 128 + nt * 16 + cb] = f2b(fv[nt]);
                }
                *(uint2*)&h8out[(size_t)m * 128 + cb * 8] = pk8(fv);
            }
        }
    }
}

// ---------------- fused head: LN1 -> elu FF -> res+LN2, one launch ---------
// Row-local chain over 1024 graph rows; 16 blocks x 64 rows. Single LDS
// buffer: each phase's MFMA reads complete (program order, band-local)
// before its epilogue overwrites the band. out = LN2(elu(LN1(gm@Wa+mb)@P1
// +p1b)@P2 +p2b + LN1(...)).
__global__ __launch_bounds__(256)
void head_chain(const float* __restrict__ gm,
                const unsigned short* __restrict__ Wa_f,
                const unsigned short* __restrict__ P1_f,
                const unsigned short* __restrict__ P2_f,
                const float* __restrict__ mdfb,
                const float* __restrict__ g1, const float* __restrict__ b1,
                const float* __restrict__ p1b, const float* __restrict__ p2b,
                const float* __restrict__ g2, const float* __restrict__ b2,
                float* __restrict__ outp) {
    __shared__ short Al[64 * 136];

    const int t = threadIdx.x;
    const int lane = t & 63, wid = t >> 6;
    const int m0 = blockIdx.x * 64;
    const int cb = lane & 15, rq = lane >> 4;
    const int aoff_base = (wid * 16 + cb) * 136 + rq * 8;
    const int boff = lane * 8;

    for (int i = t; i < 2048; i += 256) {
        int row = i >> 5, seg = i & 31;
        float4 v = *(const float4*)&gm[(size_t)(m0 + row) * 128 + seg * 4];
        ushort4 o = {f2b(v.x), f2b(v.y), f2b(v.z), f2b(v.w)};
        *(ushort4*)&Al[row * 136 + seg * 4] = o;
    }
    __syncthreads();

    f32x4 acc[8];
    // ---- GEMM1: gm@Wa + mdfb, LN1 -> y1r + Al ----
    #pragma unroll
    for (int nt = 0; nt < 8; ++nt) acc[nt] = (f32x4){0.f, 0.f, 0.f, 0.f};
    for (int kc = 0; kc < 4; ++kc) {
        short8 a0 = *(const short8*)&Al[aoff_base + kc * 32];
        #pragma unroll
        for (int nt = 0; nt < 8; ++nt)
            acc[nt] = MFMA(a0, *(const short8*)&Wa_f[(size_t)(kc * 8 + nt) * 512 + boff], acc[nt]);
    }
    float y1r[4][8];
    {
        float bs[8], lg[8], lb[8];
        #pragma unroll
        for (int nt = 0; nt < 8; ++nt) {
            int col = nt * 16 + cb;
            bs[nt] = mdfb[col]; lg[nt] = g1[col]; lb[nt] = b1[col];
        }
        #pragma unroll
        for (int reg = 0; reg < 4; ++reg) {
            int r = wid * 16 + rq * 4 + reg;
            float v[8];
            float s1 = 0.f, s2 = 0.f;
            #pragma unroll
            for (int nt = 0; nt < 8; ++nt) {
                v[nt] = acc[nt][reg] + bs[nt];
                s1 += v[nt]; s2 += v[nt] * v[nt];
            }
            #pragma unroll
            for (int o = 8; o >= 1; o >>= 1) { s1 += __shfl_xor(s1, o); s2 += __shfl_xor(s2, o); }
            float mu = s1 * (1.f / 128.f);
            float rs = rsqrtf(s2 * (1.f / 128.f) - mu * mu + 1e-5f);
            #pragma unroll
            for (int nt = 0; nt < 8; ++nt) {
                float y = (v[nt] - mu) * rs * lg[nt] + lb[nt];
                y1r[reg][nt] = y;
                Al[r * 136 + nt * 16 + cb] = (short)f2b(y);
            }
        }
    }

    // ---- GEMM2: elu(y1@P1 + p1b) -> Al ----
    #pragma unroll
    for (int nt = 0; nt < 8; ++nt) acc[nt] = (f32x4){0.f, 0.f, 0.f, 0.f};
    for (int kc = 0; kc < 4; ++kc) {
        short8 a0 = *(const short8*)&Al[aoff_base + kc * 32];
        #pragma unroll
        for (int nt = 0; nt < 8; ++nt)
            acc[nt] = MFMA(a0, *(const short8*)&P1_f[(size_t)(kc * 8 + nt) * 512 + boff], acc[nt]);
    }
    {
        float bs[8];
        #pragma unroll
        for (int nt = 0; nt < 8; ++nt) bs[nt] = p1b[nt * 16 + cb];
        #pragma unroll
        for (int reg = 0; reg < 4; ++reg) {
            int r = wid * 16 + rq * 4 + reg;
            #pragma unroll
            for (int nt = 0; nt < 8; ++nt) {
                float v = fast_elu(acc[nt][reg] + bs[nt]);
                Al[r * 136 + nt * 16 + cb] = (short)f2b(v);
            }
        }
    }

    // ---- GEMM3: LN2(t@P2 + p2b + y1r) -> out fp32 ----
    #pragma unroll
    for (int nt = 0; nt < 8; ++nt) acc[nt] = (f32x4){0.f, 0.f, 0.f, 0.f};
    for (int kc = 0; kc < 4; ++kc) {
        short8 a0 = *(const short8*)&Al[aoff_base + kc * 32];
        #pragma unroll
        for (int nt = 0; nt < 8; ++nt)
            acc[nt] = MFMA(a0, *(const short8*)&P2_f[(size_t)(kc * 8 + nt) * 512 + boff], acc[nt]);
    }
    {
        float bs[8], lg[8], lb[8];
        #pragma unroll
        for (int nt = 0; nt < 8; ++nt) {
            int col = nt * 16 + cb;
            bs[nt] = p2b[col]; lg[nt] = g2[col]; lb[nt] = b2[col];
        }
        #pragma unroll
        for (int reg = 0; reg < 4; ++reg) {
            int r = wid * 16 + rq * 4 + reg;
            int m = m0 + r;
            float v[8];
            float s1 = 0.f, s2 = 0.f;
            #pragma unroll
            for (int nt = 0; nt < 8; ++nt) {
                v[nt] = acc[nt][reg] + bs[nt] + y1r[reg][nt];
                s1 += v[nt]; s2 += v[nt] * v[nt];
            }
            #pragma unroll
            for (int o = 8; o >= 1; o >>= 1) { s1 += __shfl_xor(s1, o); s2 += __shfl_xor(s2, o); }
            float mu = s1 * (1.f / 128.f);
            float rs = rsqrtf(s2 * (1.f / 128.f) - mu * mu + 1e-5f);
            #pragma unroll
            for (int nt = 0; nt < 8; ++nt)
                outp[(size_t)m * 128 + nt * 16 + cb] = (v[nt] - mu) * rs * lg[nt] + lb[nt];
        }
    }
}

extern "C" void kernel_launch(void* const* d_in, const int* in_sizes, int n_in,
                              void* d_out, int out_size, void* d_ws, size_t ws_size,
                              hipStream_t stream) {
    const float* x      = (const float*)d_in[0];
    const float* w      = (const float*)d_in[1];
    const int*   ei     = (const int*)d_in[2];
    const int*   batch  = (const int*)d_in[3];
    const float* W_in   = (const float*)d_in[4];
    const float* b_in   = (const float*)d_in[5];
    const float* sage_Wl = (const float*)d_in[6];
    const float* sage_bl = (const float*)d_in[7];
    const float* sage_Wr = (const float*)d_in[8];
    const float* ln1_g  = (const float*)d_in[9];
    const float* ln1_b  = (const float*)d_in[10];
    const float* lin1_W = (const float*)d_in[11];
    const float* lin1_b = (const float*)d_in[12];
    const float* lin2_W = (const float*)d_in[13];
    const float* lin2_b = (const float*)d_in[14];
    const float* ln2_g  = (const float*)d_in[15];
    const float* ln2_b  = (const float*)d_in[16];
    const float* mdf_W  = (const float*)d_in[17];
    const float* mdf_b  = (const float*)d_in[18];
    const float* pln1_g = (const float*)d_in[19];
    const float* pln1_b = (const float*)d_in[20];
    const float* plin1_W = (const float*)d_in[21];
    const float* plin1_b = (const float*)d_in[22];
    const float* plin2_W = (const float*)d_in[23];
    const float* plin2_b = (const float*)d_in[24];
    const float* pln2_g = (const float*)d_in[25];
    const float* pln2_b = (const float*)d_in[26];
    float* out = (float*)d_out;

    const int* e_src = ei;
    const int* e_dst = ei + NE;

    // ---- workspace layout ----
    float* ws = (float*)d_ws;
    size_t off = 0;
    float* gm    = ws + off; off += (size_t)NG * FF;
    float* hh    = ws + off; off += (size_t)NG * FF;
    float* tt    = ws + off; off += (size_t)NG * FF;
    float* inv_deg = ws + off; off += NN;
    float* inv_cnt = ws + off; off += NG;
    unsigned short* us = (unsigned short*)(ws + off);
    size_t uoff = 0;
    unsigned short* hb0  = us + uoff; uoff += (size_t)NN * FF;
    unsigned short* hb1  = us + uoff; uoff += (size_t)NN * FF;
    unsigned short* aggb = us + uoff; uoff += (size_t)NN * FF;
    unsigned short* wt   = us + uoff; uoff += (size_t)16 * 16384;
    int* iw = (int*)(us + uoff);
    size_t ioff = 0;
    unsigned* pairs = (unsigned*)iw; ioff += (size_t)NBK * BCAP;
    int* ssrc    = iw + ioff; ioff += (size_t)NBK * BCAP;
    int* row_beg = iw + ioff; ioff += NN;
    int* row_end = iw + ioff; ioff += NN;
    int* g_off   = iw + ioff; ioff += NG + 1;
    int* bcur    = iw + ioff; ioff += NBK;
    // h8 (12.8 MB) aliases pairs (12.85 MB): pairs is dead after bucket_build,
    // h8 is first written by the input GEMM which runs after.
    unsigned char* h8 = (unsigned char*)pairs;

    // ---- weight prep (16 matrices -> frag-ordered bf16) ----
    WTab tab;
    tab.a[0] = W_in;
    for (int l = 0; l < 3; ++l) {
        tab.a[1 + l]  = sage_Wl + (size_t)l * 16384;
        tab.a[4 + l]  = sage_Wr + (size_t)l * 16384;
        tab.a[7 + l]  = lin1_W + (size_t)l * 16384;
        tab.a[10 + l] = lin2_W + (size_t)l * 16384;
    }
    tab.a[13] = mdf_W;      // first 128 rows only (Wa)
    tab.a[14] = plin1_W;
    tab.a[15] = plin2_W;
    prep_weights<<<16 * 64, 256, 0, stream>>>(tab, wt);
    const unsigned short* win_t = wt + 0 * 16384;
    const unsigned short* wa_t  = wt + 13 * 16384;
    const unsigned short* p1_t  = wt + 14 * 16384;
    const unsigned short* p2_t  = wt + 15 * 16384;

    // ---- build padded CSR (no histogram pass, no scan) ----
    init_bcur<<<1, 256, 0, stream>>>(bcur);
    graph_offsets<<<(NG + 256) / 256, 256, 0, stream>>>(batch, g_off, inv_cnt);
    radix_scatter<<<RB, 256, 0, stream>>>(e_src, e_dst, bcur, pairs, NE);
    bucket_build<<<NBK, 256, 0, stream>>>(pairs, bcur, row_beg, row_end, inv_deg, ssrc);

    const int GN = (NN + 63) / 64;     // 1563
    const int GB = NG / 64;            // 16

    // ---- input linear: hb0 (bf16) + h8 (fp8, permuted) ----
    gemm_mfma<false, true, 0, 0, false, false, true, true><<<GN, 256, 0, stream>>>(
        x, win_t, b_in, w, W_in + 128 * 128,
        nullptr, nullptr, nullptr, nullptr, hb0, h8, NN);

    // ---- 3 GC blocks: fp8 gather + fused GEMM chain ----
    unsigned short* hcur = hb0;
    unsigned short* hnxt = hb1;
    for (int l = 0; l < 3; ++l) {
        sage_agg<<<NN / 4, 256, 0, stream>>>(h8, row_beg, row_end, inv_deg, ssrc, aggb);
        gc_chain<<<GN, 256, 0, stream>>>(
            hcur, aggb, hnxt, h8,
            wt + (size_t)(1 + l) * 16384, wt + (size_t)(4 + l) * 16384,
            wt + (size_t)(7 + l) * 16384, wt + (size_t)(10 + l) * 16384,
            sage_bl + (size_t)l * FF,
            ln1_g + (size_t)l * FF, ln1_b + (size_t)l * FF,
            lin1_b + (size_t)l * FF, lin2_b + (size_t)l * FF,
            ln2_g + (size_t)l * FF, ln2_b + (size_t)l * FF, NN);
        unsigned short* tmp = hcur; hcur = hnxt; hnxt = tmp;
    }

    // ---- head: pool(h2) -> fused LN1/FF/LN2 chain (one launch) ----
    pool_mean_b<<<NG, 64, 0, stream>>>(hcur, g_off, inv_cnt, gm);
    head_chain<<<GB, 256, 0, stream>>>(
        gm, wa_t, p1_t, p2_t, mdf_b,
        pln1_g, pln1_b, plin1_b, plin2_b, pln2_g, pln2_b, out);
    (void)hh; (void)tt;
}

// Round 9
// 513.825 us; speedup vs baseline: 1.4323x; 1.0535x over previous
//
#include <hip/hip_runtime.h>
#include <math.h>

#define NN 100000
#define NE 1600000
#define NG 1024
#define FF 128
#define BSH 9
#define NBK ((NN + 511) >> BSH)   // 196 buckets of 512 nodes
#define RB 256                    // radix blocks
#define BCAP 16384                // fixed bucket capacity (mean 8192, sigma~90)

typedef __attribute__((ext_vector_type(8))) short short8;
typedef __attribute__((ext_vector_type(4))) float f32x4;
typedef __attribute__((ext_vector_type(2))) float f32x2;

__device__ __forceinline__ unsigned short f2b(float f) {
    union { float f; unsigned u; } v; v.f = f;
    unsigned r = (v.u + 0x7FFF + ((v.u >> 16) & 1)) >> 16;
    return (unsigned short)r;
}
__device__ __forceinline__ float us2f(unsigned short u) {
    union { unsigned u; float f; } v; v.u = ((unsigned)u) << 16; return v.f;
}
// hardware ELU: v_exp_f32 is 2^x; elu(v)=v>0?v:2^(v*log2e)-1.
__device__ __forceinline__ float fast_elu(float v) {
    float e = __builtin_amdgcn_exp2f(v * 1.44269504088896340736f) - 1.0f;
    return v > 0.f ? v : e;
}
// pack 8 floats -> 8 fp8 (uint2), byte i = v[i]
__device__ __forceinline__ uint2 pk8(const float* v) {
    unsigned lo = 0, hi = 0;
    lo = (unsigned)__builtin_amdgcn_cvt_pk_fp8_f32(v[0], v[1], (int)lo, false);
    lo = (unsigned)__builtin_amdgcn_cvt_pk_fp8_f32(v[2], v[3], (int)lo, true);
    hi = (unsigned)__builtin_amdgcn_cvt_pk_fp8_f32(v[4], v[5], (int)hi, false);
    hi = (unsigned)__builtin_amdgcn_cvt_pk_fp8_f32(v[6], v[7], (int)hi, true);
    uint2 r; r.x = lo; r.y = hi; return r;
}
#define MFMA(a, b, c) __builtin_amdgcn_mfma_f32_16x16x32_bf16((a), (b), (c), 0, 0, 0)

// ---------------- pass 1: scatter packed (src<<9|local) into padded buckets -
__global__ __launch_bounds__(256)
void radix_scatter(const int* __restrict__ src, const int* __restrict__ dst,
                   int* __restrict__ bcur, unsigned* __restrict__ pairs, int n) {
    __shared__ int base[NBK];
    __shared__ int cnt[NBK];
    for (int i = threadIdx.x; i < NBK; i += 256) cnt[i] = 0;
    __syncthreads();
    const int per = (n + RB - 1) / RB;
    const int beg = blockIdx.x * per;
    const int end = min(n, beg + per);
    for (int i = beg + threadIdx.x; i < end; i += 256)
        atomicAdd(&cnt[dst[i] >> BSH], 1);
    __syncthreads();
    for (int i = threadIdx.x; i < NBK; i += 256)
        base[i] = cnt[i] ? atomicAdd(&bcur[i], cnt[i]) : 0;
    __syncthreads();
    for (int i = beg + threadIdx.x; i < end; i += 256) {
        int d = dst[i];
        int p = atomicAdd(&base[d >> BSH], 1);
        pairs[p] = ((unsigned)src[i] << BSH) | (unsigned)(d & 511);
    }
}

// ---------------- pass 2: per-bucket hist+scan+scatter -> padded CSR --------
// ssrc stores PRE-SCALED byte offsets (src*128) for sage_agg's gathers.
__global__ __launch_bounds__(256)
void bucket_build(const unsigned* __restrict__ pairs, const int* __restrict__ bcur,
                  int* __restrict__ row_beg, int* __restrict__ row_end,
                  float* __restrict__ inv_deg, int* __restrict__ ssrc) {
    __shared__ int cnt[512];
    __shared__ int curs[512];
    __shared__ int wsum[4];
    const int b = blockIdx.x;
    const int n0 = b << BSH;
    const int t = threadIdx.x;
    const int lane = t & 63, wid = t >> 6;

    for (int i = t; i < 512; i += 256) cnt[i] = 0;
    __syncthreads();
    const int beg = b * BCAP, end = bcur[b];
    for (int i = beg + t; i < end; i += 256)
        atomicAdd(&cnt[pairs[i] & 511], 1);
    __syncthreads();

    int c0 = cnt[2 * t], c1 = cnt[2 * t + 1];
    int v = c0 + c1;
    int x = v;
    #pragma unroll
    for (int o = 1; o < 64; o <<= 1) {
        int y = __shfl_up(x, o);
        if (lane >= o) x += y;
    }
    if (lane == 63) wsum[wid] = x;
    __syncthreads();
    if (t == 0) {
        int s = 0;
        #pragma unroll
        for (int w2 = 0; w2 < 4; ++w2) { int tv = wsum[w2]; wsum[w2] = s; s += tv; }
    }
    __syncthreads();
    int g0 = beg + wsum[wid] + x - v;
    int g1 = g0 + c0;
    curs[2 * t] = g0;
    curs[2 * t + 1] = g1;
    {
        int node = n0 + 2 * t;
        if (node < NN) {
            row_beg[node] = g0; row_end[node] = g1;
            inv_deg[node] = 1.0f / (float)(c0 > 1 ? c0 : 1);
        }
        node = n0 + 2 * t + 1;
        if (node < NN) {
            row_beg[node] = g1; row_end[node] = g1 + c1;
            inv_deg[node] = 1.0f / (float)(c1 > 1 ? c1 : 1);
        }
    }
    __syncthreads();
    for (int i = beg + t; i < end; i += 256) {
        unsigned pr = pairs[i];
        int p = atomicAdd(&curs[pr & 511], 1);
        ssrc[p] = (int)(pr >> BSH) << 7;   // pre-scaled byte offset (row*128)
    }
}

// ---------------- graph offsets + bucket-cursor init (merged launch) --------
__global__ __launch_bounds__(256)
void graph_offsets(const int* __restrict__ batch, int* __restrict__ g_off,
                   float* __restrict__ inv_cnt, int* __restrict__ bcur) {
    int g = blockIdx.x * blockDim.x + threadIdx.x;
    if (g < NBK) bcur[g] = g * BCAP;
    if (g > NG) return;
    if (g == NG) { g_off[NG] = NN; return; }
    int lo = 0, hi = NN;
    while (lo < hi) { int mid = (lo + hi) >> 1; if (batch[mid] < g) lo = mid + 1; else hi = mid; }
    int lo2 = lo, hi2 = NN;
    while (lo2 < hi2) { int mid = (lo2 + hi2) >> 1; if (batch[mid] < g + 1) lo2 = mid + 1; else hi2 = mid; }
    g_off[g] = lo;
    int c = lo2 - lo;
    inv_cnt[g] = 1.0f / (float)(c > 1 ? c : 1);
}

// ---------------- weight prep: fp32 [k][n] -> bf16 MFMA-FRAGMENT order ------
struct WTab { const float* a[16]; };
__global__ __launch_bounds__(256)
void prep_weights(WTab tab, unsigned short* __restrict__ dst) {
    int w = blockIdx.x >> 6;
    int idx = ((blockIdx.x & 63) << 8) + threadIdx.x;
    int j = idx & 7, lane = (idx >> 3) & 63, nt = (idx >> 9) & 7, kc = idx >> 12;
    int cb = lane & 15, rq = lane >> 4;
    int k = kc * 32 + rq * 8 + j;
    int n = nt * 16 + cb;
    dst[(size_t)w * 16384 + idx] = f2b(tab.a[w][k * 128 + n]);
}

// ---------------- SAGE mean aggregation from fp8 shadow (permuted rows) -----
// R3-measured form: 4 edge-groups x 16 col-lanes, 8B gathers, predicated
// batch-of-8 (two latency stages per node, 32 edges/iter). Cheap epilogue:
// 8 values x 2 shuffles, 16 active store lanes.
__global__ __launch_bounds__(256)
void sage_agg(const unsigned char* __restrict__ h8, const int* __restrict__ row_beg,
              const int* __restrict__ row_end, const float* __restrict__ inv_deg,
              const int* __restrict__ ssrc, unsigned short* __restrict__ aggb) {
    const int wid = threadIdx.x >> 6;
    const int lane = threadIdx.x & 63;
    const int node = blockIdx.x * 4 + wid;
    const int eg = lane >> 4, j = lane & 15;
    const int jo = j * 8;
    const int beg = row_beg[node], end = row_end[node];
    f32x2 a0 = {0.f, 0.f}, a1 = {0.f, 0.f}, a2 = {0.f, 0.f}, a3 = {0.f, 0.f};
    for (int e = beg + eg; e < end; e += 32) {
        uint2 u[8];
        #pragma unroll
        for (int k = 0; k < 8; ++k) {
            int ek = e + 4 * k;
            bool ok = ek < end;
            int idx = ssrc[ok ? ek : e];                       // e always < end
            uint2 uu = *(const uint2*)(h8 + (unsigned)(idx + jo));
            uu.x = ok ? uu.x : 0u;
            uu.y = ok ? uu.y : 0u;                             // fp8 0x00 -> 0.0f
            u[k] = uu;
        }
        #pragma unroll
        for (int k = 0; k < 8; ++k) {
            a0 += __builtin_amdgcn_cvt_pk_f32_fp8(u[k].x, false);
            a1 += __builtin_amdgcn_cvt_pk_f32_fp8(u[k].x, true);
            a2 += __builtin_amdgcn_cvt_pk_f32_fp8(u[k].y, false);
            a3 += __builtin_amdgcn_cvt_pk_f32_fp8(u[k].y, true);
        }
    }
    float af[8] = {a0.x, a0.y, a1.x, a1.y, a2.x, a2.y, a3.x, a3.y};
    #pragma unroll
    for (int k = 0; k < 8; ++k) {
        af[k] += __shfl_xor(af[k], 16);
        af[k] += __shfl_xor(af[k], 32);
    }
    if (eg == 0) {
        float id = inv_deg[node];
        #pragma unroll
        for (int nt = 0; nt < 8; ++nt)
            aggb[(size_t)node * 128 + nt * 16 + j] = f2b(af[nt] * id);
    }
}

// ---------------- mean pool per graph from bf16 (vectorized, 1 wave) --------
__global__ __launch_bounds__(64)
void pool_mean_b(const unsigned short* __restrict__ src, const int* __restrict__ g_off,
                 const float* __restrict__ inv_cnt, float* __restrict__ out) {
    const int g = blockIdx.x;
    const int lane = threadIdx.x & 63;
    const int j = lane & 15, rs = lane >> 4;
    const int beg = g_off[g], end = g_off[g + 1];
    float s[8] = {0.f, 0.f, 0.f, 0.f, 0.f, 0.f, 0.f, 0.f};
    for (int n = beg + rs; n < end; n += 4) {
        short8 v = *(const short8*)&src[(size_t)n * FF + j * 8];
        #pragma unroll
        for (int i = 0; i < 8; ++i) s[i] += us2f((unsigned short)v[i]);
    }
    #pragma unroll
    for (int i = 0; i < 8; ++i) {
        s[i] += __shfl_xor(s[i], 16);
        s[i] += __shfl_xor(s[i], 32);
    }
    if (rs == 0) {
        float ic = inv_cnt[g];
        #pragma unroll
        for (int i = 0; i < 8; ++i) out[(size_t)g * FF + j * 8 + i] = s[i] * ic;
    }
}

// ---------------- MFMA bf16 GEMM, frag-ordered W from global (L2) ----------
template<bool AB16, bool R1, int RESM, int ACT, bool LN, bool OF32, bool OB16, bool OB8>
__global__ __launch_bounds__(256)
void gemm_mfma(const void* __restrict__ A_,
               const unsigned short* __restrict__ Wf,
               const float* __restrict__ bias,
               const float* __restrict__ rvec, const float* __restrict__ rrow,
               const float* __restrict__ res,
               const float* __restrict__ lng, const float* __restrict__ lnb,
               float* __restrict__ outf, unsigned short* __restrict__ outb,
               unsigned char* __restrict__ outb8, int M) {
    __shared__ short Al[64 * 136];

    const int t = threadIdx.x;
    const int lane = t & 63, wid = t >> 6;
    const int m0 = blockIdx.x * 64;
    const int cb = lane & 15, rq = lane >> 4;

    if (AB16) {
        const unsigned short* Ab = (const unsigned short*)A_;
        for (int i = t; i < 1024; i += 256) {
            int row = i >> 4, seg = i & 15;
            int gr = m0 + row; if (gr >= M) gr = M - 1;
            *(uint4*)&Al[row * 136 + seg * 8] = *(const uint4*)&Ab[(size_t)gr * 128 + seg * 8];
        }
    } else {
        const float* Af = (const float*)A_;
        for (int i = t; i < 2048; i += 256) {
            int row = i >> 5, seg = i & 31;
            int gr = m0 + row; if (gr >= M) gr = M - 1;
            float4 v = *(const float4*)&Af[(size_t)gr * 128 + seg * 4];
            ushort4 o = {f2b(v.x), f2b(v.y), f2b(v.z), f2b(v.w)};
            *(ushort4*)&Al[row * 136 + seg * 4] = o;
        }
    }
    __syncthreads();

    f32x4 acc[8];
    #pragma unroll
    for (int nt = 0; nt < 8; ++nt) acc[nt] = (f32x4){0.f, 0.f, 0.f, 0.f};

    const int aoff_base = (wid * 16 + cb) * 136 + rq * 8;
    for (int kc = 0; kc < 4; ++kc) {
        short8 a0 = *(const short8*)&Al[aoff_base + kc * 32];
        #pragma unroll
        for (int nt = 0; nt < 8; ++nt) {
            short8 b0 = *(const short8*)&Wf[(size_t)(kc * 8 + nt) * 512 + lane * 8];
            acc[nt] = MFMA(a0, b0, acc[nt]);
        }
    }

    float bs[8], rr[8], lg[8], lb[8];
    #pragma unroll
    for (int nt = 0; nt < 8; ++nt) {
        int col = nt * 16 + cb;
        bs[nt] = bias[col];
        if (R1) rr[nt] = rrow[col];
        if (LN) { lg[nt] = lng[col]; lb[nt] = lnb[col]; }
    }
    #pragma unroll
    for (int reg = 0; reg < 4; ++reg) {
        int m = m0 + wid * 16 + rq * 4 + reg;
        int mc = m < M ? m : M - 1;
        float v[8];
        #pragma unroll
        for (int nt = 0; nt < 8; ++nt) v[nt] = acc[nt][reg] + bs[nt];
        if (R1) {
            float rv = rvec[mc];
            #pragma unroll
            for (int nt = 0; nt < 8; ++nt) v[nt] += rv * rr[nt];
        }
        if (RESM == 1) {
            #pragma unroll
            for (int nt = 0; nt < 8; ++nt) v[nt] += res[(size_t)mc * 128 + nt * 16 + cb];
        }
        if (ACT == 1) {
            #pragma unroll
            for (int nt = 0; nt < 8; ++nt) v[nt] = fast_elu(v[nt]);
        }
        if (LN) {
            float s1 = 0.f, s2 = 0.f;
            #pragma unroll
            for (int nt = 0; nt < 8; ++nt) { s1 += v[nt]; s2 += v[nt] * v[nt]; }
            #pragma unroll
            for (int o = 8; o >= 1; o >>= 1) { s1 += __shfl_xor(s1, o); s2 += __shfl_xor(s2, o); }
            float mu = s1 * (1.f / 128.f);
            float rs = rsqrtf(s2 * (1.f / 128.f) - mu * mu + 1e-5f);
            #pragma unroll
            for (int nt = 0; nt < 8; ++nt) v[nt] = (v[nt] - mu) * rs * lg[nt] + lb[nt];
        }
        if (m < M) {
            #pragma unroll
            for (int nt = 0; nt < 8; ++nt) {
                size_t o = (size_t)m * 128 + nt * 16 + cb;
                if (OF32) outf[o] = v[nt];
                if (OB16) outb[o] = f2b(v[nt]);
            }
            if (OB8) *(uint2*)&outb8[(size_t)m * 128 + cb * 8] = pk8(v);
        }
    }
}

// ---------------- fused GEMM chain: W from L2 (frag order), ONE barrier -----
// (R3-measured form: 4 waves/block, y1 residual in regs, no launch bound cap)
__global__ __launch_bounds__(256)
void gc_chain(const unsigned short* __restrict__ hin, const unsigned short* __restrict__ aggb,
              unsigned short* __restrict__ hout, unsigned char* __restrict__ h8out,
              const unsigned short* __restrict__ Wl_f, const unsigned short* __restrict__ Wr_f,
              const unsigned short* __restrict__ W1_f, const unsigned short* __restrict__ W2_f,
              const float* __restrict__ bl,
              const float* __restrict__ g1, const float* __restrict__ b1,
              const float* __restrict__ bb1, const float* __restrict__ bb2,
              const float* __restrict__ g2, const float* __restrict__ b2, int M) {
    __shared__ short Hl[64 * 136];     // h tile -> y1 tile
    __shared__ short Gl[64 * 136];     // agg tile -> elu(t) tile

    const int t = threadIdx.x;
    const int lane = t & 63, wid = t >> 6;
    const int m0 = blockIdx.x * 64;
    const int cb = lane & 15, rq = lane >> 4;
    const int aoff_base = (wid * 16 + cb) * 136 + rq * 8;
    const int boff = lane * 8;

    for (int i = t; i < 1024; i += 256) {
        int row = i >> 4, seg = i & 15;
        int gr = m0 + row; if (gr >= M) gr = M - 1;
        *(uint4*)&Hl[row * 136 + seg * 8] = *(const uint4*)&hin[(size_t)gr * 128 + seg * 8];
        *(uint4*)&Gl[row * 136 + seg * 8] = *(const uint4*)&aggb[(size_t)gr * 128 + seg * 8];
    }
    __syncthreads();   // the only barrier

    f32x4 acc[8];
    #pragma unroll
    for (int nt = 0; nt < 8; ++nt) acc[nt] = (f32x4){0.f, 0.f, 0.f, 0.f};

    // ---- dual GEMM: acc = agg@Wl + h@Wr ----
    for (int kc = 0; kc < 4; ++kc) {
        short8 a0 = *(const short8*)&Gl[aoff_base + kc * 32];
        short8 a1 = *(const short8*)&Hl[aoff_base + kc * 32];
        #pragma unroll
        for (int nt = 0; nt < 8; ++nt) {
            const size_t wo = (size_t)(kc * 8 + nt) * 512 + boff;
            acc[nt] = MFMA(a0, *(const short8*)&Wl_f[wo], acc[nt]);
            acc[nt] = MFMA(a1, *(const short8*)&Wr_f[wo], acc[nt]);
        }
    }

    // ---- epilogue 1 (band-local): y1 = LN1(acc + bl + h) -> Hl + regs ----
    float y1r[4][8];
    {
        float bs[8], lg[8], lb[8];
        #pragma unroll
        for (int nt = 0; nt < 8; ++nt) {
            int col = nt * 16 + cb;
            bs[nt] = bl[col]; lg[nt] = g1[col]; lb[nt] = b1[col];
        }
        #pragma unroll
        for (int reg = 0; reg < 4; ++reg) {
            int r = wid * 16 + rq * 4 + reg;
            float v[8];
            float s1 = 0.f, s2 = 0.f;
            #pragma unroll
            for (int nt = 0; nt < 8; ++nt) {
                v[nt] = acc[nt][reg] + bs[nt] + us2f((unsigned short)Hl[r * 136 + nt * 16 + cb]);
                s1 += v[nt]; s2 += v[nt] * v[nt];
            }
            #pragma unroll
            for (int o = 8; o >= 1; o >>= 1) { s1 += __shfl_xor(s1, o); s2 += __shfl_xor(s2, o); }
            float mu = s1 * (1.f / 128.f);
            float rs = rsqrtf(s2 * (1.f / 128.f) - mu * mu + 1e-5f);
            #pragma unroll
            for (int nt = 0; nt < 8; ++nt) {
                float y = (v[nt] - mu) * rs * lg[nt] + lb[nt];
                y1r[reg][nt] = y;
                Hl[r * 136 + nt * 16 + cb] = (short)f2b(y);
            }
        }
    }

    // ---- FF1 (band-local): t = elu(y1@W1 + bb1) -> Gl ----
    #pragma unroll
    for (int nt = 0; nt < 8; ++nt) acc[nt] = (f32x4){0.f, 0.f, 0.f, 0.f};
    for (int kc = 0; kc < 4; ++kc) {
        short8 a0 = *(const short8*)&Hl[aoff_base + kc * 32];
        #pragma unroll
        for (int nt = 0; nt < 8; ++nt)
            acc[nt] = MFMA(a0, *(const short8*)&W1_f[(size_t)(kc * 8 + nt) * 512 + boff], acc[nt]);
    }
    {
        float bs[8];
        #pragma unroll
        for (int nt = 0; nt < 8; ++nt) bs[nt] = bb1[nt * 16 + cb];
        #pragma unroll
        for (int reg = 0; reg < 4; ++reg) {
            int r = wid * 16 + rq * 4 + reg;
            #pragma unroll
            for (int nt = 0; nt < 8; ++nt) {
                float v = fast_elu(acc[nt][reg] + bs[nt]);
                Gl[r * 136 + nt * 16 + cb] = (short)f2b(v);
            }
        }
    }

    // ---- FF2 (band-local): h' = LN2(t@W2 + bb2 + y1) -> global bf16 + fp8 --
    #pragma unroll
    for (int nt = 0; nt < 8; ++nt) acc[nt] = (f32x4){0.f, 0.f, 0.f, 0.f};
    for (int kc = 0; kc < 4; ++kc) {
        short8 a0 = *(const short8*)&Gl[aoff_base + kc * 32];
        #pragma unroll
        for (int nt = 0; nt < 8; ++nt)
            acc[nt] = MFMA(a0, *(const short8*)&W2_f[(size_t)(kc * 8 + nt) * 512 + boff], acc[nt]);
    }
    {
        float bs[8], lg[8], lb[8];
        #pragma unroll
        for (int nt = 0; nt < 8; ++nt) {
            int col = nt * 16 + cb;
            bs[nt] = bb2[col]; lg[nt] = g2[col]; lb[nt] = b2[col];
        }
        #pragma unroll
        for (int reg = 0; reg < 4; ++reg) {
            int r = wid * 16 + rq * 4 + reg;
            int m = m0 + r;
            float v[8];
            float s1 = 0.f, s2 = 0.f;
            #pragma unroll
            for (int nt = 0; nt < 8; ++nt) {
                v[nt] = acc[nt][reg] + bs[nt] + y1r[reg][nt];
                s1 += v[nt]; s2 += v[nt] * v[nt];
            }
            #pragma unroll
            for (int o = 8; o >= 1; o >>= 1) { s1 += __shfl_xor(s1, o); s2 += __shfl_xor(s2, o); }
            float mu = s1 * (1.f / 128.f);
            float rs = rsqrtf(s2 * (1.f / 128.f) - mu * mu + 1e-5f);
            if (m < M) {
                float fv[8];
                #pragma unroll
                for (int nt = 0; nt < 8; ++nt) {
                    fv[nt] = (v[nt] - mu) * rs * lg[nt] + lb[nt];
                    hout[(size_t)m * 128 + nt * 16 + cb] = f2b(fv[nt]);
                }
                *(uint2*)&h8out[(size_t)m * 128 + cb * 8] = pk8(fv);
            }
        }
    }
}

// ---------------- fused head: LN1 -> elu FF -> res+LN2, one launch ---------
__global__ __launch_bounds__(256)
void head_chain(const float* __restrict__ gm,
                const unsigned short* __restrict__ Wa_f,
                const unsigned short* __restrict__ P1_f,
                const unsigned short* __restrict__ P2_f,
                const float* __restrict__ mdfb,
                const float* __restrict__ g1, const float* __restrict__ b1,
                const float* __restrict__ p1b, const float* __restrict__ p2b,
                const float* __restrict__ g2, const float* __restrict__ b2,
                float* __restrict__ outp) {
    __shared__ short Al[64 * 136];

    const int t = threadIdx.x;
    const int lane = t & 63, wid = t >> 6;
    const int m0 = blockIdx.x * 64;
    const int cb = lane & 15, rq = lane >> 4;
    const int aoff_base = (wid * 16 + cb) * 136 + rq * 8;
    const int boff = lane * 8;

    for (int i = t; i < 2048; i += 256) {
        int row = i >> 5, seg = i & 31;
        float4 v = *(const float4*)&gm[(size_t)(m0 + row) * 128 + seg * 4];
        ushort4 o = {f2b(v.x), f2b(v.y), f2b(v.z), f2b(v.w)};
        *(ushort4*)&Al[row * 136 + seg * 4] = o;
    }
    __syncthreads();

    f32x4 acc[8];
    // ---- GEMM1: gm@Wa + mdfb, LN1 -> y1r + Al ----
    #pragma unroll
    for (int nt = 0; nt < 8; ++nt) acc[nt] = (f32x4){0.f, 0.f, 0.f, 0.f};
    for (int kc = 0; kc < 4; ++kc) {
        short8 a0 = *(const short8*)&Al[aoff_base + kc * 32];
        #pragma unroll
        for (int nt = 0; nt < 8; ++nt)
            acc[nt] = MFMA(a0, *(const short8*)&Wa_f[(size_t)(kc * 8 + nt) * 512 + boff], acc[nt]);
    }
    float y1r[4][8];
    {
        float bs[8], lg[8], lb[8];
        #pragma unroll
        for (int nt = 0; nt < 8; ++nt) {
            int col = nt * 16 + cb;
            bs[nt] = mdfb[col]; lg[nt] = g1[col]; lb[nt] = b1[col];
        }
        #pragma unroll
        for (int reg = 0; reg < 4; ++reg) {
            int r = wid * 16 + rq * 4 + reg;
            float v[8];
            float s1 = 0.f, s2 = 0.f;
            #pragma unroll
            for (int nt = 0; nt < 8; ++nt) {
                v[nt] = acc[nt][reg] + bs[nt];
                s1 += v[nt]; s2 += v[nt] * v[nt];
            }
            #pragma unroll
            for (int o = 8; o >= 1; o >>= 1) { s1 += __shfl_xor(s1, o); s2 += __shfl_xor(s2, o); }
            float mu = s1 * (1.f / 128.f);
            float rs = rsqrtf(s2 * (1.f / 128.f) - mu * mu + 1e-5f);
            #pragma unroll
            for (int nt = 0; nt < 8; ++nt) {
                float y = (v[nt] - mu) * rs * lg[nt] + lb[nt];
                y1r[reg][nt] = y;
                Al[r * 136 + nt * 16 + cb] = (short)f2b(y);
            }
        }
    }

    // ---- GEMM2: elu(y1@P1 + p1b) -> Al ----
    #pragma unroll
    for (int nt = 0; nt < 8; ++nt) acc[nt] = (f32x4){0.f, 0.f, 0.f, 0.f};
    for (int kc = 0; kc < 4; ++kc) {
        short8 a0 = *(const short8*)&Al[aoff_base + kc * 32];
        #pragma unroll
        for (int nt = 0; nt < 8; ++nt)
            acc[nt] = MFMA(a0, *(const short8*)&P1_f[(size_t)(kc * 8 + nt) * 512 + boff], acc[nt]);
    }
    {
        float bs[8];
        #pragma unroll
        for (int nt = 0; nt < 8; ++nt) bs[nt] = p1b[nt * 16 + cb];
        #pragma unroll
        for (int reg = 0; reg < 4; ++reg) {
            int r = wid * 16 + rq * 4 + reg;
            #pragma unroll
            for (int nt = 0; nt < 8; ++nt) {
                float v = fast_elu(acc[nt][reg] + bs[nt]);
                Al[r * 136 + nt * 16 + cb] = (short)f2b(v);
            }
        }
    }

    // ---- GEMM3: LN2(t@P2 + p2b + y1r) -> out fp32 ----
    #pragma unroll
    for (int nt = 0; nt < 8; ++nt) acc[nt] = (f32x4){0.f, 0.f, 0.f, 0.f};
    for (int kc = 0; kc < 4; ++kc) {
        short8 a0 = *(const short8*)&Al[aoff_base + kc * 32];
        #pragma unroll
        for (int nt = 0; nt < 8; ++nt)
            acc[nt] = MFMA(a0, *(const short8*)&P2_f[(size_t)(kc * 8 + nt) * 512 + boff], acc[nt]);
    }
    {
        float bs[8], lg[8], lb[8];
        #pragma unroll
        for (int nt = 0; nt < 8; ++nt) {
            int col = nt * 16 + cb;
            bs[nt] = p2b[col]; lg[nt] = g2[col]; lb[nt] = b2[col];
        }
        #pragma unroll
        for (int reg = 0; reg < 4; ++reg) {
            int r = wid * 16 + rq * 4 + reg;
            int m = m0 + r;
            float v[8];
            float s1 = 0.f, s2 = 0.f;
            #pragma unroll
            for (int nt = 0; nt < 8; ++nt) {
                v[nt] = acc[nt][reg] + bs[nt] + y1r[reg][nt];
                s1 += v[nt]; s2 += v[nt] * v[nt];
            }
            #pragma unroll
            for (int o = 8; o >= 1; o >>= 1) { s1 += __shfl_xor(s1, o); s2 += __shfl_xor(s2, o); }
            float mu = s1 * (1.f / 128.f);
            float rs = rsqrtf(s2 * (1.f / 128.f) - mu * mu + 1e-5f);
            #pragma unroll
            for (int nt = 0; nt < 8; ++nt)
                outp[(size_t)m * 128 + nt * 16 + cb] = (v[nt] - mu) * rs * lg[nt] + lb[nt];
        }
    }
}

extern "C" void kernel_launch(void* const* d_in, const int* in_sizes, int n_in,
                              void* d_out, int out_size, void* d_ws, size_t ws_size,
                              hipStream_t stream) {
    const float* x      = (const float*)d_in[0];
    const float* w      = (const float*)d_in[1];
    const int*   ei     = (const int*)d_in[2];
    const int*   batch  = (const int*)d_in[3];
    const float* W_in   = (const float*)d_in[4];
    const float* b_in   = (const float*)d_in[5];
    const float* sage_Wl = (const float*)d_in[6];
    const float* sage_bl = (const float*)d_in[7];
    const float* sage_Wr = (const float*)d_in[8];
    const float* ln1_g  = (const float*)d_in[9];
    const float* ln1_b  = (const float*)d_in[10];
    const float* lin1_W = (const float*)d_in[11];
    const float* lin1_b = (const float*)d_in[12];
    const float* lin2_W = (const float*)d_in[13];
    const float* lin2_b = (const float*)d_in[14];
    const float* ln2_g  = (const float*)d_in[15];
    const float* ln2_b  = (const float*)d_in[16];
    const float* mdf_W  = (const float*)d_in[17];
    const float* mdf_b  = (const float*)d_in[18];
    const float* pln1_g = (const float*)d_in[19];
    const float* pln1_b = (const float*)d_in[20];
    const float* plin1_W = (const float*)d_in[21];
    const float* plin1_b = (const float*)d_in[22];
    const float* plin2_W = (const float*)d_in[23];
    const float* plin2_b = (const float*)d_in[24];
    const float* pln2_g = (const float*)d_in[25];
    const float* pln2_b = (const float*)d_in[26];
    float* out = (float*)d_out;

    const int* e_src = ei;
    const int* e_dst = ei + NE;

    // ---- workspace layout ----
    float* ws = (float*)d_ws;
    size_t off = 0;
    float* gm    = ws + off; off += (size_t)NG * FF;
    float* hh    = ws + off; off += (size_t)NG * FF;
    float* tt    = ws + off; off += (size_t)NG * FF;
    float* inv_deg = ws + off; off += NN;
    float* inv_cnt = ws + off; off += NG;
    unsigned short* us = (unsigned short*)(ws + off);
    size_t uoff = 0;
    unsigned short* hb0  = us + uoff; uoff += (size_t)NN * FF;
    unsigned short* hb1  = us + uoff; uoff += (size_t)NN * FF;
    unsigned short* aggb = us + uoff; uoff += (size_t)NN * FF;
    unsigned short* wt   = us + uoff; uoff += (size_t)16 * 16384;
    int* iw = (int*)(us + uoff);
    size_t ioff = 0;
    unsigned* pairs = (unsigned*)iw; ioff += (size_t)NBK * BCAP;
    int* ssrc    = iw + ioff; ioff += (size_t)NBK * BCAP;
    int* row_beg = iw + ioff; ioff += NN;
    int* row_end = iw + ioff; ioff += NN;
    int* g_off   = iw + ioff; ioff += NG + 1;
    int* bcur    = iw + ioff; ioff += NBK;
    // h8 (12.8 MB) aliases pairs (12.85 MB): pairs is dead after bucket_build,
    // h8 is first written by the input GEMM which runs after.
    unsigned char* h8 = (unsigned char*)pairs;

    // ---- weight prep (16 matrices -> frag-ordered bf16) ----
    WTab tab;
    tab.a[0] = W_in;
    for (int l = 0; l < 3; ++l) {
        tab.a[1 + l]  = sage_Wl + (size_t)l * 16384;
        tab.a[4 + l]  = sage_Wr + (size_t)l * 16384;
        tab.a[7 + l]  = lin1_W + (size_t)l * 16384;
        tab.a[10 + l] = lin2_W + (size_t)l * 16384;
    }
    tab.a[13] = mdf_W;      // first 128 rows only (Wa)
    tab.a[14] = plin1_W;
    tab.a[15] = plin2_W;
    prep_weights<<<16 * 64, 256, 0, stream>>>(tab, wt);
    const unsigned short* win_t = wt + 0 * 16384;
    const unsigned short* wa_t  = wt + 13 * 16384;
    const unsigned short* p1_t  = wt + 14 * 16384;
    const unsigned short* p2_t  = wt + 15 * 16384;

    // ---- build padded CSR (no histogram pass, no scan) ----
    graph_offsets<<<(NG + 256) / 256, 256, 0, stream>>>(batch, g_off, inv_cnt, bcur);
    radix_scatter<<<RB, 256, 0, stream>>>(e_src, e_dst, bcur, pairs, NE);
    bucket_build<<<NBK, 256, 0, stream>>>(pairs, bcur, row_beg, row_end, inv_deg, ssrc);

    const int GN = (NN + 63) / 64;     // 1563
    const int GB = NG / 64;            // 16

    // ---- input linear: hb0 (bf16) + h8 (fp8, permuted) ----
    gemm_mfma<false, true, 0, 0, false, false, true, true><<<GN, 256, 0, stream>>>(
        x, win_t, b_in, w, W_in + 128 * 128,
        nullptr, nullptr, nullptr, nullptr, hb0, h8, NN);

    // ---- 3 GC blocks: fp8 gather + fused GEMM chain ----
    unsigned short* hcur = hb0;
    unsigned short* hnxt = hb1;
    for (int l = 0; l < 3; ++l) {
        sage_agg<<<NN / 4, 256, 0, stream>>>(h8, row_beg, row_end, inv_deg, ssrc, aggb);
        gc_chain<<<GN, 256, 0, stream>>>(
            hcur, aggb, hnxt, h8,
            wt + (size_t)(1 + l) * 16384, wt + (size_t)(4 + l) * 16384,
            wt + (size_t)(7 + l) * 16384, wt + (size_t)(10 + l) * 16384,
            sage_bl + (size_t)l * FF,
            ln1_g + (size_t)l * FF, ln1_b + (size_t)l * FF,
            lin1_b + (size_t)l * FF, lin2_b + (size_t)l * FF,
            ln2_g + (size_t)l * FF, ln2_b + (size_t)l * FF, NN);
        unsigned short* tmp = hcur; hcur = hnxt; hnxt = tmp;
    }

    // ---- head: pool(h2) -> fused LN1/FF/LN2 chain (one launch) ----
    pool_mean_b<<<NG, 64, 0, stream>>>(hcur, g_off, inv_cnt, gm);
    head_chain<<<GB, 256, 0, stream>>>(
        gm, wa_t, p1_t, p2_t, mdf_b,
        pln1_g, pln1_b, plin1_b, plin2_b, pln2_g, pln2_b, out);
    (void)hh; (void)tt;
}

// Round 10
// 504.471 us; speedup vs baseline: 1.4589x; 1.0185x over previous
//
#include <hip/hip_runtime.h>
#include <math.h>

#define NN 100000
#define NE 1600000
#define NG 1024
#define FF 128
#define BSH 9
#define NBK ((NN + 511) >> BSH)   // 196 buckets of 512 nodes
#define RB 512                    // radix blocks
#define BCAP 16384                // fixed bucket capacity (mean 8192, sigma~90)

typedef __attribute__((ext_vector_type(8))) short short8;
typedef __attribute__((ext_vector_type(4))) float f32x4;
typedef __attribute__((ext_vector_type(2))) float f32x2;

__device__ __forceinline__ unsigned short f2b(float f) {
    union { float f; unsigned u; } v; v.f = f;
    unsigned r = (v.u + 0x7FFF + ((v.u >> 16) & 1)) >> 16;
    return (unsigned short)r;
}
__device__ __forceinline__ float us2f(unsigned short u) {
    union { unsigned u; float f; } v; v.u = ((unsigned)u) << 16; return v.f;
}
// hardware ELU: v_exp_f32 is 2^x; elu(v)=v>0?v:2^(v*log2e)-1.
__device__ __forceinline__ float fast_elu(float v) {
    float e = __builtin_amdgcn_exp2f(v * 1.44269504088896340736f) - 1.0f;
    return v > 0.f ? v : e;
}
// pack 8 floats -> 8 fp8 (uint2), byte i = v[i]
__device__ __forceinline__ uint2 pk8(const float* v) {
    unsigned lo = 0, hi = 0;
    lo = (unsigned)__builtin_amdgcn_cvt_pk_fp8_f32(v[0], v[1], (int)lo, false);
    lo = (unsigned)__builtin_amdgcn_cvt_pk_fp8_f32(v[2], v[3], (int)lo, true);
    hi = (unsigned)__builtin_amdgcn_cvt_pk_fp8_f32(v[4], v[5], (int)hi, false);
    hi = (unsigned)__builtin_amdgcn_cvt_pk_fp8_f32(v[6], v[7], (int)hi, true);
    uint2 r; r.x = lo; r.y = hi; return r;
}
#define MFMA(a, b, c) __builtin_amdgcn_mfma_f32_16x16x32_bf16((a), (b), (c), 0, 0, 0)

// ---------------- pass 1: scatter packed (src<<9|local) into padded buckets -
__global__ __launch_bounds__(256)
void radix_scatter(const int* __restrict__ src, const int* __restrict__ dst,
                   int* __restrict__ bcur, unsigned* __restrict__ pairs, int n) {
    __shared__ int base[NBK];
    __shared__ int cnt[NBK];
    for (int i = threadIdx.x; i < NBK; i += 256) cnt[i] = 0;
    __syncthreads();
    const int per = (n + RB - 1) / RB;
    const int beg = blockIdx.x * per;
    const int end = min(n, beg + per);
    for (int i = beg + threadIdx.x; i < end; i += 256)
        atomicAdd(&cnt[dst[i] >> BSH], 1);
    __syncthreads();
    for (int i = threadIdx.x; i < NBK; i += 256)
        base[i] = cnt[i] ? atomicAdd(&bcur[i], cnt[i]) : 0;
    __syncthreads();
    for (int i = beg + threadIdx.x; i < end; i += 256) {
        int d = dst[i];
        int p = atomicAdd(&base[d >> BSH], 1);
        pairs[p] = ((unsigned)src[i] << BSH) | (unsigned)(d & 511);
    }
}

// ---------------- pass 2: per-bucket hist+scan+scatter -> padded CSR --------
// 512 threads (8 waves): 1 counter/thread, 2x wave parallelism on the two
// streaming passes. ssrc stores PRE-SCALED byte offsets (src*128).
__global__ __launch_bounds__(512)
void bucket_build(const unsigned* __restrict__ pairs, const int* __restrict__ bcur,
                  int* __restrict__ row_beg, int* __restrict__ row_end,
                  float* __restrict__ inv_deg, int* __restrict__ ssrc) {
    __shared__ int cnt[512];
    __shared__ int curs[512];
    __shared__ int wsum[8];
    const int b = blockIdx.x;
    const int n0 = b << BSH;
    const int t = threadIdx.x;
    const int lane = t & 63, wid = t >> 6;

    cnt[t] = 0;
    __syncthreads();
    const int beg = b * BCAP, end = bcur[b];
    for (int i = beg + t; i < end; i += 512)
        atomicAdd(&cnt[pairs[i] & 511], 1);
    __syncthreads();

    int c = cnt[t];
    int x = c;
    #pragma unroll
    for (int o = 1; o < 64; o <<= 1) {
        int y = __shfl_up(x, o);
        if (lane >= o) x += y;
    }
    if (lane == 63) wsum[wid] = x;
    __syncthreads();
    if (t == 0) {
        int s = 0;
        #pragma unroll
        for (int w2 = 0; w2 < 8; ++w2) { int tv = wsum[w2]; wsum[w2] = s; s += tv; }
    }
    __syncthreads();
    int g0 = beg + wsum[wid] + x - c;   // exclusive prefix
    curs[t] = g0;
    {
        int node = n0 + t;
        if (node < NN) {
            row_beg[node] = g0; row_end[node] = g0 + c;
            inv_deg[node] = 1.0f / (float)(c > 1 ? c : 1);
        }
    }
    __syncthreads();
    for (int i = beg + t; i < end; i += 512) {
        unsigned pr = pairs[i];
        int p = atomicAdd(&curs[pr & 511], 1);
        ssrc[p] = (int)(pr >> BSH) << 7;   // pre-scaled byte offset (row*128)
    }
}

// ---------------- graph offsets + bucket-cursor init + ssrc[0] sentinel -----
__global__ __launch_bounds__(256)
void graph_offsets(const int* __restrict__ batch, int* __restrict__ g_off,
                   float* __restrict__ inv_cnt, int* __restrict__ bcur,
                   int* __restrict__ ssrc) {
    int g = blockIdx.x * blockDim.x + threadIdx.x;
    if (g == 0) ssrc[0] = 0;    // sentinel: valid gather offset for masked lanes
    if (g < NBK) bcur[g] = g * BCAP;
    if (g > NG) return;
    if (g == NG) { g_off[NG] = NN; return; }
    int lo = 0, hi = NN;
    while (lo < hi) { int mid = (lo + hi) >> 1; if (batch[mid] < g) lo = mid + 1; else hi = mid; }
    int lo2 = lo, hi2 = NN;
    while (lo2 < hi2) { int mid = (lo2 + hi2) >> 1; if (batch[mid] < g + 1) lo2 = mid + 1; else hi2 = mid; }
    g_off[g] = lo;
    int c = lo2 - lo;
    inv_cnt[g] = 1.0f / (float)(c > 1 ? c : 1);
}

// ---------------- weight prep: fp32 [k][n] -> bf16 MFMA-FRAGMENT order ------
struct WTab { const float* a[16]; };
__global__ __launch_bounds__(256)
void prep_weights(WTab tab, unsigned short* __restrict__ dst) {
    int w = blockIdx.x >> 6;
    int idx = ((blockIdx.x & 63) << 8) + threadIdx.x;
    int j = idx & 7, lane = (idx >> 3) & 63, nt = (idx >> 9) & 7, kc = idx >> 12;
    int cb = lane & 15, rq = lane >> 4;
    int k = kc * 32 + rq * 8 + j;
    int n = nt * 16 + cb;
    dst[(size_t)w * 16384 + idx] = f2b(tab.a[w][k * 128 + n]);
}

// ---------------- SAGE mean aggregation: TWO nodes per wave -----------------
// Each wave owns 2 nodes -> two independent ssrc->gather latency chains in
// flight (2x MLP at constant per-node VALU). 4 edge-groups x 16 col-lanes,
// 8B gathers, predicated batch-of-8 per chain. Masked lanes gather via the
// ssrc[0] sentinel (always a valid h8 row offset).
__global__ __launch_bounds__(256)
void sage_agg(const unsigned char* __restrict__ h8, const int* __restrict__ row_beg,
              const int* __restrict__ row_end, const float* __restrict__ inv_deg,
              const int* __restrict__ ssrc, unsigned short* __restrict__ aggb) {
    const int wid = threadIdx.x >> 6;
    const int lane = threadIdx.x & 63;
    const int n0 = blockIdx.x * 8 + wid * 2;
    const int n1 = n0 + 1;
    const int eg = lane >> 4, j = lane & 15;
    const int jo = j * 8;
    const int beg0 = row_beg[n0], end0 = row_end[n0];
    const int beg1 = row_beg[n1], end1 = row_end[n1];
    f32x2 a0 = {0.f, 0.f}, a1 = {0.f, 0.f}, a2 = {0.f, 0.f}, a3 = {0.f, 0.f};
    f32x2 b0 = {0.f, 0.f}, b1 = {0.f, 0.f}, b2 = {0.f, 0.f}, b3 = {0.f, 0.f};
    int e0 = beg0 + eg, e1 = beg1 + eg;
    const int d0 = end0 - beg0, d1 = end1 - beg1;
    const int nit = ((d0 > d1 ? d0 : d1) + 31) >> 5;
    for (int it = 0; it < nit; ++it, e0 += 32, e1 += 32) {
        uint2 u0[8], u1[8];
        #pragma unroll
        for (int k = 0; k < 8; ++k) {
            int ek = e0 + 4 * k;
            bool ok = ek < end0;
            int idx = ssrc[ok ? ek : 0];
            uint2 uu = *(const uint2*)(h8 + (unsigned)(idx + jo));
            uu.x = ok ? uu.x : 0u;
            uu.y = ok ? uu.y : 0u;                             // fp8 0x00 -> 0.0f
            u0[k] = uu;
        }
        #pragma unroll
        for (int k = 0; k < 8; ++k) {
            int ek = e1 + 4 * k;
            bool ok = ek < end1;
            int idx = ssrc[ok ? ek : 0];
            uint2 uu = *(const uint2*)(h8 + (unsigned)(idx + jo));
            uu.x = ok ? uu.x : 0u;
            uu.y = ok ? uu.y : 0u;
            u1[k] = uu;
        }
        #pragma unroll
        for (int k = 0; k < 8; ++k) {
            a0 += __builtin_amdgcn_cvt_pk_f32_fp8(u0[k].x, false);
            a1 += __builtin_amdgcn_cvt_pk_f32_fp8(u0[k].x, true);
            a2 += __builtin_amdgcn_cvt_pk_f32_fp8(u0[k].y, false);
            a3 += __builtin_amdgcn_cvt_pk_f32_fp8(u0[k].y, true);
            b0 += __builtin_amdgcn_cvt_pk_f32_fp8(u1[k].x, false);
            b1 += __builtin_amdgcn_cvt_pk_f32_fp8(u1[k].x, true);
            b2 += __builtin_amdgcn_cvt_pk_f32_fp8(u1[k].y, false);
            b3 += __builtin_amdgcn_cvt_pk_f32_fp8(u1[k].y, true);
        }
    }
    float af[8] = {a0.x, a0.y, a1.x, a1.y, a2.x, a2.y, a3.x, a3.y};
    float bf[8] = {b0.x, b0.y, b1.x, b1.y, b2.x, b2.y, b3.x, b3.y};
    #pragma unroll
    for (int k = 0; k < 8; ++k) {
        af[k] += __shfl_xor(af[k], 16);
        af[k] += __shfl_xor(af[k], 32);
        bf[k] += __shfl_xor(bf[k], 16);
        bf[k] += __shfl_xor(bf[k], 32);
    }
    if (eg == 0) {
        float id0 = inv_deg[n0];
        float id1 = inv_deg[n1];
        #pragma unroll
        for (int nt = 0; nt < 8; ++nt) {
            aggb[(size_t)n0 * 128 + nt * 16 + j] = f2b(af[nt] * id0);
            aggb[(size_t)n1 * 128 + nt * 16 + j] = f2b(bf[nt] * id1);
        }
    }
}

// ---------------- mean pool per graph from bf16 (4 waves + LDS reduce) ------
__global__ __launch_bounds__(256)
void pool_mean_b(const unsigned short* __restrict__ src, const int* __restrict__ g_off,
                 const float* __restrict__ inv_cnt, float* __restrict__ out) {
    __shared__ float red[3][128];
    const int g = blockIdx.x;
    const int t = threadIdx.x;
    const int lane = t & 63, wid = t >> 6;
    const int j = lane & 15, rs = lane >> 4;
    const int beg = g_off[g], end = g_off[g + 1];
    float s[8] = {0.f, 0.f, 0.f, 0.f, 0.f, 0.f, 0.f, 0.f};
    for (int n = beg + rs + wid * 4; n < end; n += 16) {
        short8 v = *(const short8*)&src[(size_t)n * FF + j * 8];
        #pragma unroll
        for (int i = 0; i < 8; ++i) s[i] += us2f((unsigned short)v[i]);
    }
    #pragma unroll
    for (int i = 0; i < 8; ++i) {
        s[i] += __shfl_xor(s[i], 16);
        s[i] += __shfl_xor(s[i], 32);
    }
    if (wid > 0 && rs == 0) {
        #pragma unroll
        for (int i = 0; i < 8; ++i) red[wid - 1][j * 8 + i] = s[i];
    }
    __syncthreads();
    if (wid == 0 && rs == 0) {
        float ic = inv_cnt[g];
        #pragma unroll
        for (int i = 0; i < 8; ++i) {
            float v = s[i] + red[0][j * 8 + i] + red[1][j * 8 + i] + red[2][j * 8 + i];
            out[(size_t)g * FF + j * 8 + i] = v * ic;
        }
    }
}

// ---------------- MFMA bf16 GEMM, frag-ordered W from global (L2) ----------
template<bool AB16, bool R1, int RESM, int ACT, bool LN, bool OF32, bool OB16, bool OB8>
__global__ __launch_bounds__(256)
void gemm_mfma(const void* __restrict__ A_,
               const unsigned short* __restrict__ Wf,
               const float* __restrict__ bias,
               const float* __restrict__ rvec, const float* __restrict__ rrow,
               const float* __restrict__ res,
               const float* __restrict__ lng, const float* __restrict__ lnb,
               float* __restrict__ outf, unsigned short* __restrict__ outb,
               unsigned char* __restrict__ outb8, int M) {
    __shared__ short Al[64 * 136];

    const int t = threadIdx.x;
    const int lane = t & 63, wid = t >> 6;
    const int m0 = blockIdx.x * 64;
    const int cb = lane & 15, rq = lane >> 4;

    if (AB16) {
        const unsigned short* Ab = (const unsigned short*)A_;
        for (int i = t; i < 1024; i += 256) {
            int row = i >> 4, seg = i & 15;
            int gr = m0 + row; if (gr >= M) gr = M - 1;
            *(uint4*)&Al[row * 136 + seg * 8] = *(const uint4*)&Ab[(size_t)gr * 128 + seg * 8];
        }
    } else {
        const float* Af = (const float*)A_;
        for (int i = t; i < 2048; i += 256) {
            int row = i >> 5, seg = i & 31;
            int gr = m0 + row; if (gr >= M) gr = M - 1;
            float4 v = *(const float4*)&Af[(size_t)gr * 128 + seg * 4];
            ushort4 o = {f2b(v.x), f2b(v.y), f2b(v.z), f2b(v.w)};
            *(ushort4*)&Al[row * 136 + seg * 4] = o;
        }
    }
    __syncthreads();

    f32x4 acc[8];
    #pragma unroll
    for (int nt = 0; nt < 8; ++nt) acc[nt] = (f32x4){0.f, 0.f, 0.f, 0.f};

    const int aoff_base = (wid * 16 + cb) * 136 + rq * 8;
    for (int kc = 0; kc < 4; ++kc) {
        short8 a0 = *(const short8*)&Al[aoff_base + kc * 32];
        #pragma unroll
        for (int nt = 0; nt < 8; ++nt) {
            short8 b0 = *(const short8*)&Wf[(size_t)(kc * 8 + nt) * 512 + lane * 8];
            acc[nt] = MFMA(a0, b0, acc[nt]);
        }
    }

    float bs[8], rr[8], lg[8], lb[8];
    #pragma unroll
    for (int nt = 0; nt < 8; ++nt) {
        int col = nt * 16 + cb;
        bs[nt] = bias[col];
        if (R1) rr[nt] = rrow[col];
        if (LN) { lg[nt] = lng[col]; lb[nt] = lnb[col]; }
    }
    #pragma unroll
    for (int reg = 0; reg < 4; ++reg) {
        int m = m0 + wid * 16 + rq * 4 + reg;
        int mc = m < M ? m : M - 1;
        float v[8];
        #pragma unroll
        for (int nt = 0; nt < 8; ++nt) v[nt] = acc[nt][reg] + bs[nt];
        if (R1) {
            float rv = rvec[mc];
            #pragma unroll
            for (int nt = 0; nt < 8; ++nt) v[nt] += rv * rr[nt];
        }
        if (RESM == 1) {
            #pragma unroll
            for (int nt = 0; nt < 8; ++nt) v[nt] += res[(size_t)mc * 128 + nt * 16 + cb];
        }
        if (ACT == 1) {
            #pragma unroll
            for (int nt = 0; nt < 8; ++nt) v[nt] = fast_elu(v[nt]);
        }
        if (LN) {
            float s1 = 0.f, s2 = 0.f;
            #pragma unroll
            for (int nt = 0; nt < 8; ++nt) { s1 += v[nt]; s2 += v[nt] * v[nt]; }
            #pragma unroll
            for (int o = 8; o >= 1; o >>= 1) { s1 += __shfl_xor(s1, o); s2 += __shfl_xor(s2, o); }
            float mu = s1 * (1.f / 128.f);
            float rs = rsqrtf(s2 * (1.f / 128.f) - mu * mu + 1e-5f);
            #pragma unroll
            for (int nt = 0; nt < 8; ++nt) v[nt] = (v[nt] - mu) * rs * lg[nt] + lb[nt];
        }
        if (m < M) {
            #pragma unroll
            for (int nt = 0; nt < 8; ++nt) {
                size_t o = (size_t)m * 128 + nt * 16 + cb;
                if (OF32) outf[o] = v[nt];
                if (OB16) outb[o] = f2b(v[nt]);
            }
            if (OB8) *(uint2*)&outb8[(size_t)m * 128 + cb * 8] = pk8(v);
        }
    }
}

// ---------------- fused GEMM chain: W from L2 (frag order), ONE barrier -----
// (R3-measured form: 4 waves/block, y1 residual in regs, no launch bound cap)
__global__ __launch_bounds__(256)
void gc_chain(const unsigned short* __restrict__ hin, const unsigned short* __restrict__ aggb,
              unsigned short* __restrict__ hout, unsigned char* __restrict__ h8out,
              const unsigned short* __restrict__ Wl_f, const unsigned short* __restrict__ Wr_f,
              const unsigned short* __restrict__ W1_f, const unsigned short* __restrict__ W2_f,
              const float* __restrict__ bl,
              const float* __restrict__ g1, const float* __restrict__ b1,
              const float* __restrict__ bb1, const float* __restrict__ bb2,
              const float* __restrict__ g2, const float* __restrict__ b2, int M) {
    __shared__ short Hl[64 * 136];     // h tile -> y1 tile
    __shared__ short Gl[64 * 136];     // agg tile -> elu(t) tile

    const int t = threadIdx.x;
    const int lane = t & 63, wid = t >> 6;
    const int m0 = blockIdx.x * 64;
    const int cb = lane & 15, rq = lane >> 4;
    const int aoff_base = (wid * 16 + cb) * 136 + rq * 8;
    const int boff = lane * 8;

    for (int i = t; i < 1024; i += 256) {
        int row = i >> 4, seg = i & 15;
        int gr = m0 + row; if (gr >= M) gr = M - 1;
        *(uint4*)&Hl[row * 136 + seg * 8] = *(const uint4*)&hin[(size_t)gr * 128 + seg * 8];
        *(uint4*)&Gl[row * 136 + seg * 8] = *(const uint4*)&aggb[(size_t)gr * 128 + seg * 8];
    }
    __syncthreads();   // the only barrier

    f32x4 acc[8];
    #pragma unroll
    for (int nt = 0; nt < 8; ++nt) acc[nt] = (f32x4){0.f, 0.f, 0.f, 0.f};

    // ---- dual GEMM: acc = agg@Wl + h@Wr ----
    for (int kc = 0; kc < 4; ++kc) {
        short8 a0 = *(const short8*)&Gl[aoff_base + kc * 32];
        short8 a1 = *(const short8*)&Hl[aoff_base + kc * 32];
        #pragma unroll
        for (int nt = 0; nt < 8; ++nt) {
            const size_t wo = (size_t)(kc * 8 + nt) * 512 + boff;
            acc[nt] = MFMA(a0, *(const short8*)&Wl_f[wo], acc[nt]);
            acc[nt] = MFMA(a1, *(const short8*)&Wr_f[wo], acc[nt]);
        }
    }

    // ---- epilogue 1 (band-local): y1 = LN1(acc + bl + h) -> Hl + regs ----
    float y1r[4][8];
    {
        float bs[8], lg[8], lb[8];
        #pragma unroll
        for (int nt = 0; nt < 8; ++nt) {
            int col = nt * 16 + cb;
            bs[nt] = bl[col]; lg[nt] = g1[col]; lb[nt] = b1[col];
        }
        #pragma unroll
        for (int reg = 0; reg < 4; ++reg) {
            int r = wid * 16 + rq * 4 + reg;
            float v[8];
            float s1 = 0.f, s2 = 0.f;
            #pragma unroll
            for (int nt = 0; nt < 8; ++nt) {
                v[nt] = acc[nt][reg] + bs[nt] + us2f((unsigned short)Hl[r * 136 + nt * 16 + cb]);
                s1 += v[nt]; s2 += v[nt] * v[nt];
            }
            #pragma unroll
            for (int o = 8; o >= 1; o >>= 1) { s1 += __shfl_xor(s1, o); s2 += __shfl_xor(s2, o); }
            float mu = s1 * (1.f / 128.f);
            float rs = rsqrtf(s2 * (1.f / 128.f) - mu * mu + 1e-5f);
            #pragma unroll
            for (int nt = 0; nt < 8; ++nt) {
                float y = (v[nt] - mu) * rs * lg[nt] + lb[nt];
                y1r[reg][nt] = y;
                Hl[r * 136 + nt * 16 + cb] = (short)f2b(y);
            }
        }
    }

    // ---- FF1 (band-local): t = elu(y1@W1 + bb1) -> Gl ----
    #pragma unroll
    for (int nt = 0; nt < 8; ++nt) acc[nt] = (f32x4){0.f, 0.f, 0.f, 0.f};
    for (int kc = 0; kc < 4; ++kc) {
        short8 a0 = *(const short8*)&Hl[aoff_base + kc * 32];
        #pragma unroll
        for (int nt = 0; nt < 8; ++nt)
            acc[nt] = MFMA(a0, *(const short8*)&W1_f[(size_t)(kc * 8 + nt) * 512 + boff], acc[nt]);
    }
    {
        float bs[8];
        #pragma unroll
        for (int nt = 0; nt < 8; ++nt) bs[nt] = bb1[nt * 16 + cb];
        #pragma unroll
        for (int reg = 0; reg < 4; ++reg) {
            int r = wid * 16 + rq * 4 + reg;
            #pragma unroll
            for (int nt = 0; nt < 8; ++nt) {
                float v = fast_elu(acc[nt][reg] + bs[nt]);
                Gl[r * 136 + nt * 16 + cb] = (short)f2b(v);
            }
        }
    }

    // ---- FF2 (band-local): h' = LN2(t@W2 + bb2 + y1) -> global bf16 + fp8 --
    #pragma unroll
    for (int nt = 0; nt < 8; ++nt) acc[nt] = (f32x4){0.f, 0.f, 0.f, 0.f};
    for (int kc = 0; kc < 4; ++kc) {
        short8 a0 = *(const short8*)&Gl[aoff_base + kc * 32];
        #pragma unroll
        for (int nt = 0; nt < 8; ++nt)
            acc[nt] = MFMA(a0, *(const short8*)&W2_f[(size_t)(kc * 8 + nt) * 512 + boff], acc[nt]);
    }
    {
        float bs[8], lg[8], lb[8];
        #pragma unroll
        for (int nt = 0; nt < 8; ++nt) {
            int col = nt * 16 + cb;
            bs[nt] = bb2[col]; lg[nt] = g2[col]; lb[nt] = b2[col];
        }
        #pragma unroll
        for (int reg = 0; reg < 4; ++reg) {
            int r = wid * 16 + rq * 4 + reg;
            int m = m0 + r;
            float v[8];
            float s1 = 0.f, s2 = 0.f;
            #pragma unroll
            for (int nt = 0; nt < 8; ++nt) {
                v[nt] = acc[nt][reg] + bs[nt] + y1r[reg][nt];
                s1 += v[nt]; s2 += v[nt] * v[nt];
            }
            #pragma unroll
            for (int o = 8; o >= 1; o >>= 1) { s1 += __shfl_xor(s1, o); s2 += __shfl_xor(s2, o); }
            float mu = s1 * (1.f / 128.f);
            float rs = rsqrtf(s2 * (1.f / 128.f) - mu * mu + 1e-5f);
            if (m < M) {
                float fv[8];
                #pragma unroll
                for (int nt = 0; nt < 8; ++nt) {
                    fv[nt] = (v[nt] - mu) * rs * lg[nt] + lb[nt];
                    hout[(size_t)m * 128 + nt * 16 + cb] = f2b(fv[nt]);
                }
                *(uint2*)&h8out[(size_t)m * 128 + cb * 8] = pk8(fv);
            }
        }
    }
}

// ---------------- fused head: LN1 -> elu FF -> res+LN2, one launch ---------
__global__ __launch_bounds__(256)
void head_chain(const float* __restrict__ gm,
                const unsigned short* __restrict__ Wa_f,
                const unsigned short* __restrict__ P1_f,
                const unsigned short* __restrict__ P2_f,
                const float* __restrict__ mdfb,
                const float* __restrict__ g1, const float* __restrict__ b1,
                const float* __restrict__ p1b, const float* __restrict__ p2b,
                const float* __restrict__ g2, const float* __restrict__ b2,
                float* __restrict__ outp) {
    __shared__ short Al[64 * 136];

    const int t = threadIdx.x;
    const int lane = t & 63, wid = t >> 6;
    const int m0 = blockIdx.x * 64;
    const int cb = lane & 15, rq = lane >> 4;
    const int aoff_base = (wid * 16 + cb) * 136 + rq * 8;
    const int boff = lane * 8;

    for (int i = t; i < 2048; i += 256) {
        int row = i >> 5, seg = i & 31;
        float4 v = *(const float4*)&gm[(size_t)(m0 + row) * 128 + seg * 4];
        ushort4 o = {f2b(v.x), f2b(v.y), f2b(v.z), f2b(v.w)};
        *(ushort4*)&Al[row * 136 + seg * 4] = o;
    }
    __syncthreads();

    f32x4 acc[8];
    // ---- GEMM1: gm@Wa + mdfb, LN1 -> y1r + Al ----
    #pragma unroll
    for (int nt = 0; nt < 8; ++nt) acc[nt] = (f32x4){0.f, 0.f, 0.f, 0.f};
    for (int kc = 0; kc < 4; ++kc) {
        short8 a0 = *(const short8*)&Al[aoff_base + kc * 32];
        #pragma unroll
        for (int nt = 0; nt < 8; ++nt)
            acc[nt] = MFMA(a0, *(const short8*)&Wa_f[(size_t)(kc * 8 + nt) * 512 + boff], acc[nt]);
    }
    float y1r[4][8];
    {
        float bs[8], lg[8], lb[8];
        #pragma unroll
        for (int nt = 0; nt < 8; ++nt) {
            int col = nt * 16 + cb;
            bs[nt] = mdfb[col]; lg[nt] = g1[col]; lb[nt] = b1[col];
        }
        #pragma unroll
        for (int reg = 0; reg < 4; ++reg) {
            int r = wid * 16 + rq * 4 + reg;
            float v[8];
            float s1 = 0.f, s2 = 0.f;
            #pragma unroll
            for (int nt = 0; nt < 8; ++nt) {
                v[nt] = acc[nt][reg] + bs[nt];
                s1 += v[nt]; s2 += v[nt] * v[nt];
            }
            #pragma unroll
            for (int o = 8; o >= 1; o >>= 1) { s1 += __shfl_xor(s1, o); s2 += __shfl_xor(s2, o); }
            float mu = s1 * (1.f / 128.f);
            float rs = rsqrtf(s2 * (1.f / 128.f) - mu * mu + 1e-5f);
            #pragma unroll
            for (int nt = 0; nt < 8; ++nt) {
                float y = (v[nt] - mu) * rs * lg[nt] + lb[nt];
                y1r[reg][nt] = y;
                Al[r * 136 + nt * 16 + cb] = (short)f2b(y);
            }
        }
    }

    // ---- GEMM2: elu(y1@P1 + p1b) -> Al ----
    #pragma unroll
    for (int nt = 0; nt < 8; ++nt) acc[nt] = (f32x4){0.f, 0.f, 0.f, 0.f};
    for (int kc = 0; kc < 4; ++kc) {
        short8 a0 = *(const short8*)&Al[aoff_base + kc * 32];
        #pragma unroll
        for (int nt = 0; nt < 8; ++nt)
            acc[nt] = MFMA(a0, *(const short8*)&P1_f[(size_t)(kc * 8 + nt) * 512 + boff], acc[nt]);
    }
    {
        float bs[8];
        #pragma unroll
        for (int nt = 0; nt < 8; ++nt) bs[nt] = p1b[nt * 16 + cb];
        #pragma unroll
        for (int reg = 0; reg < 4; ++reg) {
            int r = wid * 16 + rq * 4 + reg;
            #pragma unroll
            for (int nt = 0; nt < 8; ++nt) {
                float v = fast_elu(acc[nt][reg] + bs[nt]);
                Al[r * 136 + nt * 16 + cb] = (short)f2b(v);
            }
        }
    }

    // ---- GEMM3: LN2(t@P2 + p2b + y1r) -> out fp32 ----
    #pragma unroll
    for (int nt = 0; nt < 8; ++nt) acc[nt] = (f32x4){0.f, 0.f, 0.f, 0.f};
    for (int kc = 0; kc < 4; ++kc) {
        short8 a0 = *(const short8*)&Al[aoff_base + kc * 32];
        #pragma unroll
        for (int nt = 0; nt < 8; ++nt)
            acc[nt] = MFMA(a0, *(const short8*)&P2_f[(size_t)(kc * 8 + nt) * 512 + boff], acc[nt]);
    }
    {
        float bs[8], lg[8], lb[8];
        #pragma unroll
        for (int nt = 0; nt < 8; ++nt) {
            int col = nt * 16 + cb;
            bs[nt] = p2b[col]; lg[nt] = g2[col]; lb[nt] = b2[col];
        }
        #pragma unroll
        for (int reg = 0; reg < 4; ++reg) {
            int r = wid * 16 + rq * 4 + reg;
            int m = m0 + r;
            float v[8];
            float s1 = 0.f, s2 = 0.f;
            #pragma unroll
            for (int nt = 0; nt < 8; ++nt) {
                v[nt] = acc[nt][reg] + bs[nt] + y1r[reg][nt];
                s1 += v[nt]; s2 += v[nt] * v[nt];
            }
            #pragma unroll
            for (int o = 8; o >= 1; o >>= 1) { s1 += __shfl_xor(s1, o); s2 += __shfl_xor(s2, o); }
            float mu = s1 * (1.f / 128.f);
            float rs = rsqrtf(s2 * (1.f / 128.f) - mu * mu + 1e-5f);
            #pragma unroll
            for (int nt = 0; nt < 8; ++nt)
                outp[(size_t)m * 128 + nt * 16 + cb] = (v[nt] - mu) * rs * lg[nt] + lb[nt];
        }
    }
}

extern "C" void kernel_launch(void* const* d_in, const int* in_sizes, int n_in,
                              void* d_out, int out_size, void* d_ws, size_t ws_size,
                              hipStream_t stream) {
    const float* x      = (const float*)d_in[0];
    const float* w      = (const float*)d_in[1];
    const int*   ei     = (const int*)d_in[2];
    const int*   batch  = (const int*)d_in[3];
    const float* W_in   = (const float*)d_in[4];
    const float* b_in   = (const float*)d_in[5];
    const float* sage_Wl = (const float*)d_in[6];
    const float* sage_bl = (const float*)d_in[7];
    const float* sage_Wr = (const float*)d_in[8];
    const float* ln1_g  = (const float*)d_in[9];
    const float* ln1_b  = (const float*)d_in[10];
    const float* lin1_W = (const float*)d_in[11];
    const float* lin1_b = (const float*)d_in[12];
    const float* lin2_W = (const float*)d_in[13];
    const float* lin2_b = (const float*)d_in[14];
    const float* ln2_g  = (const float*)d_in[15];
    const float* ln2_b  = (const float*)d_in[16];
    const float* mdf_W  = (const float*)d_in[17];
    const float* mdf_b  = (const float*)d_in[18];
    const float* pln1_g = (const float*)d_in[19];
    const float* pln1_b = (const float*)d_in[20];
    const float* plin1_W = (const float*)d_in[21];
    const float* plin1_b = (const float*)d_in[22];
    const float* plin2_W = (const float*)d_in[23];
    const float* plin2_b = (const float*)d_in[24];
    const float* pln2_g = (const float*)d_in[25];
    const float* pln2_b = (const float*)d_in[26];
    float* out = (float*)d_out;

    const int* e_src = ei;
    const int* e_dst = ei + NE;

    // ---- workspace layout ----
    float* ws = (float*)d_ws;
    size_t off = 0;
    float* gm    = ws + off; off += (size_t)NG * FF;
    float* hh    = ws + off; off += (size_t)NG * FF;
    float* tt    = ws + off; off += (size_t)NG * FF;
    float* inv_deg = ws + off; off += NN;
    float* inv_cnt = ws + off; off += NG;
    unsigned short* us = (unsigned short*)(ws + off);
    size_t uoff = 0;
    unsigned short* hb0  = us + uoff; uoff += (size_t)NN * FF;
    unsigned short* hb1  = us + uoff; uoff += (size_t)NN * FF;
    unsigned short* aggb = us + uoff; uoff += (size_t)NN * FF;
    unsigned short* wt   = us + uoff; uoff += (size_t)16 * 16384;
    int* iw = (int*)(us + uoff);
    size_t ioff = 0;
    unsigned* pairs = (unsigned*)iw; ioff += (size_t)NBK * BCAP;
    int* ssrc    = iw + ioff; ioff += (size_t)NBK * BCAP;
    int* row_beg = iw + ioff; ioff += NN;
    int* row_end = iw + ioff; ioff += NN;
    int* g_off   = iw + ioff; ioff += NG + 1;
    int* bcur    = iw + ioff; ioff += NBK;
    // h8 (12.8 MB) aliases pairs (12.85 MB): pairs is dead after bucket_build,
    // h8 is first written by the input GEMM which runs after.
    unsigned char* h8 = (unsigned char*)pairs;

    // ---- weight prep (16 matrices -> frag-ordered bf16) ----
    WTab tab;
    tab.a[0] = W_in;
    for (int l = 0; l < 3; ++l) {
        tab.a[1 + l]  = sage_Wl + (size_t)l * 16384;
        tab.a[4 + l]  = sage_Wr + (size_t)l * 16384;
        tab.a[7 + l]  = lin1_W + (size_t)l * 16384;
        tab.a[10 + l] = lin2_W + (size_t)l * 16384;
    }
    tab.a[13] = mdf_W;      // first 128 rows only (Wa)
    tab.a[14] = plin1_W;
    tab.a[15] = plin2_W;
    prep_weights<<<16 * 64, 256, 0, stream>>>(tab, wt);
    const unsigned short* win_t = wt + 0 * 16384;
    const unsigned short* wa_t  = wt + 13 * 16384;
    const unsigned short* p1_t  = wt + 14 * 16384;
    const unsigned short* p2_t  = wt + 15 * 16384;

    // ---- build padded CSR (no histogram pass, no scan) ----
    graph_offsets<<<(NG + 256) / 256, 256, 0, stream>>>(batch, g_off, inv_cnt, bcur, ssrc);
    radix_scatter<<<RB, 256, 0, stream>>>(e_src, e_dst, bcur, pairs, NE);
    bucket_build<<<NBK, 512, 0, stream>>>(pairs, bcur, row_beg, row_end, inv_deg, ssrc);

    const int GN = (NN + 63) / 64;     // 1563
    const int GB = NG / 64;            // 16

    // ---- input linear: hb0 (bf16) + h8 (fp8, permuted) ----
    gemm_mfma<false, true, 0, 0, false, false, true, true><<<GN, 256, 0, stream>>>(
        x, win_t, b_in, w, W_in + 128 * 128,
        nullptr, nullptr, nullptr, nullptr, hb0, h8, NN);

    // ---- 3 GC blocks: fp8 gather + fused GEMM chain ----
    unsigned short* hcur = hb0;
    unsigned short* hnxt = hb1;
    for (int l = 0; l < 3; ++l) {
        sage_agg<<<NN / 8, 256, 0, stream>>>(h8, row_beg, row_end, inv_deg, ssrc, aggb);
        gc_chain<<<GN, 256, 0, stream>>>(
            hcur, aggb, hnxt, h8,
            wt + (size_t)(1 + l) * 16384, wt + (size_t)(4 + l) * 16384,
            wt + (size_t)(7 + l) * 16384, wt + (size_t)(10 + l) * 16384,
            sage_bl + (size_t)l * FF,
            ln1_g + (size_t)l * FF, ln1_b + (size_t)l * FF,
            lin1_b + (size_t)l * FF, lin2_b + (size_t)l * FF,
            ln2_g + (size_t)l * FF, ln2_b + (size_t)l * FF, NN);
        unsigned short* tmp = hcur; hcur = hnxt; hnxt = tmp;
    }

    // ---- head: pool(h2) -> fused LN1/FF/LN2 chain (one launch) ----
    pool_mean_b<<<NG, 256, 0, stream>>>(hcur, g_off, inv_cnt, gm);
    head_chain<<<GB, 256, 0, stream>>>(
        gm, wa_t, p1_t, p2_t, mdf_b,
        pln1_g, pln1_b, plin1_b, plin2_b, pln2_g, pln2_b, out);
    (void)hh; (void)tt;
}

// Round 11
// 491.981 us; speedup vs baseline: 1.4959x; 1.0254x over previous
//
#include <hip/hip_runtime.h>
#include <math.h>

#define NN 100000
#define NE 1600000
#define NG 1024
#define FF 128
#define BSH 9
#define NBK ((NN + 511) >> BSH)   // 196 buckets of 512 nodes
#define RB 512                    // radix blocks
#define BCAP 16384                // fixed bucket capacity (mean 8192, sigma~90)

typedef __attribute__((ext_vector_type(8))) short short8;
typedef __attribute__((ext_vector_type(4))) float f32x4;
typedef __attribute__((ext_vector_type(2))) float f32x2;

__device__ __forceinline__ unsigned short f2b(float f) {
    union { float f; unsigned u; } v; v.f = f;
    unsigned r = (v.u + 0x7FFF + ((v.u >> 16) & 1)) >> 16;
    return (unsigned short)r;
}
__device__ __forceinline__ float us2f(unsigned short u) {
    union { unsigned u; float f; } v; v.u = ((unsigned)u) << 16; return v.f;
}
// hardware ELU: v_exp_f32 is 2^x; elu(v)=v>0?v:2^(v*log2e)-1.
__device__ __forceinline__ float fast_elu(float v) {
    float e = __builtin_amdgcn_exp2f(v * 1.44269504088896340736f) - 1.0f;
    return v > 0.f ? v : e;
}
// pack 8 floats -> 8 fp8 (uint2), byte i = v[i]
__device__ __forceinline__ uint2 pk8(const float* v) {
    unsigned lo = 0, hi = 0;
    lo = (unsigned)__builtin_amdgcn_cvt_pk_fp8_f32(v[0], v[1], (int)lo, false);
    lo = (unsigned)__builtin_amdgcn_cvt_pk_fp8_f32(v[2], v[3], (int)lo, true);
    hi = (unsigned)__builtin_amdgcn_cvt_pk_fp8_f32(v[4], v[5], (int)hi, false);
    hi = (unsigned)__builtin_amdgcn_cvt_pk_fp8_f32(v[6], v[7], (int)hi, true);
    uint2 r; r.x = lo; r.y = hi; return r;
}
#define MFMA(a, b, c) __builtin_amdgcn_mfma_f32_16x16x32_bf16((a), (b), (c), 0, 0, 0)

// ---------------- pass 1: scatter packed (src<<9|local) into padded buckets -
__global__ __launch_bounds__(256)
void radix_scatter(const int* __restrict__ src, const int* __restrict__ dst,
                   int* __restrict__ bcur, unsigned* __restrict__ pairs, int n) {
    __shared__ int base[NBK];
    __shared__ int cnt[NBK];
    for (int i = threadIdx.x; i < NBK; i += 256) cnt[i] = 0;
    __syncthreads();
    const int per = (n + RB - 1) / RB;
    const int beg = blockIdx.x * per;
    const int end = min(n, beg + per);
    for (int i = beg + threadIdx.x; i < end; i += 256)
        atomicAdd(&cnt[dst[i] >> BSH], 1);
    __syncthreads();
    for (int i = threadIdx.x; i < NBK; i += 256)
        base[i] = cnt[i] ? atomicAdd(&bcur[i], cnt[i]) : 0;
    __syncthreads();
    for (int i = beg + threadIdx.x; i < end; i += 256) {
        int d = dst[i];
        int p = atomicAdd(&base[d >> BSH], 1);
        pairs[p] = ((unsigned)src[i] << BSH) | (unsigned)(d & 511);
    }
}

// ---------------- pass 2: per-bucket hist+scan+scatter -> padded CSR --------
// 512 threads (8 waves): 1 counter/thread. ssrc stores PRE-SCALED byte
// offsets (src*128).
__global__ __launch_bounds__(512)
void bucket_build(const unsigned* __restrict__ pairs, const int* __restrict__ bcur,
                  int* __restrict__ row_beg, int* __restrict__ row_end,
                  float* __restrict__ inv_deg, int* __restrict__ ssrc) {
    __shared__ int cnt[512];
    __shared__ int curs[512];
    __shared__ int wsum[8];
    const int b = blockIdx.x;
    const int n0 = b << BSH;
    const int t = threadIdx.x;
    const int lane = t & 63, wid = t >> 6;

    cnt[t] = 0;
    __syncthreads();
    const int beg = b * BCAP, end = bcur[b];
    for (int i = beg + t; i < end; i += 512)
        atomicAdd(&cnt[pairs[i] & 511], 1);
    __syncthreads();

    int c = cnt[t];
    int x = c;
    #pragma unroll
    for (int o = 1; o < 64; o <<= 1) {
        int y = __shfl_up(x, o);
        if (lane >= o) x += y;
    }
    if (lane == 63) wsum[wid] = x;
    __syncthreads();
    if (t == 0) {
        int s = 0;
        #pragma unroll
        for (int w2 = 0; w2 < 8; ++w2) { int tv = wsum[w2]; wsum[w2] = s; s += tv; }
    }
    __syncthreads();
    int g0 = beg + wsum[wid] + x - c;   // exclusive prefix
    curs[t] = g0;
    {
        int node = n0 + t;
        if (node < NN) {
            row_beg[node] = g0; row_end[node] = g0 + c;
            inv_deg[node] = 1.0f / (float)(c > 1 ? c : 1);
        }
    }
    __syncthreads();
    for (int i = beg + t; i < end; i += 512) {
        unsigned pr = pairs[i];
        int p = atomicAdd(&curs[pr & 511], 1);
        ssrc[p] = (int)(pr >> BSH) << 7;   // pre-scaled byte offset (row*128)
    }
}

// ---------------- graph offsets + bucket-cursor init + ssrc[0] sentinel -----
__global__ __launch_bounds__(256)
void graph_offsets(const int* __restrict__ batch, int* __restrict__ g_off,
                   float* __restrict__ inv_cnt, int* __restrict__ bcur,
                   int* __restrict__ ssrc) {
    int g = blockIdx.x * blockDim.x + threadIdx.x;
    if (g == 0) ssrc[0] = 0;    // sentinel: valid gather offset for masked lanes
    if (g < NBK) bcur[g] = g * BCAP;
    if (g > NG) return;
    if (g == NG) { g_off[NG] = NN; return; }
    int lo = 0, hi = NN;
    while (lo < hi) { int mid = (lo + hi) >> 1; if (batch[mid] < g) lo = mid + 1; else hi = mid; }
    int lo2 = lo, hi2 = NN;
    while (lo2 < hi2) { int mid = (lo2 + hi2) >> 1; if (batch[mid] < g + 1) lo2 = mid + 1; else hi2 = mid; }
    g_off[g] = lo;
    int c = lo2 - lo;
    inv_cnt[g] = 1.0f / (float)(c > 1 ? c : 1);
}

// ---------------- weight prep: fp32 [k][n] -> bf16 MFMA-FRAGMENT order ------
struct WTab { const float* a[16]; };
__global__ __launch_bounds__(256)
void prep_weights(WTab tab, unsigned short* __restrict__ dst) {
    int w = blockIdx.x >> 6;
    int idx = ((blockIdx.x & 63) << 8) + threadIdx.x;
    int j = idx & 7, lane = (idx >> 3) & 63, nt = (idx >> 9) & 7, kc = idx >> 12;
    int cb = lane & 15, rq = lane >> 4;
    int k = kc * 32 + rq * 8 + j;
    int n = nt * 16 + cb;
    dst[(size_t)w * 16384 + idx] = f2b(tab.a[w][k * 128 + n]);
}

// ---------------- SAGE mean aggregation: TWO nodes per wave -----------------
__global__ __launch_bounds__(256)
void sage_agg(const unsigned char* __restrict__ h8, const int* __restrict__ row_beg,
              const int* __restrict__ row_end, const float* __restrict__ inv_deg,
              const int* __restrict__ ssrc, unsigned short* __restrict__ aggb) {
    const int wid = threadIdx.x >> 6;
    const int lane = threadIdx.x & 63;
    const int n0 = blockIdx.x * 8 + wid * 2;
    const int n1 = n0 + 1;
    const int eg = lane >> 4, j = lane & 15;
    const int jo = j * 8;
    const int beg0 = row_beg[n0], end0 = row_end[n0];
    const int beg1 = row_beg[n1], end1 = row_end[n1];
    f32x2 a0 = {0.f, 0.f}, a1 = {0.f, 0.f}, a2 = {0.f, 0.f}, a3 = {0.f, 0.f};
    f32x2 b0 = {0.f, 0.f}, b1 = {0.f, 0.f}, b2 = {0.f, 0.f}, b3 = {0.f, 0.f};
    int e0 = beg0 + eg, e1 = beg1 + eg;
    const int d0 = end0 - beg0, d1 = end1 - beg1;
    const int nit = ((d0 > d1 ? d0 : d1) + 31) >> 5;
    for (int it = 0; it < nit; ++it, e0 += 32, e1 += 32) {
        uint2 u0[8], u1[8];
        #pragma unroll
        for (int k = 0; k < 8; ++k) {
            int ek = e0 + 4 * k;
            bool ok = ek < end0;
            int idx = ssrc[ok ? ek : 0];
            uint2 uu = *(const uint2*)(h8 + (unsigned)(idx + jo));
            uu.x = ok ? uu.x : 0u;
            uu.y = ok ? uu.y : 0u;                             // fp8 0x00 -> 0.0f
            u0[k] = uu;
        }
        #pragma unroll
        for (int k = 0; k < 8; ++k) {
            int ek = e1 + 4 * k;
            bool ok = ek < end1;
            int idx = ssrc[ok ? ek : 0];
            uint2 uu = *(const uint2*)(h8 + (unsigned)(idx + jo));
            uu.x = ok ? uu.x : 0u;
            uu.y = ok ? uu.y : 0u;
            u1[k] = uu;
        }
        #pragma unroll
        for (int k = 0; k < 8; ++k) {
            a0 += __builtin_amdgcn_cvt_pk_f32_fp8(u0[k].x, false);
            a1 += __builtin_amdgcn_cvt_pk_f32_fp8(u0[k].x, true);
            a2 += __builtin_amdgcn_cvt_pk_f32_fp8(u0[k].y, false);
            a3 += __builtin_amdgcn_cvt_pk_f32_fp8(u0[k].y, true);
            b0 += __builtin_amdgcn_cvt_pk_f32_fp8(u1[k].x, false);
            b1 += __builtin_amdgcn_cvt_pk_f32_fp8(u1[k].x, true);
            b2 += __builtin_amdgcn_cvt_pk_f32_fp8(u1[k].y, false);
            b3 += __builtin_amdgcn_cvt_pk_f32_fp8(u1[k].y, true);
        }
    }
    float af[8] = {a0.x, a0.y, a1.x, a1.y, a2.x, a2.y, a3.x, a3.y};
    float bf[8] = {b0.x, b0.y, b1.x, b1.y, b2.x, b2.y, b3.x, b3.y};
    #pragma unroll
    for (int k = 0; k < 8; ++k) {
        af[k] += __shfl_xor(af[k], 16);
        af[k] += __shfl_xor(af[k], 32);
        bf[k] += __shfl_xor(bf[k], 16);
        bf[k] += __shfl_xor(bf[k], 32);
    }
    if (eg == 0) {
        float id0 = inv_deg[n0];
        float id1 = inv_deg[n1];
        #pragma unroll
        for (int nt = 0; nt < 8; ++nt) {
            aggb[(size_t)n0 * 128 + nt * 16 + j] = f2b(af[nt] * id0);
            aggb[(size_t)n1 * 128 + nt * 16 + j] = f2b(bf[nt] * id1);
        }
    }
}

// ---------------- mean pool per graph from bf16 (4 waves + LDS reduce) ------
__global__ __launch_bounds__(256)
void pool_mean_b(const unsigned short* __restrict__ src, const int* __restrict__ g_off,
                 const float* __restrict__ inv_cnt, float* __restrict__ out) {
    __shared__ float red[3][128];
    const int g = blockIdx.x;
    const int t = threadIdx.x;
    const int lane = t & 63, wid = t >> 6;
    const int j = lane & 15, rs = lane >> 4;
    const int beg = g_off[g], end = g_off[g + 1];
    float s[8] = {0.f, 0.f, 0.f, 0.f, 0.f, 0.f, 0.f, 0.f};
    for (int n = beg + rs + wid * 4; n < end; n += 16) {
        short8 v = *(const short8*)&src[(size_t)n * FF + j * 8];
        #pragma unroll
        for (int i = 0; i < 8; ++i) s[i] += us2f((unsigned short)v[i]);
    }
    #pragma unroll
    for (int i = 0; i < 8; ++i) {
        s[i] += __shfl_xor(s[i], 16);
        s[i] += __shfl_xor(s[i], 32);
    }
    if (wid > 0 && rs == 0) {
        #pragma unroll
        for (int i = 0; i < 8; ++i) red[wid - 1][j * 8 + i] = s[i];
    }
    __syncthreads();
    if (wid == 0 && rs == 0) {
        float ic = inv_cnt[g];
        #pragma unroll
        for (int i = 0; i < 8; ++i) {
            float v = s[i] + red[0][j * 8 + i] + red[1][j * 8 + i] + red[2][j * 8 + i];
            out[(size_t)g * FF + j * 8 + i] = v * ic;
        }
    }
}

// ---------------- MFMA bf16 GEMM: BARRIER-FREE (wave-private band stage) ----
// Each wave stages its OWN 16-row band of A into LDS, so there is no
// cross-wave LDS dependency and NO __syncthreads: waves run self-paced,
// overlapping each other's stage latency with MFMA/epilogue work.
template<bool AB16, bool R1, int RESM, int ACT, bool LN, bool OF32, bool OB16, bool OB8>
__global__ __launch_bounds__(256)
void gemm_mfma(const void* __restrict__ A_,
               const unsigned short* __restrict__ Wf,
               const float* __restrict__ bias,
               const float* __restrict__ rvec, const float* __restrict__ rrow,
               const float* __restrict__ res,
               const float* __restrict__ lng, const float* __restrict__ lnb,
               float* __restrict__ outf, unsigned short* __restrict__ outb,
               unsigned char* __restrict__ outb8, int M) {
    __shared__ short Al[64 * 136];

    const int t = threadIdx.x;
    const int lane = t & 63, wid = t >> 6;
    const int m0 = blockIdx.x * 64;
    const int cb = lane & 15, rq = lane >> 4;
    const int band = wid * 16;

    if (AB16) {
        const unsigned short* Ab = (const unsigned short*)A_;
        #pragma unroll
        for (int i2 = 0; i2 < 4; ++i2) {
            int i = lane + i2 * 64;
            int row = band + (i >> 4), seg = i & 15;
            int gr = m0 + row; if (gr >= M) gr = M - 1;
            *(uint4*)&Al[row * 136 + seg * 8] = *(const uint4*)&Ab[(size_t)gr * 128 + seg * 8];
        }
    } else {
        const float* Af = (const float*)A_;
        #pragma unroll
        for (int i2 = 0; i2 < 8; ++i2) {
            int i = lane + i2 * 64;
            int row = band + (i >> 5), seg = i & 31;
            int gr = m0 + row; if (gr >= M) gr = M - 1;
            float4 v = *(const float4*)&Af[(size_t)gr * 128 + seg * 4];
            ushort4 o = {f2b(v.x), f2b(v.y), f2b(v.z), f2b(v.w)};
            *(ushort4*)&Al[row * 136 + seg * 4] = o;
        }
    }
    // no barrier: all LDS traffic is band-local (same wave wrote it)

    f32x4 acc[8];
    #pragma unroll
    for (int nt = 0; nt < 8; ++nt) acc[nt] = (f32x4){0.f, 0.f, 0.f, 0.f};

    const int aoff_base = (band + cb) * 136 + rq * 8;
    for (int kc = 0; kc < 4; ++kc) {
        short8 a0 = *(const short8*)&Al[aoff_base + kc * 32];
        #pragma unroll
        for (int nt = 0; nt < 8; ++nt) {
            short8 b0 = *(const short8*)&Wf[(size_t)(kc * 8 + nt) * 512 + lane * 8];
            acc[nt] = MFMA(a0, b0, acc[nt]);
        }
    }

    float bs[8], rr[8], lg[8], lb[8];
    #pragma unroll
    for (int nt = 0; nt < 8; ++nt) {
        int col = nt * 16 + cb;
        bs[nt] = bias[col];
        if (R1) rr[nt] = rrow[col];
        if (LN) { lg[nt] = lng[col]; lb[nt] = lnb[col]; }
    }
    #pragma unroll
    for (int reg = 0; reg < 4; ++reg) {
        int m = m0 + band + rq * 4 + reg;
        int mc = m < M ? m : M - 1;
        float v[8];
        #pragma unroll
        for (int nt = 0; nt < 8; ++nt) v[nt] = acc[nt][reg] + bs[nt];
        if (R1) {
            float rv = rvec[mc];
            #pragma unroll
            for (int nt = 0; nt < 8; ++nt) v[nt] += rv * rr[nt];
        }
        if (RESM == 1) {
            #pragma unroll
            for (int nt = 0; nt < 8; ++nt) v[nt] += res[(size_t)mc * 128 + nt * 16 + cb];
        }
        if (ACT == 1) {
            #pragma unroll
            for (int nt = 0; nt < 8; ++nt) v[nt] = fast_elu(v[nt]);
        }
        if (LN) {
            float s1 = 0.f, s2 = 0.f;
            #pragma unroll
            for (int nt = 0; nt < 8; ++nt) { s1 += v[nt]; s2 += v[nt] * v[nt]; }
            #pragma unroll
            for (int o = 8; o >= 1; o >>= 1) { s1 += __shfl_xor(s1, o); s2 += __shfl_xor(s2, o); }
            float mu = s1 * (1.f / 128.f);
            float rs = rsqrtf(s2 * (1.f / 128.f) - mu * mu + 1e-5f);
            #pragma unroll
            for (int nt = 0; nt < 8; ++nt) v[nt] = (v[nt] - mu) * rs * lg[nt] + lb[nt];
        }
        if (m < M) {
            #pragma unroll
            for (int nt = 0; nt < 8; ++nt) {
                size_t o = (size_t)m * 128 + nt * 16 + cb;
                if (OF32) outf[o] = v[nt];
                if (OB16) outb[o] = f2b(v[nt]);
            }
            if (OB8) *(uint2*)&outb8[(size_t)m * 128 + cb * 8] = pk8(v);
        }
    }
}

// ---------------- fused GEMM chain: BARRIER-FREE (wave-private bands) -------
// Every LDS access (A-frags, LN residual, y1 store/reload, FF1/FF2 operands)
// is band-local: wave wid touches only rows wid*16..wid*16+15 of Hl/Gl. Each
// wave stages its own band, so the kernel has ZERO barriers — the 4 waves
// run self-paced through {stage, GEMM, LN1, FF1, FF2}, overlapping each
// other's memory latency on the CU.
__global__ __launch_bounds__(256)
void gc_chain(const unsigned short* __restrict__ hin, const unsigned short* __restrict__ aggb,
              unsigned short* __restrict__ hout, unsigned char* __restrict__ h8out,
              const unsigned short* __restrict__ Wl_f, const unsigned short* __restrict__ Wr_f,
              const unsigned short* __restrict__ W1_f, const unsigned short* __restrict__ W2_f,
              const float* __restrict__ bl,
              const float* __restrict__ g1, const float* __restrict__ b1,
              const float* __restrict__ bb1, const float* __restrict__ bb2,
              const float* __restrict__ g2, const float* __restrict__ b2, int M) {
    __shared__ short Hl[64 * 136];     // h tile -> y1 tile
    __shared__ short Gl[64 * 136];     // agg tile -> elu(t) tile

    const int t = threadIdx.x;
    const int lane = t & 63, wid = t >> 6;
    const int m0 = blockIdx.x * 64;
    const int cb = lane & 15, rq = lane >> 4;
    const int band = wid * 16;
    const int aoff_base = (band + cb) * 136 + rq * 8;
    const int boff = lane * 8;

    #pragma unroll
    for (int i2 = 0; i2 < 4; ++i2) {
        int i = lane + i2 * 64;
        int row = band + (i >> 4), seg = i & 15;
        int gr = m0 + row; if (gr >= M) gr = M - 1;
        *(uint4*)&Hl[row * 136 + seg * 8] = *(const uint4*)&hin[(size_t)gr * 128 + seg * 8];
        *(uint4*)&Gl[row * 136 + seg * 8] = *(const uint4*)&aggb[(size_t)gr * 128 + seg * 8];
    }
    // no barrier: band-local LDS only

    f32x4 acc[8];
    #pragma unroll
    for (int nt = 0; nt < 8; ++nt) acc[nt] = (f32x4){0.f, 0.f, 0.f, 0.f};

    // ---- dual GEMM: acc = agg@Wl + h@Wr ----
    for (int kc = 0; kc < 4; ++kc) {
        short8 a0 = *(const short8*)&Gl[aoff_base + kc * 32];
        short8 a1 = *(const short8*)&Hl[aoff_base + kc * 32];
        #pragma unroll
        for (int nt = 0; nt < 8; ++nt) {
            const size_t wo = (size_t)(kc * 8 + nt) * 512 + boff;
            acc[nt] = MFMA(a0, *(const short8*)&Wl_f[wo], acc[nt]);
            acc[nt] = MFMA(a1, *(const short8*)&Wr_f[wo], acc[nt]);
        }
    }

    // ---- epilogue 1 (band-local): y1 = LN1(acc + bl + h) -> Hl + regs ----
    float y1r[4][8];
    {
        float bs[8], lg[8], lb[8];
        #pragma unroll
        for (int nt = 0; nt < 8; ++nt) {
            int col = nt * 16 + cb;
            bs[nt] = bl[col]; lg[nt] = g1[col]; lb[nt] = b1[col];
        }
        #pragma unroll
        for (int reg = 0; reg < 4; ++reg) {
            int r = band + rq * 4 + reg;
            float v[8];
            float s1 = 0.f, s2 = 0.f;
            #pragma unroll
            for (int nt = 0; nt < 8; ++nt) {
                v[nt] = acc[nt][reg] + bs[nt] + us2f((unsigned short)Hl[r * 136 + nt * 16 + cb]);
                s1 += v[nt]; s2 += v[nt] * v[nt];
            }
            #pragma unroll
            for (int o = 8; o >= 1; o >>= 1) { s1 += __shfl_xor(s1, o); s2 += __shfl_xor(s2, o); }
            float mu = s1 * (1.f / 128.f);
            float rs = rsqrtf(s2 * (1.f / 128.f) - mu * mu + 1e-5f);
            #pragma unroll
            for (int nt = 0; nt < 8; ++nt) {
                float y = (v[nt] - mu) * rs * lg[nt] + lb[nt];
                y1r[reg][nt] = y;
                Hl[r * 136 + nt * 16 + cb] = (short)f2b(y);
            }
        }
    }

    // ---- FF1 (band-local): t = elu(y1@W1 + bb1) -> Gl ----
    #pragma unroll
    for (int nt = 0; nt < 8; ++nt) acc[nt] = (f32x4){0.f, 0.f, 0.f, 0.f};
    for (int kc = 0; kc < 4; ++kc) {
        short8 a0 = *(const short8*)&Hl[aoff_base + kc * 32];
        #pragma unroll
        for (int nt = 0; nt < 8; ++nt)
            acc[nt] = MFMA(a0, *(const short8*)&W1_f[(size_t)(kc * 8 + nt) * 512 + boff], acc[nt]);
    }
    {
        float bs[8];
        #pragma unroll
        for (int nt = 0; nt < 8; ++nt) bs[nt] = bb1[nt * 16 + cb];
        #pragma unroll
        for (int reg = 0; reg < 4; ++reg) {
            int r = band + rq * 4 + reg;
            #pragma unroll
            for (int nt = 0; nt < 8; ++nt) {
                float v = fast_elu(acc[nt][reg] + bs[nt]);
                Gl[r * 136 + nt * 16 + cb] = (short)f2b(v);
            }
        }
    }

    // ---- FF2 (band-local): h' = LN2(t@W2 + bb2 + y1) -> global bf16 + fp8 --
    #pragma unroll
    for (int nt = 0; nt < 8; ++nt) acc[nt] = (f32x4){0.f, 0.f, 0.f, 0.f};
    for (int kc = 0; kc < 4; ++kc) {
        short8 a0 = *(const short8*)&Gl[aoff_base + kc * 32];
        #pragma unroll
        for (int nt = 0; nt < 8; ++nt)
            acc[nt] = MFMA(a0, *(const short8*)&W2_f[(size_t)(kc * 8 + nt) * 512 + boff], acc[nt]);
    }
    {
        float bs[8], lg[8], lb[8];
        #pragma unroll
        for (int nt = 0; nt < 8; ++nt) {
            int col = nt * 16 + cb;
            bs[nt] = bb2[col]; lg[nt] = g2[col]; lb[nt] = b2[col];
        }
        #pragma unroll
        for (int reg = 0; reg < 4; ++reg) {
            int r = band + rq * 4 + reg;
            int m = m0 + r;
            float v[8];
            float s1 = 0.f, s2 = 0.f;
            #pragma unroll
            for (int nt = 0; nt < 8; ++nt) {
                v[nt] = acc[nt][reg] + bs[nt] + y1r[reg][nt];
                s1 += v[nt]; s2 += v[nt] * v[nt];
            }
            #pragma unroll
            for (int o = 8; o >= 1; o >>= 1) { s1 += __shfl_xor(s1, o); s2 += __shfl_xor(s2, o); }
            float mu = s1 * (1.f / 128.f);
            float rs = rsqrtf(s2 * (1.f / 128.f) - mu * mu + 1e-5f);
            if (m < M) {
                float fv[8];
                #pragma unroll
                for (int nt = 0; nt < 8; ++nt) {
                    fv[nt] = (v[nt] - mu) * rs * lg[nt] + lb[nt];
                    hout[(size_t)m * 128 + nt * 16 + cb] = f2b(fv[nt]);
                }
                *(uint2*)&h8out[(size_t)m * 128 + cb * 8] = pk8(fv);
            }
        }
    }
}

// ---------------- fused head: BARRIER-FREE band-local chain -----------------
__global__ __launch_bounds__(256)
void head_chain(const float* __restrict__ gm,
                const unsigned short* __restrict__ Wa_f,
                const unsigned short* __restrict__ P1_f,
                const unsigned short* __restrict__ P2_f,
                const float* __restrict__ mdfb,
                const float* __restrict__ g1, const float* __restrict__ b1,
                const float* __restrict__ p1b, const float* __restrict__ p2b,
                const float* __restrict__ g2, const float* __restrict__ b2,
                float* __restrict__ outp) {
    __shared__ short Al[64 * 136];

    const int t = threadIdx.x;
    const int lane = t & 63, wid = t >> 6;
    const int m0 = blockIdx.x * 64;
    const int cb = lane & 15, rq = lane >> 4;
    const int band = wid * 16;
    const int aoff_base = (band + cb) * 136 + rq * 8;
    const int boff = lane * 8;

    #pragma unroll
    for (int i2 = 0; i2 < 8; ++i2) {
        int i = lane + i2 * 64;
        int row = band + (i >> 5), seg = i & 31;
        float4 v = *(const float4*)&gm[(size_t)(m0 + row) * 128 + seg * 4];
        ushort4 o = {f2b(v.x), f2b(v.y), f2b(v.z), f2b(v.w)};
        *(ushort4*)&Al[row * 136 + seg * 4] = o;
    }
    // no barrier: band-local LDS only

    f32x4 acc[8];
    // ---- GEMM1: gm@Wa + mdfb, LN1 -> y1r + Al ----
    #pragma unroll
    for (int nt = 0; nt < 8; ++nt) acc[nt] = (f32x4){0.f, 0.f, 0.f, 0.f};
    for (int kc = 0; kc < 4; ++kc) {
        short8 a0 = *(const short8*)&Al[aoff_base + kc * 32];
        #pragma unroll
        for (int nt = 0; nt < 8; ++nt)
            acc[nt] = MFMA(a0, *(const short8*)&Wa_f[(size_t)(kc * 8 + nt) * 512 + boff], acc[nt]);
    }
    float y1r[4][8];
    {
        float bs[8], lg[8], lb[8];
        #pragma unroll
        for (int nt = 0; nt < 8; ++nt) {
            int col = nt * 16 + cb;
            bs[nt] = mdfb[col]; lg[nt] = g1[col]; lb[nt] = b1[col];
        }
        #pragma unroll
        for (int reg = 0; reg < 4; ++reg) {
            int r = band + rq * 4 + reg;
            float v[8];
            float s1 = 0.f, s2 = 0.f;
            #pragma unroll
            for (int nt = 0; nt < 8; ++nt) {
                v[nt] = acc[nt][reg] + bs[nt];
                s1 += v[nt]; s2 += v[nt] * v[nt];
            }
            #pragma unroll
            for (int o = 8; o >= 1; o >>= 1) { s1 += __shfl_xor(s1, o); s2 += __shfl_xor(s2, o); }
            float mu = s1 * (1.f / 128.f);
            float rs = rsqrtf(s2 * (1.f / 128.f) - mu * mu + 1e-5f);
            #pragma unroll
            for (int nt = 0; nt < 8; ++nt) {
                float y = (v[nt] - mu) * rs * lg[nt] + lb[nt];
                y1r[reg][nt] = y;
                Al[r * 136 + nt * 16 + cb] = (short)f2b(y);
            }
        }
    }

    // ---- GEMM2: elu(y1@P1 + p1b) -> Al ----
    #pragma unroll
    for (int nt = 0; nt < 8; ++nt) acc[nt] = (f32x4){0.f, 0.f, 0.f, 0.f};
    for (int kc = 0; kc < 4; ++kc) {
        short8 a0 = *(const short8*)&Al[aoff_base + kc * 32];
        #pragma unroll
        for (int nt = 0; nt < 8; ++nt)
            acc[nt] = MFMA(a0, *(const short8*)&P1_f[(size_t)(kc * 8 + nt) * 512 + boff], acc[nt]);
    }
    {
        float bs[8];
        #pragma unroll
        for (int nt = 0; nt < 8; ++nt) bs[nt] = p1b[nt * 16 + cb];
        #pragma unroll
        for (int reg = 0; reg < 4; ++reg) {
            int r = band + rq * 4 + reg;
            #pragma unroll
            for (int nt = 0; nt < 8; ++nt) {
                float v = fast_elu(acc[nt][reg] + bs[nt]);
                Al[r * 136 + nt * 16 + cb] = (short)f2b(v);
            }
        }
    }

    // ---- GEMM3: LN2(t@P2 + p2b + y1r) -> out fp32 ----
    #pragma unroll
    for (int nt = 0; nt < 8; ++nt) acc[nt] = (f32x4){0.f, 0.f, 0.f, 0.f};
    for (int kc = 0; kc < 4; ++kc) {
        short8 a0 = *(const short8*)&Al[aoff_base + kc * 32];
        #pragma unroll
        for (int nt = 0; nt < 8; ++nt)
            acc[nt] = MFMA(a0, *(const short8*)&P2_f[(size_t)(kc * 8 + nt) * 512 + boff], acc[nt]);
    }
    {
        float bs[8], lg[8], lb[8];
        #pragma unroll
        for (int nt = 0; nt < 8; ++nt) {
            int col = nt * 16 + cb;
            bs[nt] = p2b[col]; lg[nt] = g2[col]; lb[nt] = b2[col];
        }
        #pragma unroll
        for (int reg = 0; reg < 4; ++reg) {
            int r = band + rq * 4 + reg;
            int m = m0 + r;
            float v[8];
            float s1 = 0.f, s2 = 0.f;
            #pragma unroll
            for (int nt = 0; nt < 8; ++nt) {
                v[nt] = acc[nt][reg] + bs[nt] + y1r[reg][nt];
                s1 += v[nt]; s2 += v[nt] * v[nt];
            }
            #pragma unroll
            for (int o = 8; o >= 1; o >>= 1) { s1 += __shfl_xor(s1, o); s2 += __shfl_xor(s2, o); }
            float mu = s1 * (1.f / 128.f);
            float rs = rsqrtf(s2 * (1.f / 128.f) - mu * mu + 1e-5f);
            #pragma unroll
            for (int nt = 0; nt < 8; ++nt)
                outp[(size_t)m * 128 + nt * 16 + cb] = (v[nt] - mu) * rs * lg[nt] + lb[nt];
        }
    }
}

extern "C" void kernel_launch(void* const* d_in, const int* in_sizes, int n_in,
                              void* d_out, int out_size, void* d_ws, size_t ws_size,
                              hipStream_t stream) {
    const float* x      = (const float*)d_in[0];
    const float* w      = (const float*)d_in[1];
    const int*   ei     = (const int*)d_in[2];
    const int*   batch  = (const int*)d_in[3];
    const float* W_in   = (const float*)d_in[4];
    const float* b_in   = (const float*)d_in[5];
    const float* sage_Wl = (const float*)d_in[6];
    const float* sage_bl = (const float*)d_in[7];
    const float* sage_Wr = (const float*)d_in[8];
    const float* ln1_g  = (const float*)d_in[9];
    const float* ln1_b  = (const float*)d_in[10];
    const float* lin1_W = (const float*)d_in[11];
    const float* lin1_b = (const float*)d_in[12];
    const float* lin2_W = (const float*)d_in[13];
    const float* lin2_b = (const float*)d_in[14];
    const float* ln2_g  = (const float*)d_in[15];
    const float* ln2_b  = (const float*)d_in[16];
    const float* mdf_W  = (const float*)d_in[17];
    const float* mdf_b  = (const float*)d_in[18];
    const float* pln1_g = (const float*)d_in[19];
    const float* pln1_b = (const float*)d_in[20];
    const float* plin1_W = (const float*)d_in[21];
    const float* plin1_b = (const float*)d_in[22];
    const float* plin2_W = (const float*)d_in[23];
    const float* plin2_b = (const float*)d_in[24];
    const float* pln2_g = (const float*)d_in[25];
    const float* pln2_b = (const float*)d_in[26];
    float* out = (float*)d_out;

    const int* e_src = ei;
    const int* e_dst = ei + NE;

    // ---- workspace layout ----
    float* ws = (float*)d_ws;
    size_t off = 0;
    float* gm    = ws + off; off += (size_t)NG * FF;
    float* hh    = ws + off; off += (size_t)NG * FF;
    float* tt    = ws + off; off += (size_t)NG * FF;
    float* inv_deg = ws + off; off += NN;
    float* inv_cnt = ws + off; off += NG;
    unsigned short* us = (unsigned short*)(ws + off);
    size_t uoff = 0;
    unsigned short* hb0  = us + uoff; uoff += (size_t)NN * FF;
    unsigned short* hb1  = us + uoff; uoff += (size_t)NN * FF;
    unsigned short* aggb = us + uoff; uoff += (size_t)NN * FF;
    unsigned short* wt   = us + uoff; uoff += (size_t)16 * 16384;
    int* iw = (int*)(us + uoff);
    size_t ioff = 0;
    unsigned* pairs = (unsigned*)iw; ioff += (size_t)NBK * BCAP;
    int* ssrc    = iw + ioff; ioff += (size_t)NBK * BCAP;
    int* row_beg = iw + ioff; ioff += NN;
    int* row_end = iw + ioff; ioff += NN;
    int* g_off   = iw + ioff; ioff += NG + 1;
    int* bcur    = iw + ioff; ioff += NBK;
    // h8 (12.8 MB) aliases pairs (12.85 MB): pairs is dead after bucket_build,
    // h8 is first written by the input GEMM which runs after.
    unsigned char* h8 = (unsigned char*)pairs;

    // ---- weight prep (16 matrices -> frag-ordered bf16) ----
    WTab tab;
    tab.a[0] = W_in;
    for (int l = 0; l < 3; ++l) {
        tab.a[1 + l]  = sage_Wl + (size_t)l * 16384;
        tab.a[4 + l]  = sage_Wr + (size_t)l * 16384;
        tab.a[7 + l]  = lin1_W + (size_t)l * 16384;
        tab.a[10 + l] = lin2_W + (size_t)l * 16384;
    }
    tab.a[13] = mdf_W;      // first 128 rows only (Wa)
    tab.a[14] = plin1_W;
    tab.a[15] = plin2_W;
    prep_weights<<<16 * 64, 256, 0, stream>>>(tab, wt);
    const unsigned short* win_t = wt + 0 * 16384;
    const unsigned short* wa_t  = wt + 13 * 16384;
    const unsigned short* p1_t  = wt + 14 * 16384;
    const unsigned short* p2_t  = wt + 15 * 16384;

    // ---- build padded CSR (no histogram pass, no scan) ----
    graph_offsets<<<(NG + 256) / 256, 256, 0, stream>>>(batch, g_off, inv_cnt, bcur, ssrc);
    radix_scatter<<<RB, 256, 0, stream>>>(e_src, e_dst, bcur, pairs, NE);
    bucket_build<<<NBK, 512, 0, stream>>>(pairs, bcur, row_beg, row_end, inv_deg, ssrc);

    const int GN = (NN + 63) / 64;     // 1563
    const int GB = NG / 64;            // 16

    // ---- input linear: hb0 (bf16) + h8 (fp8, permuted) ----
    gemm_mfma<false, true, 0, 0, false, false, true, true><<<GN, 256, 0, stream>>>(
        x, win_t, b_in, w, W_in + 128 * 128,
        nullptr, nullptr, nullptr, nullptr, hb0, h8, NN);

    // ---- 3 GC blocks: fp8 gather + fused GEMM chain ----
    unsigned short* hcur = hb0;
    unsigned short* hnxt = hb1;
    for (int l = 0; l < 3; ++l) {
        sage_agg<<<NN / 8, 256, 0, stream>>>(h8, row_beg, row_end, inv_deg, ssrc, aggb);
        gc_chain<<<GN, 256, 0, stream>>>(
            hcur, aggb, hnxt, h8,
            wt + (size_t)(1 + l) * 16384, wt + (size_t)(4 + l) * 16384,
            wt + (size_t)(7 + l) * 16384, wt + (size_t)(10 + l) * 16384,
            sage_bl + (size_t)l * FF,
            ln1_g + (size_t)l * FF, ln1_b + (size_t)l * FF,
            lin1_b + (size_t)l * FF, lin2_b + (size_t)l * FF,
            ln2_g + (size_t)l * FF, ln2_b + (size_t)l * FF, NN);
        unsigned short* tmp = hcur; hcur = hnxt; hnxt = tmp;
    }

    // ---- head: pool(h2) -> fused LN1/FF/LN2 chain (one launch) ----
    pool_mean_b<<<NG, 256, 0, stream>>>(hcur, g_off, inv_cnt, gm);
    head_chain<<<GB, 256, 0, stream>>>(
        gm, wa_t, p1_t, p2_t, mdf_b,
        pln1_g, pln1_b, plin1_b, plin2_b, pln2_g, pln2_b, out);
    (void)hh; (void)tt;
}

// Round 12
// 489.441 us; speedup vs baseline: 1.5037x; 1.0052x over previous
//
#include <hip/hip_runtime.h>
#include <math.h>

#define NN 100000
#define NE 1600000
#define NG 1024
#define FF 128
#define BSH 9
#define NBK ((NN + 511) >> BSH)   // 196 buckets of 512 nodes
#define RB 512                    // radix blocks
#define BCAP 16384                // fixed bucket capacity (mean 8192, sigma~90)

typedef __attribute__((ext_vector_type(8))) short short8;
typedef __attribute__((ext_vector_type(4))) float f32x4;
typedef __attribute__((ext_vector_type(2))) float f32x2;

__device__ __forceinline__ unsigned short f2b(float f) {
    union { float f; unsigned u; } v; v.f = f;
    unsigned r = (v.u + 0x7FFF + ((v.u >> 16) & 1)) >> 16;
    return (unsigned short)r;
}
__device__ __forceinline__ float us2f(unsigned short u) {
    union { unsigned u; float f; } v; v.u = ((unsigned)u) << 16; return v.f;
}
// hardware ELU: v_exp_f32 is 2^x; elu(v)=v>0?v:2^(v*log2e)-1.
__device__ __forceinline__ float fast_elu(float v) {
    float e = __builtin_amdgcn_exp2f(v * 1.44269504088896340736f) - 1.0f;
    return v > 0.f ? v : e;
}
// pack 8 floats -> 8 fp8 (uint2), byte i = v[i]
__device__ __forceinline__ uint2 pk8(const float* v) {
    unsigned lo = 0, hi = 0;
    lo = (unsigned)__builtin_amdgcn_cvt_pk_fp8_f32(v[0], v[1], (int)lo, false);
    lo = (unsigned)__builtin_amdgcn_cvt_pk_fp8_f32(v[2], v[3], (int)lo, true);
    hi = (unsigned)__builtin_amdgcn_cvt_pk_fp8_f32(v[4], v[5], (int)hi, false);
    hi = (unsigned)__builtin_amdgcn_cvt_pk_fp8_f32(v[6], v[7], (int)hi, true);
    uint2 r; r.x = lo; r.y = hi; return r;
}
#define MFMA(a, b, c) __builtin_amdgcn_mfma_f32_16x16x32_bf16((a), (b), (c), 0, 0, 0)

// ---------------- pass 1: scatter packed (src<<9|local) into padded buckets -
// Quad-vectorized streaming (int4 loads; NE divisible by 4, per aligned to 4).
__global__ __launch_bounds__(256)
void radix_scatter(const int* __restrict__ src, const int* __restrict__ dst,
                   int* __restrict__ bcur, unsigned* __restrict__ pairs, int n) {
    __shared__ int base[NBK];
    __shared__ int cnt[NBK];
    for (int i = threadIdx.x; i < NBK; i += 256) cnt[i] = 0;
    __syncthreads();
    const int per = (((n + RB - 1) / RB) + 3) & ~3;
    const int beg = blockIdx.x * per;
    const int end = min(n, beg + per);
    {
        int i = beg + 4 * (int)threadIdx.x;
        for (; i + 3 < end; i += 1024) {
            int4 d4 = *(const int4*)&dst[i];
            atomicAdd(&cnt[d4.x >> BSH], 1);
            atomicAdd(&cnt[d4.y >> BSH], 1);
            atomicAdd(&cnt[d4.z >> BSH], 1);
            atomicAdd(&cnt[d4.w >> BSH], 1);
        }
        for (; i < end; ++i) atomicAdd(&cnt[dst[i] >> BSH], 1);
    }
    __syncthreads();
    for (int i = threadIdx.x; i < NBK; i += 256)
        base[i] = cnt[i] ? atomicAdd(&bcur[i], cnt[i]) : 0;
    __syncthreads();
    {
        int i = beg + 4 * (int)threadIdx.x;
        for (; i + 3 < end; i += 1024) {
            int4 d4 = *(const int4*)&dst[i];
            int4 s4 = *(const int4*)&src[i];
            int p;
            p = atomicAdd(&base[d4.x >> BSH], 1);
            pairs[p] = ((unsigned)s4.x << BSH) | (unsigned)(d4.x & 511);
            p = atomicAdd(&base[d4.y >> BSH], 1);
            pairs[p] = ((unsigned)s4.y << BSH) | (unsigned)(d4.y & 511);
            p = atomicAdd(&base[d4.z >> BSH], 1);
            pairs[p] = ((unsigned)s4.z << BSH) | (unsigned)(d4.z & 511);
            p = atomicAdd(&base[d4.w >> BSH], 1);
            pairs[p] = ((unsigned)s4.w << BSH) | (unsigned)(d4.w & 511);
        }
        for (; i < end; ++i) {
            int d = dst[i];
            int p = atomicAdd(&base[d >> BSH], 1);
            pairs[p] = ((unsigned)src[i] << BSH) | (unsigned)(d & 511);
        }
    }
}

// ---------------- pass 2: per-bucket hist+scan+scatter -> padded CSR --------
// 512 threads (8 waves), quad-vectorized streaming. Also absorbs the old
// graph_offsets kernel: blocks 0-2 compute g_off/inv_cnt (independent work).
// ssrc stores PRE-SCALED byte offsets (src*128).
__global__ __launch_bounds__(512)
void bucket_build(const unsigned* __restrict__ pairs, const int* __restrict__ bcur,
                  int* __restrict__ row_beg, int* __restrict__ row_end,
                  float* __restrict__ inv_deg, int* __restrict__ ssrc,
                  const int* __restrict__ batch, int* __restrict__ g_off,
                  float* __restrict__ inv_cnt) {
    __shared__ int cnt[512];
    __shared__ int curs[512];
    __shared__ int wsum[8];
    const int b = blockIdx.x;
    const int n0 = b << BSH;
    const int t = threadIdx.x;
    const int lane = t & 63, wid = t >> 6;

    // folded graph_offsets: g in [0, NG], handled by blocks 0..2
    {
        int g = b * 512 + t;
        if (g <= NG) {
            if (g == NG) {
                g_off[NG] = NN;
            } else {
                int lo = 0, hi = NN;
                while (lo < hi) { int mid = (lo + hi) >> 1; if (batch[mid] < g) lo = mid + 1; else hi = mid; }
                int lo2 = lo, hi2 = NN;
                while (lo2 < hi2) { int mid = (lo2 + hi2) >> 1; if (batch[mid] < g + 1) lo2 = mid + 1; else hi2 = mid; }
                g_off[g] = lo;
                int c = lo2 - lo;
                inv_cnt[g] = 1.0f / (float)(c > 1 ? c : 1);
            }
        }
    }

    cnt[t] = 0;
    __syncthreads();
    const int beg = b * BCAP, end = bcur[b];
    {
        int i = beg + 4 * t;
        for (; i + 3 < end; i += 2048) {
            uint4 p4 = *(const uint4*)&pairs[i];
            atomicAdd(&cnt[p4.x & 511], 1);
            atomicAdd(&cnt[p4.y & 511], 1);
            atomicAdd(&cnt[p4.z & 511], 1);
            atomicAdd(&cnt[p4.w & 511], 1);
        }
        for (; i < end; ++i) atomicAdd(&cnt[pairs[i] & 511], 1);
    }
    __syncthreads();

    int c = cnt[t];
    int x = c;
    #pragma unroll
    for (int o = 1; o < 64; o <<= 1) {
        int y = __shfl_up(x, o);
        if (lane >= o) x += y;
    }
    if (lane == 63) wsum[wid] = x;
    __syncthreads();
    if (t == 0) {
        int s = 0;
        #pragma unroll
        for (int w2 = 0; w2 < 8; ++w2) { int tv = wsum[w2]; wsum[w2] = s; s += tv; }
    }
    __syncthreads();
    int g0 = beg + wsum[wid] + x - c;   // exclusive prefix
    curs[t] = g0;
    {
        int node = n0 + t;
        if (node < NN) {
            row_beg[node] = g0; row_end[node] = g0 + c;
            inv_deg[node] = 1.0f / (float)(c > 1 ? c : 1);
        }
    }
    __syncthreads();
    {
        int i = beg + 4 * t;
        for (; i + 3 < end; i += 2048) {
            uint4 p4 = *(const uint4*)&pairs[i];
            int p;
            p = atomicAdd(&curs[p4.x & 511], 1); ssrc[p] = (int)(p4.x >> BSH) << 7;
            p = atomicAdd(&curs[p4.y & 511], 1); ssrc[p] = (int)(p4.y >> BSH) << 7;
            p = atomicAdd(&curs[p4.z & 511], 1); ssrc[p] = (int)(p4.z >> BSH) << 7;
            p = atomicAdd(&curs[p4.w & 511], 1); ssrc[p] = (int)(p4.w >> BSH) << 7;
        }
        for (; i < end; ++i) {
            unsigned pr = pairs[i];
            int p = atomicAdd(&curs[pr & 511], 1);
            ssrc[p] = (int)(pr >> BSH) << 7;
        }
    }
}

// ---------------- weight prep: coalesced via LDS staging --------------------
// One block per matrix: stage 128x128 fp32 -> bf16 into LDS with fully
// coalesced float4 reads, then emit MFMA-fragment order with coalesced
// 2B writes (consecutive threads -> consecutive dst). Block 0 also inits
// bucket cursors + the ssrc[0] sentinel (runs before radix_scatter).
struct WTab { const float* a[16]; };
__global__ __launch_bounds__(256)
void prep_weights(WTab tab, unsigned short* __restrict__ dst,
                  int* __restrict__ bcur, int* __restrict__ ssrc) {
    __shared__ unsigned short Wl[128 * 128];
    const int w = blockIdx.x;
    const int t = threadIdx.x;
    if (w == 0) {
        for (int i = t; i < NBK; i += 256) bcur[i] = i * BCAP;
        if (t == 0) ssrc[0] = 0;   // sentinel: valid gather offset
    }
    const float4* src = (const float4*)tab.a[w];
    for (int i = t; i < 4096; i += 256) {
        float4 v = src[i];
        ushort4 o = {f2b(v.x), f2b(v.y), f2b(v.z), f2b(v.w)};
        *(ushort4*)&Wl[i * 4] = o;
    }
    __syncthreads();
    unsigned short* dw = dst + (size_t)w * 16384;
    for (int i2 = 0; i2 < 64; ++i2) {
        int idx = t + i2 * 256;
        int j = idx & 7, lane = (idx >> 3) & 63, nt = (idx >> 9) & 7, kc = idx >> 12;
        int cb = lane & 15, rq = lane >> 4;
        int k = kc * 32 + rq * 8 + j;
        int n = nt * 16 + cb;
        dw[idx] = Wl[k * 128 + n];
    }
}

// ---------------- SAGE mean aggregation: TWO nodes per wave -----------------
__global__ __launch_bounds__(256)
void sage_agg(const unsigned char* __restrict__ h8, const int* __restrict__ row_beg,
              const int* __restrict__ row_end, const float* __restrict__ inv_deg,
              const int* __restrict__ ssrc, unsigned short* __restrict__ aggb) {
    const int wid = threadIdx.x >> 6;
    const int lane = threadIdx.x & 63;
    const int n0 = blockIdx.x * 8 + wid * 2;
    const int n1 = n0 + 1;
    const int eg = lane >> 4, j = lane & 15;
    const int jo = j * 8;
    const int beg0 = row_beg[n0], end0 = row_end[n0];
    const int beg1 = row_beg[n1], end1 = row_end[n1];
    f32x2 a0 = {0.f, 0.f}, a1 = {0.f, 0.f}, a2 = {0.f, 0.f}, a3 = {0.f, 0.f};
    f32x2 b0 = {0.f, 0.f}, b1 = {0.f, 0.f}, b2 = {0.f, 0.f}, b3 = {0.f, 0.f};
    int e0 = beg0 + eg, e1 = beg1 + eg;
    const int d0 = end0 - beg0, d1 = end1 - beg1;
    const int nit = ((d0 > d1 ? d0 : d1) + 31) >> 5;
    for (int it = 0; it < nit; ++it, e0 += 32, e1 += 32) {
        uint2 u0[8], u1[8];
        #pragma unroll
        for (int k = 0; k < 8; ++k) {
            int ek = e0 + 4 * k;
            bool ok = ek < end0;
            int idx = ssrc[ok ? ek : 0];
            uint2 uu = *(const uint2*)(h8 + (unsigned)(idx + jo));
            uu.x = ok ? uu.x : 0u;
            uu.y = ok ? uu.y : 0u;                             // fp8 0x00 -> 0.0f
            u0[k] = uu;
        }
        #pragma unroll
        for (int k = 0; k < 8; ++k) {
            int ek = e1 + 4 * k;
            bool ok = ek < end1;
            int idx = ssrc[ok ? ek : 0];
            uint2 uu = *(const uint2*)(h8 + (unsigned)(idx + jo));
            uu.x = ok ? uu.x : 0u;
            uu.y = ok ? uu.y : 0u;
            u1[k] = uu;
        }
        #pragma unroll
        for (int k = 0; k < 8; ++k) {
            a0 += __builtin_amdgcn_cvt_pk_f32_fp8(u0[k].x, false);
            a1 += __builtin_amdgcn_cvt_pk_f32_fp8(u0[k].x, true);
            a2 += __builtin_amdgcn_cvt_pk_f32_fp8(u0[k].y, false);
            a3 += __builtin_amdgcn_cvt_pk_f32_fp8(u0[k].y, true);
            b0 += __builtin_amdgcn_cvt_pk_f32_fp8(u1[k].x, false);
            b1 += __builtin_amdgcn_cvt_pk_f32_fp8(u1[k].x, true);
            b2 += __builtin_amdgcn_cvt_pk_f32_fp8(u1[k].y, false);
            b3 += __builtin_amdgcn_cvt_pk_f32_fp8(u1[k].y, true);
        }
    }
    float af[8] = {a0.x, a0.y, a1.x, a1.y, a2.x, a2.y, a3.x, a3.y};
    float bf[8] = {b0.x, b0.y, b1.x, b1.y, b2.x, b2.y, b3.x, b3.y};
    #pragma unroll
    for (int k = 0; k < 8; ++k) {
        af[k] += __shfl_xor(af[k], 16);
        af[k] += __shfl_xor(af[k], 32);
        bf[k] += __shfl_xor(bf[k], 16);
        bf[k] += __shfl_xor(bf[k], 32);
    }
    if (eg == 0) {
        float id0 = inv_deg[n0];
        float id1 = inv_deg[n1];
        #pragma unroll
        for (int nt = 0; nt < 8; ++nt) {
            aggb[(size_t)n0 * 128 + nt * 16 + j] = f2b(af[nt] * id0);
            aggb[(size_t)n1 * 128 + nt * 16 + j] = f2b(bf[nt] * id1);
        }
    }
}

// ---------------- mean pool per graph from bf16 (4 waves + LDS reduce) ------
__global__ __launch_bounds__(256)
void pool_mean_b(const unsigned short* __restrict__ src, const int* __restrict__ g_off,
                 const float* __restrict__ inv_cnt, float* __restrict__ out) {
    __shared__ float red[3][128];
    const int g = blockIdx.x;
    const int t = threadIdx.x;
    const int lane = t & 63, wid = t >> 6;
    const int j = lane & 15, rs = lane >> 4;
    const int beg = g_off[g], end = g_off[g + 1];
    float s[8] = {0.f, 0.f, 0.f, 0.f, 0.f, 0.f, 0.f, 0.f};
    for (int n = beg + rs + wid * 4; n < end; n += 16) {
        short8 v = *(const short8*)&src[(size_t)n * FF + j * 8];
        #pragma unroll
        for (int i = 0; i < 8; ++i) s[i] += us2f((unsigned short)v[i]);
    }
    #pragma unroll
    for (int i = 0; i < 8; ++i) {
        s[i] += __shfl_xor(s[i], 16);
        s[i] += __shfl_xor(s[i], 32);
    }
    if (wid > 0 && rs == 0) {
        #pragma unroll
        for (int i = 0; i < 8; ++i) red[wid - 1][j * 8 + i] = s[i];
    }
    __syncthreads();
    if (wid == 0 && rs == 0) {
        float ic = inv_cnt[g];
        #pragma unroll
        for (int i = 0; i < 8; ++i) {
            float v = s[i] + red[0][j * 8 + i] + red[1][j * 8 + i] + red[2][j * 8 + i];
            out[(size_t)g * FF + j * 8 + i] = v * ic;
        }
    }
}

// ---------------- MFMA bf16 GEMM: BARRIER-FREE (wave-private band stage) ----
template<bool AB16, bool R1, int RESM, int ACT, bool LN, bool OF32, bool OB16, bool OB8>
__global__ __launch_bounds__(256)
void gemm_mfma(const void* __restrict__ A_,
               const unsigned short* __restrict__ Wf,
               const float* __restrict__ bias,
               const float* __restrict__ rvec, const float* __restrict__ rrow,
               const float* __restrict__ res,
               const float* __restrict__ lng, const float* __restrict__ lnb,
               float* __restrict__ outf, unsigned short* __restrict__ outb,
               unsigned char* __restrict__ outb8, int M) {
    __shared__ short Al[64 * 136];

    const int t = threadIdx.x;
    const int lane = t & 63, wid = t >> 6;
    const int m0 = blockIdx.x * 64;
    const int cb = lane & 15, rq = lane >> 4;
    const int band = wid * 16;

    if (AB16) {
        const unsigned short* Ab = (const unsigned short*)A_;
        #pragma unroll
        for (int i2 = 0; i2 < 4; ++i2) {
            int i = lane + i2 * 64;
            int row = band + (i >> 4), seg = i & 15;
            int gr = m0 + row; if (gr >= M) gr = M - 1;
            *(uint4*)&Al[row * 136 + seg * 8] = *(const uint4*)&Ab[(size_t)gr * 128 + seg * 8];
        }
    } else {
        const float* Af = (const float*)A_;
        #pragma unroll
        for (int i2 = 0; i2 < 8; ++i2) {
            int i = lane + i2 * 64;
            int row = band + (i >> 5), seg = i & 31;
            int gr = m0 + row; if (gr >= M) gr = M - 1;
            float4 v = *(const float4*)&Af[(size_t)gr * 128 + seg * 4];
            ushort4 o = {f2b(v.x), f2b(v.y), f2b(v.z), f2b(v.w)};
            *(ushort4*)&Al[row * 136 + seg * 4] = o;
        }
    }
    // no barrier: all LDS traffic is band-local (same wave wrote it)

    f32x4 acc[8];
    #pragma unroll
    for (int nt = 0; nt < 8; ++nt) acc[nt] = (f32x4){0.f, 0.f, 0.f, 0.f};

    const int aoff_base = (band + cb) * 136 + rq * 8;
    for (int kc = 0; kc < 4; ++kc) {
        short8 a0 = *(const short8*)&Al[aoff_base + kc * 32];
        #pragma unroll
        for (int nt = 0; nt < 8; ++nt) {
            short8 b0 = *(const short8*)&Wf[(size_t)(kc * 8 + nt) * 512 + lane * 8];
            acc[nt] = MFMA(a0, b0, acc[nt]);
        }
    }

    float bs[8], rr[8], lg[8], lb[8];
    #pragma unroll
    for (int nt = 0; nt < 8; ++nt) {
        int col = nt * 16 + cb;
        bs[nt] = bias[col];
        if (R1) rr[nt] = rrow[col];
        if (LN) { lg[nt] = lng[col]; lb[nt] = lnb[col]; }
    }
    #pragma unroll
    for (int reg = 0; reg < 4; ++reg) {
        int m = m0 + band + rq * 4 + reg;
        int mc = m < M ? m : M - 1;
        float v[8];
        #pragma unroll
        for (int nt = 0; nt < 8; ++nt) v[nt] = acc[nt][reg] + bs[nt];
        if (R1) {
            float rv = rvec[mc];
            #pragma unroll
            for (int nt = 0; nt < 8; ++nt) v[nt] += rv * rr[nt];
        }
        if (RESM == 1) {
            #pragma unroll
            for (int nt = 0; nt < 8; ++nt) v[nt] += res[(size_t)mc * 128 + nt * 16 + cb];
        }
        if (ACT == 1) {
            #pragma unroll
            for (int nt = 0; nt < 8; ++nt) v[nt] = fast_elu(v[nt]);
        }
        if (LN) {
            float s1 = 0.f, s2 = 0.f;
            #pragma unroll
            for (int nt = 0; nt < 8; ++nt) { s1 += v[nt]; s2 += v[nt] * v[nt]; }
            #pragma unroll
            for (int o = 8; o >= 1; o >>= 1) { s1 += __shfl_xor(s1, o); s2 += __shfl_xor(s2, o); }
            float mu = s1 * (1.f / 128.f);
            float rs = rsqrtf(s2 * (1.f / 128.f) - mu * mu + 1e-5f);
            #pragma unroll
            for (int nt = 0; nt < 8; ++nt) v[nt] = (v[nt] - mu) * rs * lg[nt] + lb[nt];
        }
        if (m < M) {
            #pragma unroll
            for (int nt = 0; nt < 8; ++nt) {
                size_t o = (size_t)m * 128 + nt * 16 + cb;
                if (OF32) outf[o] = v[nt];
                if (OB16) outb[o] = f2b(v[nt]);
            }
            if (OB8) *(uint2*)&outb8[(size_t)m * 128 + cb * 8] = pk8(v);
        }
    }
}

// ---------------- fused GEMM chain: BARRIER-FREE (wave-private bands) -------
__global__ __launch_bounds__(256)
void gc_chain(const unsigned short* __restrict__ hin, const unsigned short* __restrict__ aggb,
              unsigned short* __restrict__ hout, unsigned char* __restrict__ h8out,
              const unsigned short* __restrict__ Wl_f, const unsigned short* __restrict__ Wr_f,
              const unsigned short* __restrict__ W1_f, const unsigned short* __restrict__ W2_f,
              const float* __restrict__ bl,
              const float* __restrict__ g1, const float* __restrict__ b1,
              const float* __restrict__ bb1, const float* __restrict__ bb2,
              const float* __restrict__ g2, const float* __restrict__ b2, int M) {
    __shared__ short Hl[64 * 136];     // h tile -> y1 tile
    __shared__ short Gl[64 * 136];     // agg tile -> elu(t) tile

    const int t = threadIdx.x;
    const int lane = t & 63, wid = t >> 6;
    const int m0 = blockIdx.x * 64;
    const int cb = lane & 15, rq = lane >> 4;
    const int band = wid * 16;
    const int aoff_base = (band + cb) * 136 + rq * 8;
    const int boff = lane * 8;

    #pragma unroll
    for (int i2 = 0; i2 < 4; ++i2) {
        int i = lane + i2 * 64;
        int row = band + (i >> 4), seg = i & 15;
        int gr = m0 + row; if (gr >= M) gr = M - 1;
        *(uint4*)&Hl[row * 136 + seg * 8] = *(const uint4*)&hin[(size_t)gr * 128 + seg * 8];
        *(uint4*)&Gl[row * 136 + seg * 8] = *(const uint4*)&aggb[(size_t)gr * 128 + seg * 8];
    }
    // no barrier: band-local LDS only

    f32x4 acc[8];
    #pragma unroll
    for (int nt = 0; nt < 8; ++nt) acc[nt] = (f32x4){0.f, 0.f, 0.f, 0.f};

    // ---- dual GEMM: acc = agg@Wl + h@Wr ----
    for (int kc = 0; kc < 4; ++kc) {
        short8 a0 = *(const short8*)&Gl[aoff_base + kc * 32];
        short8 a1 = *(const short8*)&Hl[aoff_base + kc * 32];
        #pragma unroll
        for (int nt = 0; nt < 8; ++nt) {
            const size_t wo = (size_t)(kc * 8 + nt) * 512 + boff;
            acc[nt] = MFMA(a0, *(const short8*)&Wl_f[wo], acc[nt]);
            acc[nt] = MFMA(a1, *(const short8*)&Wr_f[wo], acc[nt]);
        }
    }

    // ---- epilogue 1 (band-local): y1 = LN1(acc + bl + h) -> Hl + regs ----
    float y1r[4][8];
    {
        float bs[8], lg[8], lb[8];
        #pragma unroll
        for (int nt = 0; nt < 8; ++nt) {
            int col = nt * 16 + cb;
            bs[nt] = bl[col]; lg[nt] = g1[col]; lb[nt] = b1[col];
        }
        #pragma unroll
        for (int reg = 0; reg < 4; ++reg) {
            int r = band + rq * 4 + reg;
            float v[8];
            float s1 = 0.f, s2 = 0.f;
            #pragma unroll
            for (int nt = 0; nt < 8; ++nt) {
                v[nt] = acc[nt][reg] + bs[nt] + us2f((unsigned short)Hl[r * 136 + nt * 16 + cb]);
                s1 += v[nt]; s2 += v[nt] * v[nt];
            }
            #pragma unroll
            for (int o = 8; o >= 1; o >>= 1) { s1 += __shfl_xor(s1, o); s2 += __shfl_xor(s2, o); }
            float mu = s1 * (1.f / 128.f);
            float rs = rsqrtf(s2 * (1.f / 128.f) - mu * mu + 1e-5f);
            #pragma unroll
            for (int nt = 0; nt < 8; ++nt) {
                float y = (v[nt] - mu) * rs * lg[nt] + lb[nt];
                y1r[reg][nt] = y;
                Hl[r * 136 + nt * 16 + cb] = (short)f2b(y);
            }
        }
    }

    // ---- FF1 (band-local): t = elu(y1@W1 + bb1) -> Gl ----
    #pragma unroll
    for (int nt = 0; nt < 8; ++nt) acc[nt] = (f32x4){0.f, 0.f, 0.f, 0.f};
    for (int kc = 0; kc < 4; ++kc) {
        short8 a0 = *(const short8*)&Hl[aoff_base + kc * 32];
        #pragma unroll
        for (int nt = 0; nt < 8; ++nt)
            acc[nt] = MFMA(a0, *(const short8*)&W1_f[(size_t)(kc * 8 + nt) * 512 + boff], acc[nt]);
    }
    {
        float bs[8];
        #pragma unroll
        for (int nt = 0; nt < 8; ++nt) bs[nt] = bb1[nt * 16 + cb];
        #pragma unroll
        for (int reg = 0; reg < 4; ++reg) {
            int r = band + rq * 4 + reg;
            #pragma unroll
            for (int nt = 0; nt < 8; ++nt) {
                float v = fast_elu(acc[nt][reg] + bs[nt]);
                Gl[r * 136 + nt * 16 + cb] = (short)f2b(v);
            }
        }
    }

    // ---- FF2 (band-local): h' = LN2(t@W2 + bb2 + y1) -> global bf16 + fp8 --
    #pragma unroll
    for (int nt = 0; nt < 8; ++nt) acc[nt] = (f32x4){0.f, 0.f, 0.f, 0.f};
    for (int kc = 0; kc < 4; ++kc) {
        short8 a0 = *(const short8*)&Gl[aoff_base + kc * 32];
        #pragma unroll
        for (int nt = 0; nt < 8; ++nt)
            acc[nt] = MFMA(a0, *(const short8*)&W2_f[(size_t)(kc * 8 + nt) * 512 + boff], acc[nt]);
    }
    {
        float bs[8], lg[8], lb[8];
        #pragma unroll
        for (int nt = 0; nt < 8; ++nt) {
            int col = nt * 16 + cb;
            bs[nt] = bb2[col]; lg[nt] = g2[col]; lb[nt] = b2[col];
        }
        #pragma unroll
        for (int reg = 0; reg < 4; ++reg) {
            int r = band + rq * 4 + reg;
            int m = m0 + r;
            float v[8];
            float s1 = 0.f, s2 = 0.f;
            #pragma unroll
            for (int nt = 0; nt < 8; ++nt) {
                v[nt] = acc[nt][reg] + bs[nt] + y1r[reg][nt];
                s1 += v[nt]; s2 += v[nt] * v[nt];
            }
            #pragma unroll
            for (int o = 8; o >= 1; o >>= 1) { s1 += __shfl_xor(s1, o); s2 += __shfl_xor(s2, o); }
            float mu = s1 * (1.f / 128.f);
            float rs = rsqrtf(s2 * (1.f / 128.f) - mu * mu + 1e-5f);
            if (m < M) {
                float fv[8];
                #pragma unroll
                for (int nt = 0; nt < 8; ++nt) {
                    fv[nt] = (v[nt] - mu) * rs * lg[nt] + lb[nt];
                    hout[(size_t)m * 128 + nt * 16 + cb] = f2b(fv[nt]);
                }
                *(uint2*)&h8out[(size_t)m * 128 + cb * 8] = pk8(fv);
            }
        }
    }
}

// ---------------- fused head: BARRIER-FREE band-local chain -----------------
__global__ __launch_bounds__(256)
void head_chain(const float* __restrict__ gm,
                const unsigned short* __restrict__ Wa_f,
                const unsigned short* __restrict__ P1_f,
                const unsigned short* __restrict__ P2_f,
                const float* __restrict__ mdfb,
                const float* __restrict__ g1, const float* __restrict__ b1,
                const float* __restrict__ p1b, const float* __restrict__ p2b,
                const float* __restrict__ g2, const float* __restrict__ b2,
                float* __restrict__ outp) {
    __shared__ short Al[64 * 136];

    const int t = threadIdx.x;
    const int lane = t & 63, wid = t >> 6;
    const int m0 = blockIdx.x * 64;
    const int cb = lane & 15, rq = lane >> 4;
    const int band = wid * 16;
    const int aoff_base = (band + cb) * 136 + rq * 8;
    const int boff = lane * 8;

    #pragma unroll
    for (int i2 = 0; i2 < 8; ++i2) {
        int i = lane + i2 * 64;
        int row = band + (i >> 5), seg = i & 31;
        float4 v = *(const float4*)&gm[(size_t)(m0 + row) * 128 + seg * 4];
        ushort4 o = {f2b(v.x), f2b(v.y), f2b(v.z), f2b(v.w)};
        *(ushort4*)&Al[row * 136 + seg * 4] = o;
    }
    // no barrier: band-local LDS only

    f32x4 acc[8];
    // ---- GEMM1: gm@Wa + mdfb, LN1 -> y1r + Al ----
    #pragma unroll
    for (int nt = 0; nt < 8; ++nt) acc[nt] = (f32x4){0.f, 0.f, 0.f, 0.f};
    for (int kc = 0; kc < 4; ++kc) {
        short8 a0 = *(const short8*)&Al[aoff_base + kc * 32];
        #pragma unroll
        for (int nt = 0; nt < 8; ++nt)
            acc[nt] = MFMA(a0, *(const short8*)&Wa_f[(size_t)(kc * 8 + nt) * 512 + boff], acc[nt]);
    }
    float y1r[4][8];
    {
        float bs[8], lg[8], lb[8];
        #pragma unroll
        for (int nt = 0; nt < 8; ++nt) {
            int col = nt * 16 + cb;
            bs[nt] = mdfb[col]; lg[nt] = g1[col]; lb[nt] = b1[col];
        }
        #pragma unroll
        for (int reg = 0; reg < 4; ++reg) {
            int r = band + rq * 4 + reg;
            float v[8];
            float s1 = 0.f, s2 = 0.f;
            #pragma unroll
            for (int nt = 0; nt < 8; ++nt) {
                v[nt] = acc[nt][reg] + bs[nt];
                s1 += v[nt]; s2 += v[nt] * v[nt];
            }
            #pragma unroll
            for (int o = 8; o >= 1; o >>= 1) { s1 += __shfl_xor(s1, o); s2 += __shfl_xor(s2, o); }
            float mu = s1 * (1.f / 128.f);
            float rs = rsqrtf(s2 * (1.f / 128.f) - mu * mu + 1e-5f);
            #pragma unroll
            for (int nt = 0; nt < 8; ++nt) {
                float y = (v[nt] - mu) * rs * lg[nt] + lb[nt];
                y1r[reg][nt] = y;
                Al[r * 136 + nt * 16 + cb] = (short)f2b(y);
            }
        }
    }

    // ---- GEMM2: elu(y1@P1 + p1b) -> Al ----
    #pragma unroll
    for (int nt = 0; nt < 8; ++nt) acc[nt] = (f32x4){0.f, 0.f, 0.f, 0.f};
    for (int kc = 0; kc < 4; ++kc) {
        short8 a0 = *(const short8*)&Al[aoff_base + kc * 32];
        #pragma unroll
        for (int nt = 0; nt < 8; ++nt)
            acc[nt] = MFMA(a0, *(const short8*)&P1_f[(size_t)(kc * 8 + nt) * 512 + boff], acc[nt]);
    }
    {
        float bs[8];
        #pragma unroll
        for (int nt = 0; nt < 8; ++nt) bs[nt] = p1b[nt * 16 + cb];
        #pragma unroll
        for (int reg = 0; reg < 4; ++reg) {
            int r = band + rq * 4 + reg;
            #pragma unroll
            for (int nt = 0; nt < 8; ++nt) {
                float v = fast_elu(acc[nt][reg] + bs[nt]);
                Al[r * 136 + nt * 16 + cb] = (short)f2b(v);
            }
        }
    }

    // ---- GEMM3: LN2(t@P2 + p2b + y1r) -> out fp32 ----
    #pragma unroll
    for (int nt = 0; nt < 8; ++nt) acc[nt] = (f32x4){0.f, 0.f, 0.f, 0.f};
    for (int kc = 0; kc < 4; ++kc) {
        short8 a0 = *(const short8*)&Al[aoff_base + kc * 32];
        #pragma unroll
        for (int nt = 0; nt < 8; ++nt)
            acc[nt] = MFMA(a0, *(const short8*)&P2_f[(size_t)(kc * 8 + nt) * 512 + boff], acc[nt]);
    }
    {
        float bs[8], lg[8], lb[8];
        #pragma unroll
        for (int nt = 0; nt < 8; ++nt) {
            int col = nt * 16 + cb;
            bs[nt] = p2b[col]; lg[nt] = g2[col]; lb[nt] = b2[col];
        }
        #pragma unroll
        for (int reg = 0; reg < 4; ++reg) {
            int r = band + rq * 4 + reg;
            int m = m0 + r;
            float v[8];
            float s1 = 0.f, s2 = 0.f;
            #pragma unroll
            for (int nt = 0; nt < 8; ++nt) {
                v[nt] = acc[nt][reg] + bs[nt] + y1r[reg][nt];
                s1 += v[nt]; s2 += v[nt] * v[nt];
            }
            #pragma unroll
            for (int o = 8; o >= 1; o >>= 1) { s1 += __shfl_xor(s1, o); s2 += __shfl_xor(s2, o); }
            float mu = s1 * (1.f / 128.f);
            float rs = rsqrtf(s2 * (1.f / 128.f) - mu * mu + 1e-5f);
            #pragma unroll
            for (int nt = 0; nt < 8; ++nt)
                outp[(size_t)m * 128 + nt * 16 + cb] = (v[nt] - mu) * rs * lg[nt] + lb[nt];
        }
    }
}

extern "C" void kernel_launch(void* const* d_in, const int* in_sizes, int n_in,
                              void* d_out, int out_size, void* d_ws, size_t ws_size,
                              hipStream_t stream) {
    const float* x      = (const float*)d_in[0];
    const float* w      = (const float*)d_in[1];
    const int*   ei     = (const int*)d_in[2];
    const int*   batch  = (const int*)d_in[3];
    const float* W_in   = (const float*)d_in[4];
    const float* b_in   = (const float*)d_in[5];
    const float* sage_Wl = (const float*)d_in[6];
    const float* sage_bl = (const float*)d_in[7];
    const float* sage_Wr = (const float*)d_in[8];
    const float* ln1_g  = (const float*)d_in[9];
    const float* ln1_b  = (const float*)d_in[10];
    const float* lin1_W = (const float*)d_in[11];
    const float* lin1_b = (const float*)d_in[12];
    const float* lin2_W = (const float*)d_in[13];
    const float* lin2_b = (const float*)d_in[14];
    const float* ln2_g  = (const float*)d_in[15];
    const float* ln2_b  = (const float*)d_in[16];
    const float* mdf_W  = (const float*)d_in[17];
    const float* mdf_b  = (const float*)d_in[18];
    const float* pln1_g = (const float*)d_in[19];
    const float* pln1_b = (const float*)d_in[20];
    const float* plin1_W = (const float*)d_in[21];
    const float* plin1_b = (const float*)d_in[22];
    const float* plin2_W = (const float*)d_in[23];
    const float* plin2_b = (const float*)d_in[24];
    const float* pln2_g = (const float*)d_in[25];
    const float* pln2_b = (const float*)d_in[26];
    float* out = (float*)d_out;

    const int* e_src = ei;
    const int* e_dst = ei + NE;

    // ---- workspace layout ----
    float* ws = (float*)d_ws;
    size_t off = 0;
    float* gm    = ws + off; off += (size_t)NG * FF;
    float* hh    = ws + off; off += (size_t)NG * FF;
    float* tt    = ws + off; off += (size_t)NG * FF;
    float* inv_deg = ws + off; off += NN;
    float* inv_cnt = ws + off; off += NG;
    unsigned short* us = (unsigned short*)(ws + off);
    size_t uoff = 0;
    unsigned short* hb0  = us + uoff; uoff += (size_t)NN * FF;
    unsigned short* hb1  = us + uoff; uoff += (size_t)NN * FF;
    unsigned short* aggb = us + uoff; uoff += (size_t)NN * FF;
    unsigned short* wt   = us + uoff; uoff += (size_t)16 * 16384;
    int* iw = (int*)(us + uoff);
    size_t ioff = 0;
    unsigned* pairs = (unsigned*)iw; ioff += (size_t)NBK * BCAP;
    int* ssrc    = iw + ioff; ioff += (size_t)NBK * BCAP;
    int* row_beg = iw + ioff; ioff += NN;
    int* row_end = iw + ioff; ioff += NN;
    int* g_off   = iw + ioff; ioff += NG + 1;
    int* bcur    = iw + ioff; ioff += NBK;
    // h8 (12.8 MB) aliases pairs (12.85 MB): pairs is dead after bucket_build,
    // h8 is first written by the input GEMM which runs after.
    unsigned char* h8 = (unsigned char*)pairs;

    // ---- weight prep (16 matrices, coalesced via LDS) + bcur/sentinel ----
    WTab tab;
    tab.a[0] = W_in;
    for (int l = 0; l < 3; ++l) {
        tab.a[1 + l]  = sage_Wl + (size_t)l * 16384;
        tab.a[4 + l]  = sage_Wr + (size_t)l * 16384;
        tab.a[7 + l]  = lin1_W + (size_t)l * 16384;
        tab.a[10 + l] = lin2_W + (size_t)l * 16384;
    }
    tab.a[13] = mdf_W;      // first 128 rows only (Wa)
    tab.a[14] = plin1_W;
    tab.a[15] = plin2_W;
    prep_weights<<<16, 256, 0, stream>>>(tab, wt, bcur, ssrc);
    const unsigned short* win_t = wt + 0 * 16384;
    const unsigned short* wa_t  = wt + 13 * 16384;
    const unsigned short* p1_t  = wt + 14 * 16384;
    const unsigned short* p2_t  = wt + 15 * 16384;

    // ---- build padded CSR (graph offsets folded into bucket_build) ----
    radix_scatter<<<RB, 256, 0, stream>>>(e_src, e_dst, bcur, pairs, NE);
    bucket_build<<<NBK, 512, 0, stream>>>(pairs, bcur, row_beg, row_end,
                                          inv_deg, ssrc, batch, g_off, inv_cnt);

    const int GN = (NN + 63) / 64;     // 1563
    const int GB = NG / 64;            // 16

    // ---- input linear: hb0 (bf16) + h8 (fp8, permuted) ----
    gemm_mfma<false, true, 0, 0, false, false, true, true><<<GN, 256, 0, stream>>>(
        x, win_t, b_in, w, W_in + 128 * 128,
        nullptr, nullptr, nullptr, nullptr, hb0, h8, NN);

    // ---- 3 GC blocks: fp8 gather + fused GEMM chain ----
    unsigned short* hcur = hb0;
    unsigned short* hnxt = hb1;
    for (int l = 0; l < 3; ++l) {
        sage_agg<<<NN / 8, 256, 0, stream>>>(h8, row_beg, row_end, inv_deg, ssrc, aggb);
        gc_chain<<<GN, 256, 0, stream>>>(
            hcur, aggb, hnxt, h8,
            wt + (size_t)(1 + l) * 16384, wt + (size_t)(4 + l) * 16384,
            wt + (size_t)(7 + l) * 16384, wt + (size_t)(10 + l) * 16384,
            sage_bl + (size_t)l * FF,
            ln1_g + (size_t)l * FF, ln1_b + (size_t)l * FF,
            lin1_b + (size_t)l * FF, lin2_b + (size_t)l * FF,
            ln2_g + (size_t)l * FF, ln2_b + (size_t)l * FF, NN);
        unsigned short* tmp = hcur; hcur = hnxt; hnxt = tmp;
    }

    // ---- head: pool(h2) -> fused LN1/FF/LN2 chain (one launch) ----
    pool_mean_b<<<NG, 256, 0, stream>>>(hcur, g_off, inv_cnt, gm);
    head_chain<<<GB, 256, 0, stream>>>(
        gm, wa_t, p1_t, p2_t, mdf_b,
        pln1_g, pln1_b, plin1_b, plin2_b, pln2_g, pln2_b, out);
    (void)hh; (void)tt;
}